// Round 7
// baseline (5391.833 us; speedup 1.0000x reference)
//
#include <hip/hip_runtime.h>

#define TT 10
#define NN 10000
#define CC 4
#define HH 128
#define EE 160000

typedef unsigned char u8;

// ---------------- U/V precompute: U[m=k*2+half][n][:] = h[n] @ W1[k][half*128:+128][:]
// fc1w layout (3,256,128): W1[k][f][h]; (k*256+half*128)*128 == m*16384.
__global__ __launch_bounds__(256)
void uv_kernel(const float* __restrict__ hid, const float* __restrict__ fc1w,
               float* __restrict__ UV){
  __shared__ float hL[32][136];
  const int tid = threadIdx.x;
  const int n0 = blockIdx.x << 5;
  const int m = blockIdx.y;
  const float* __restrict__ W = fc1w + (size_t)m * (HH*HH);

  #pragma unroll
  for (int it = 0; it < 4; ++it){
    int s = tid + (it << 8);          // 0..1023 float4 slots
    int r = s >> 5, c4 = s & 31;
    int node = n0 + r; if (node > NN-1) node = NN-1;
    float4 v = *(const float4*)(hid + (size_t)node*HH + (c4 << 2));
    *(float4*)(&hL[r][c4 << 2]) = v;
  }
  __syncthreads();

  const int rg = tid >> 5, cg = tid & 31;
  float acc[4][4] = {};
  for (int kk = 0; kk < HH; ++kk){
    float hv[4];
    #pragma unroll
    for (int rr = 0; rr < 4; ++rr) hv[rr] = hL[(rg << 2) + rr][kk];
    float4 wv = *(const float4*)(W + kk*HH + (cg << 2));
    #pragma unroll
    for (int rr = 0; rr < 4; ++rr){
      acc[rr][0] = fmaf(hv[rr], wv.x, acc[rr][0]);
      acc[rr][1] = fmaf(hv[rr], wv.y, acc[rr][1]);
      acc[rr][2] = fmaf(hv[rr], wv.z, acc[rr][2]);
      acc[rr][3] = fmaf(hv[rr], wv.w, acc[rr][3]);
    }
  }
  #pragma unroll
  for (int rr = 0; rr < 4; ++rr){
    int node = n0 + (rg << 2) + rr;
    if (node < NN){
      float4 o = { acc[rr][0], acc[rr][1], acc[rr][2], acc[rr][3] };
      *(float4*)(UV + ((size_t)m*NN + node)*HH + (cg << 2)) = o;
    }
  }
}

// ---------------- Edge kernel: 64 edges/block, per-thread tile 8 edges x 4 cols.
// m1 = tanh(U[k][row] + V[k][col] + b1); msg = sum_k tanh(m1@W2[k] + b2); atomic scatter.
__global__ __launch_bounds__(256)
void edge_kernel(const int* __restrict__ edge, const float* __restrict__ UV,
                 const float* __restrict__ b1, const float* __restrict__ b2,
                 const float* __restrict__ fc2w, float* __restrict__ agg){
  __shared__ float m1L[64][132];   // one branch: 64 edges x 128 (pad 4) = 33.8KB
  __shared__ int er[64], ec[64];
  const int tid = threadIdx.x;
  const int e0 = blockIdx.x << 6;

  if (tid < 64) er[tid] = edge[e0 + tid];
  else if (tid < 128) ec[tid - 64] = edge[EE + e0 + tid - 64];

  const int eg = tid >> 5, cg = tid & 31;
  const int cOff = cg << 2;
  float acc[8][4] = {};

  for (int k = 0; k < 3; ++k){
    __syncthreads();               // indices ready (k=0) / previous matmul reads done
    // stage m1 for branch k: 64 rows x 32 float4-cols = 2048 slots, 8 per thread
    {
      float4 b = *(const float4*)(b1 + k*HH + cOff);
      const float* __restrict__ Ub = UV + (size_t)(2*k)*NN*HH;
      const float* __restrict__ Vb = UV + (size_t)(2*k + 1)*NN*HH;
      #pragma unroll
      for (int it = 0; it < 8; ++it){
        int e = (tid >> 5) + (it << 3);
        float4 u = *(const float4*)(Ub + (size_t)er[e]*HH + cOff);
        float4 v = *(const float4*)(Vb + (size_t)ec[e]*HH + cOff);
        float4 o;
        o.x = tanhf(u.x + v.x + b.x);
        o.y = tanhf(u.y + v.y + b.y);
        o.z = tanhf(u.z + v.z + b.z);
        o.w = tanhf(u.w + v.w + b.w);
        *(float4*)(&m1L[e][cOff]) = o;
      }
    }
    __syncthreads();

    const float* __restrict__ W2 = fc2w + (size_t)k*HH*HH;
    float lacc[8][4] = {};
    for (int kk = 0; kk < HH; kk += 4){
      float4 wv[4];
      #pragma unroll
      for (int j = 0; j < 4; ++j)
        wv[j] = *(const float4*)(W2 + (kk + j)*HH + cOff);
      #pragma unroll
      for (int ee = 0; ee < 8; ++ee){
        float4 mv = *(const float4*)(&m1L[(eg << 3) + ee][kk]);
        const float* m = (const float*)&mv;
        #pragma unroll
        for (int j = 0; j < 4; ++j){
          lacc[ee][0] = fmaf(m[j], wv[j].x, lacc[ee][0]);
          lacc[ee][1] = fmaf(m[j], wv[j].y, lacc[ee][1]);
          lacc[ee][2] = fmaf(m[j], wv[j].z, lacc[ee][2]);
          lacc[ee][3] = fmaf(m[j], wv[j].w, lacc[ee][3]);
        }
      }
    }
    {
      float4 bb = *(const float4*)(b2 + k*HH + cOff);
      #pragma unroll
      for (int ee = 0; ee < 8; ++ee){
        acc[ee][0] += tanhf(lacc[ee][0] + bb.x);
        acc[ee][1] += tanhf(lacc[ee][1] + bb.y);
        acc[ee][2] += tanhf(lacc[ee][2] + bb.z);
        acc[ee][3] += tanhf(lacc[ee][3] + bb.w);
      }
    }
  }

  #pragma unroll
  for (int ee = 0; ee < 8; ++ee){
    int node = ec[(eg << 3) + ee];
    float* ap = agg + (size_t)node*HH + cOff;
    #pragma unroll
    for (int cc = 0; cc < 4; ++cc) atomicAdd(ap + cc, acc[ee][cc]);
  }
}

// ---------------- Node kernel: GRU gates + 3-layer output MLP + prediction.
__global__ __launch_bounds__(256)
void node_kernel(const float* __restrict__ xin, const float* __restrict__ prevpred,
                 const int* __restrict__ burn, int t,
                 const float* __restrict__ agg, float* __restrict__ hid,
                 const float* __restrict__ whr, const float* __restrict__ whi, const float* __restrict__ whh,
                 const float* __restrict__ irw, const float* __restrict__ irb,
                 const float* __restrict__ iiw, const float* __restrict__ iib,
                 const float* __restrict__ inw, const float* __restrict__ inb,
                 const float* __restrict__ o1w, const float* __restrict__ o1b,
                 const float* __restrict__ o2w, const float* __restrict__ o2b,
                 const float* __restrict__ o3w, const float* __restrict__ o3b,
                 float* __restrict__ out){
  __shared__ float aggL[32][136];
  __shared__ float hNL[32][136];
  __shared__ float p1L[32][136];
  __shared__ float p2L[32][136];
  __shared__ float xLs[32][4];
  const int tid = threadIdx.x;
  const int n0 = blockIdx.x << 5;
  const float* __restrict__ xs = (t == 0 || t < burn[0]) ? xin : prevpred;

  #pragma unroll
  for (int it = 0; it < 4; ++it){
    int s = tid + (it << 8);
    int r = s >> 5, c4 = s & 31;
    int node = n0 + r; if (node > NN-1) node = NN-1;
    float4 v = *(const float4*)(agg + (size_t)node*HH + (c4 << 2));
    *(float4*)(&aggL[r][c4 << 2]) = v;
  }
  if (tid < 128){
    int r = tid >> 2, c = tid & 3;
    int node = n0 + r; if (node > NN-1) node = NN-1;
    xLs[r][c] = xs[(size_t)node*CC + c];
  }
  __syncthreads();

  const int ng = tid >> 5, cg = tid & 31;
  // GRU matmuls: ar/ai/ah = agg @ {whr, whi, whh}
  float ar[4][4] = {}, ai[4][4] = {}, ah[4][4] = {};
  for (int kk = 0; kk < HH; ++kk){
    float av[4];
    #pragma unroll
    for (int rr = 0; rr < 4; ++rr) av[rr] = aggL[(ng << 2) + rr][kk];
    float4 wR = *(const float4*)(whr + kk*HH + (cg << 2));
    float4 wI = *(const float4*)(whi + kk*HH + (cg << 2));
    float4 wH = *(const float4*)(whh + kk*HH + (cg << 2));
    #pragma unroll
    for (int rr = 0; rr < 4; ++rr){
      ar[rr][0] = fmaf(av[rr], wR.x, ar[rr][0]); ar[rr][1] = fmaf(av[rr], wR.y, ar[rr][1]);
      ar[rr][2] = fmaf(av[rr], wR.z, ar[rr][2]); ar[rr][3] = fmaf(av[rr], wR.w, ar[rr][3]);
      ai[rr][0] = fmaf(av[rr], wI.x, ai[rr][0]); ai[rr][1] = fmaf(av[rr], wI.y, ai[rr][1]);
      ai[rr][2] = fmaf(av[rr], wI.z, ai[rr][2]); ai[rr][3] = fmaf(av[rr], wI.w, ai[rr][3]);
      ah[rr][0] = fmaf(av[rr], wH.x, ah[rr][0]); ah[rr][1] = fmaf(av[rr], wH.y, ah[rr][1]);
      ah[rr][2] = fmaf(av[rr], wH.z, ah[rr][2]); ah[rr][3] = fmaf(av[rr], wH.w, ah[rr][3]);
    }
  }
  // gates + hidden update
  {
    float4 wr4[CC], wi4[CC], wn4[CC];
    #pragma unroll
    for (int c = 0; c < CC; ++c){
      wr4[c] = *(const float4*)(irw + c*HH + (cg << 2));
      wi4[c] = *(const float4*)(iiw + c*HH + (cg << 2));
      wn4[c] = *(const float4*)(inw + c*HH + (cg << 2));
    }
    float4 rb = *(const float4*)(irb + (cg << 2));
    float4 ib = *(const float4*)(iib + (cg << 2));
    float4 nb = *(const float4*)(inb + (cg << 2));
    #pragma unroll
    for (int rr = 0; rr < 4; ++rr){
      int row = (ng << 2) + rr;
      int node = n0 + row;
      int nodec = node > NN-1 ? NN-1 : node;
      float xv[CC];
      #pragma unroll
      for (int c = 0; c < CC; ++c) xv[c] = xLs[row][c];
      #pragma unroll
      for (int cc = 0; cc < 4; ++cc){
        int col = (cg << 2) + cc;
        float xr = ((const float*)&rb)[cc], xi = ((const float*)&ib)[cc], xn = ((const float*)&nb)[cc];
        #pragma unroll
        for (int c = 0; c < CC; ++c){
          xr = fmaf(xv[c], ((const float*)&wr4[c])[cc], xr);
          xi = fmaf(xv[c], ((const float*)&wi4[c])[cc], xi);
          xn = fmaf(xv[c], ((const float*)&wn4[c])[cc], xn);
        }
        float r = 1.f / (1.f + expf(-(xr + ar[rr][cc])));
        float i = 1.f / (1.f + expf(-(xi + ai[rr][cc])));
        float n = tanhf(xn + r * ah[rr][cc]);
        float hold = hid[(size_t)nodec*HH + col];
        float hnew = (1.f - i)*n + i*hold;
        if (node < NN) hid[(size_t)node*HH + col] = hnew;
        hNL[row][col] = hnew;
      }
    }
  }
  __syncthreads();

  // out1
  {
    float q[4][4] = {};
    for (int kk = 0; kk < HH; ++kk){
      float hv[4];
      #pragma unroll
      for (int rr = 0; rr < 4; ++rr) hv[rr] = hNL[(ng << 2) + rr][kk];
      float4 wv = *(const float4*)(o1w + kk*HH + (cg << 2));
      #pragma unroll
      for (int rr = 0; rr < 4; ++rr){
        q[rr][0] = fmaf(hv[rr], wv.x, q[rr][0]); q[rr][1] = fmaf(hv[rr], wv.y, q[rr][1]);
        q[rr][2] = fmaf(hv[rr], wv.z, q[rr][2]); q[rr][3] = fmaf(hv[rr], wv.w, q[rr][3]);
      }
    }
    float4 bb = *(const float4*)(o1b + (cg << 2));
    #pragma unroll
    for (int rr = 0; rr < 4; ++rr){
      p1L[(ng << 2) + rr][(cg << 2) + 0] = fmaxf(q[rr][0] + bb.x, 0.f);
      p1L[(ng << 2) + rr][(cg << 2) + 1] = fmaxf(q[rr][1] + bb.y, 0.f);
      p1L[(ng << 2) + rr][(cg << 2) + 2] = fmaxf(q[rr][2] + bb.z, 0.f);
      p1L[(ng << 2) + rr][(cg << 2) + 3] = fmaxf(q[rr][3] + bb.w, 0.f);
    }
  }
  __syncthreads();

  // out2
  {
    float q[4][4] = {};
    for (int kk = 0; kk < HH; ++kk){
      float hv[4];
      #pragma unroll
      for (int rr = 0; rr < 4; ++rr) hv[rr] = p1L[(ng << 2) + rr][kk];
      float4 wv = *(const float4*)(o2w + kk*HH + (cg << 2));
      #pragma unroll
      for (int rr = 0; rr < 4; ++rr){
        q[rr][0] = fmaf(hv[rr], wv.x, q[rr][0]); q[rr][1] = fmaf(hv[rr], wv.y, q[rr][1]);
        q[rr][2] = fmaf(hv[rr], wv.z, q[rr][2]); q[rr][3] = fmaf(hv[rr], wv.w, q[rr][3]);
      }
    }
    float4 bb = *(const float4*)(o2b + (cg << 2));
    #pragma unroll
    for (int rr = 0; rr < 4; ++rr){
      p2L[(ng << 2) + rr][(cg << 2) + 0] = fmaxf(q[rr][0] + bb.x, 0.f);
      p2L[(ng << 2) + rr][(cg << 2) + 1] = fmaxf(q[rr][1] + bb.y, 0.f);
      p2L[(ng << 2) + rr][(cg << 2) + 2] = fmaxf(q[rr][2] + bb.z, 0.f);
      p2L[(ng << 2) + rr][(cg << 2) + 3] = fmaxf(q[rr][3] + bb.w, 0.f);
    }
  }
  __syncthreads();

  // out3: H -> 4, then pred = x + relu(...)
  if (tid < 128){
    int r = tid >> 2, c = tid & 3;
    int node = n0 + r;
    if (node < NN){
      float s = o3b[c];
      for (int kk = 0; kk < HH; ++kk) s = fmaf(p2L[r][kk], o3w[kk*CC + c], s);
      float v = fmaxf(s, 0.f);
      out[((size_t)t*NN + node)*CC + c] = xLs[r][c] + v;
    }
  }
}

extern "C" void kernel_launch(void* const* d_in, const int* in_sizes, int n_in,
                              void* d_out, int out_size, void* d_ws, size_t ws_size,
                              hipStream_t stream){
  const float* inputs = (const float*)d_in[0];
  const float* fc1w = (const float*)d_in[1];
  const float* fc1b = (const float*)d_in[2];
  const float* fc2w = (const float*)d_in[3];
  const float* fc2b = (const float*)d_in[4];
  const float* whr  = (const float*)d_in[5];
  const float* whi  = (const float*)d_in[6];
  const float* whh  = (const float*)d_in[7];
  const float* irw  = (const float*)d_in[8];
  const float* irb  = (const float*)d_in[9];
  const float* iiw  = (const float*)d_in[10];
  const float* iib  = (const float*)d_in[11];
  const float* inw  = (const float*)d_in[12];
  const float* inb  = (const float*)d_in[13];
  const float* o1w  = (const float*)d_in[14];
  const float* o1b  = (const float*)d_in[15];
  const float* o2w  = (const float*)d_in[16];
  const float* o2b  = (const float*)d_in[17];
  const float* o3w  = (const float*)d_in[18];
  const float* o3b  = (const float*)d_in[19];
  const int* edge   = (const int*)d_in[20];
  const int* burn   = (const int*)d_in[21];
  float* out = (float*)d_out;

  u8* ws = (u8*)d_ws;
  float* hid = (float*)(ws);               // N*H fp32 = 5,120,000 B
  float* agg = (float*)(ws + 5120000);     // N*H fp32 = 5,120,000 B
  float* UV  = (float*)(ws + 10240000);    // 6*N*H fp32 = 30,720,000 B

  hipMemsetAsync(hid, 0, 5120000, stream);

  const int nblk = (NN + 31) / 32;  // 313
  for (int t = 0; t < TT; ++t){
    hipMemsetAsync(agg, 0, 5120000, stream);
    hipLaunchKernelGGL(uv_kernel, dim3(nblk, 6), dim3(256), 0, stream, hid, fc1w, UV);
    hipLaunchKernelGGL(edge_kernel, dim3(EE/64), dim3(256), 0, stream,
                       edge, UV, fc1b, fc2b, fc2w, agg);
    hipLaunchKernelGGL(node_kernel, dim3(nblk), dim3(256), 0, stream,
                       inputs + (size_t)t*NN*CC, out + (size_t)(t > 0 ? t-1 : 0)*NN*CC, burn, t,
                       agg, hid, whr, whi, whh, irw, irb, iiw, iib, inw, inb,
                       o1w, o1b, o2w, o2b, o3w, o3b, out);
  }
}

// Round 8
// 2513.450 us; speedup vs baseline: 2.1452x; 2.1452x over previous
//
#include <hip/hip_runtime.h>

#define TT 10
#define NN 10000
#define CC 4
#define HH 128
#define EE 160000

typedef unsigned char u8;
typedef unsigned short u16;
typedef unsigned int u32;
typedef __attribute__((ext_vector_type(8))) short bf16x8;
typedef __attribute__((ext_vector_type(4))) float f32x4;

__device__ __forceinline__ u16 f2b(float x){ // f32 -> bf16 RNE
  union { float f; u32 u; } v; v.f = x;
  return (u16)((v.u + 0x7fffu + ((v.u >> 16) & 1u)) >> 16);
}
__device__ __forceinline__ float b2f(u16 b){
  union { u32 u; float f; } v; v.u = ((u32)b) << 16;
  return v.f;
}
__device__ __forceinline__ f32x4 zero4(){ f32x4 z = {0.f,0.f,0.f,0.f}; return z; }
__device__ __forceinline__ f32x4 mfmab(bf16x8 a, bf16x8 b, f32x4 c){
  return __builtin_amdgcn_mfma_f32_16x16x32_bf16(a, b, c, 0, 0, 0);
}
// A-fragment read from XOR-swizzled LDS tile (rows of 128 u16 = 16 slots of 16B)
__device__ __forceinline__ bf16x8 ldA(const u16* L, int row, int sl){
  return *(const bf16x8*)(L + (row << 7) + ((sl ^ (row & 7)) << 3));
}
__device__ __forceinline__ bf16x8 ldB(const u16* packs, int frag, int lane){
  return *(const bf16x8*)(packs + frag*512 + lane*8);
}

// ---------------- W2 -> split-bf16 MFMA B-fragments.
// frag f<96: hi; f>=96: lo residual. g = f%96: br = g>>5, kt = (g&31)>>3, ct = g&7.
// lane l elem j holds W2[br][kt*32 + (l>>4)*8 + j][ct*16 + (l&15)].
__global__ void pack_w2(const float* __restrict__ fc2w, u16* __restrict__ dst){
  int f = blockIdx.x, l = threadIdx.x;
  int lo = f >= 96;
  int g = lo ? f - 96 : f;
  int br = g >> 5, rem = g & 31, kt = rem >> 3, ct = rem & 7;
  int col = (ct << 4) + (l & 15);
  const float* __restrict__ src = fc2w + (size_t)br*HH*HH;
  u16* d = dst + f*512 + l*8;
  #pragma unroll
  for (int j = 0; j < 8; ++j){
    int kk = (kt << 5) + ((l >> 4) << 3) + j;
    float v = src[kk*HH + col];
    u16 h = f2b(v);
    d[j] = lo ? f2b(v - b2f(h)) : h;
  }
}

// ---------------- U/V precompute: U[m=k*2+half][n][:] = h[n] @ W1[k][half*128:+128][:]
__global__ __launch_bounds__(256)
void uv_kernel(const float* __restrict__ hid, const float* __restrict__ fc1w,
               float* __restrict__ UV){
  __shared__ float hL[32][136];
  const int tid = threadIdx.x;
  const int n0 = blockIdx.x << 5;
  const int m = blockIdx.y;
  const float* __restrict__ W = fc1w + (size_t)m * (HH*HH);

  #pragma unroll
  for (int it = 0; it < 4; ++it){
    int s = tid + (it << 8);
    int r = s >> 5, c4 = s & 31;
    int node = n0 + r; if (node > NN-1) node = NN-1;
    float4 v = *(const float4*)(hid + (size_t)node*HH + (c4 << 2));
    *(float4*)(&hL[r][c4 << 2]) = v;
  }
  __syncthreads();

  const int rg = tid >> 5, cg = tid & 31;
  float acc[4][4] = {};
  for (int kk = 0; kk < HH; ++kk){
    float hv[4];
    #pragma unroll
    for (int rr = 0; rr < 4; ++rr) hv[rr] = hL[(rg << 2) + rr][kk];
    float4 wv = *(const float4*)(W + kk*HH + (cg << 2));
    #pragma unroll
    for (int rr = 0; rr < 4; ++rr){
      acc[rr][0] = fmaf(hv[rr], wv.x, acc[rr][0]);
      acc[rr][1] = fmaf(hv[rr], wv.y, acc[rr][1]);
      acc[rr][2] = fmaf(hv[rr], wv.z, acc[rr][2]);
      acc[rr][3] = fmaf(hv[rr], wv.w, acc[rr][3]);
    }
  }
  #pragma unroll
  for (int rr = 0; rr < 4; ++rr){
    int node = n0 + (rg << 2) + rr;
    if (node < NN){
      float4 o = { acc[rr][0], acc[rr][1], acc[rr][2], acc[rr][3] };
      *(float4*)(UV + ((size_t)m*NN + node)*HH + (cg << 2)) = o;
    }
  }
}

// ---------------- Edge kernel: 32 edges/block, layer-2 via split-bf16 MFMA.
// m1 = tanh(U[k][row]+V[k][col]+b1) -> bf16 hi/lo in swizzled LDS;
// lacc = m1hi@W2hi + m1lo@W2hi + m1hi@W2lo (f32 acc); msg += tanhf(lacc+b2); scatter.
__global__ __launch_bounds__(256)
void edge_kernel(const int* __restrict__ edge, const float* __restrict__ UV,
                 const float* __restrict__ b1, const float* __restrict__ b2,
                 const u16* __restrict__ packs, float* __restrict__ agg){
  __shared__ __align__(16) u16 m1hi[32*128];
  __shared__ __align__(16) u16 m1lo[32*128];
  __shared__ int er[32], ec[32];
  const int tid = threadIdx.x;
  const int lane = tid & 63, wid = tid >> 6;
  const int e0 = blockIdx.x << 5;

  if (tid < 32) er[tid] = edge[e0 + tid];
  else if (tid < 64) ec[tid - 32] = edge[EE + e0 + tid - 32];

  const int c4 = tid & 31;          // staging float4-col group (invariant)
  const int cOff = c4 << 2;
  const int ct0 = wid << 1;
  const int r0 = lane & 15, r1 = r0 + 16, kg = lane >> 4;

  f32x4 acc[2][2];
  acc[0][0]=zero4(); acc[0][1]=zero4(); acc[1][0]=zero4(); acc[1][1]=zero4();

  for (int k = 0; k < 3; ++k){
    __syncthreads();               // indices ready (k=0) / previous MFMA reads done
    // stage m1 branch k: tanh + split-bf16 pack into swizzled LDS
    {
      float4 b = *(const float4*)(b1 + k*HH + cOff);
      const float* __restrict__ Ub = UV + (size_t)(2*k)*NN*HH;
      const float* __restrict__ Vb = UV + (size_t)(2*k + 1)*NN*HH;
      #pragma unroll
      for (int it = 0; it < 4; ++it){
        int e = (tid >> 5) + (it << 3);
        float4 u = *(const float4*)(Ub + (size_t)er[e]*HH + cOff);
        float4 v = *(const float4*)(Vb + (size_t)ec[e]*HH + cOff);
        float m0 = tanhf(u.x + v.x + b.x);
        float m1 = tanhf(u.y + v.y + b.y);
        float m2 = tanhf(u.z + v.z + b.z);
        float m3 = tanhf(u.w + v.w + b.w);
        ushort4 hi, lo;
        hi.x = f2b(m0); lo.x = f2b(m0 - b2f(hi.x));
        hi.y = f2b(m1); lo.y = f2b(m1 - b2f(hi.y));
        hi.z = f2b(m2); lo.z = f2b(m2 - b2f(hi.z));
        hi.w = f2b(m3); lo.w = f2b(m3 - b2f(hi.w));
        int idx = (e << 7) + (((c4 >> 1) ^ (e & 7)) << 3) + ((c4 & 1) << 2);
        *(ushort4*)(m1hi + idx) = hi;
        *(ushort4*)(m1lo + idx) = lo;
      }
    }
    __syncthreads();

    f32x4 lacc[2][2];
    lacc[0][0]=zero4(); lacc[0][1]=zero4(); lacc[1][0]=zero4(); lacc[1][1]=zero4();
    #pragma unroll
    for (int kt = 0; kt < 4; ++kt){
      int sl = (kt << 2) + kg;
      bf16x8 a0h = ldA(m1hi, r0, sl);
      bf16x8 a1h = ldA(m1hi, r1, sl);
      bf16x8 a0l = ldA(m1lo, r0, sl);
      bf16x8 a1l = ldA(m1lo, r1, sl);
      #pragma unroll
      for (int ctl = 0; ctl < 2; ++ctl){
        int fh = k*32 + (kt << 3) + ct0 + ctl;
        bf16x8 bh = ldB(packs, fh, lane);
        bf16x8 bl = ldB(packs, fh + 96, lane);
        lacc[0][ctl] = mfmab(a0h, bh, lacc[0][ctl]);
        lacc[0][ctl] = mfmab(a0l, bh, lacc[0][ctl]);
        lacc[0][ctl] = mfmab(a0h, bl, lacc[0][ctl]);
        lacc[1][ctl] = mfmab(a1h, bh, lacc[1][ctl]);
        lacc[1][ctl] = mfmab(a1l, bh, lacc[1][ctl]);
        lacc[1][ctl] = mfmab(a1h, bl, lacc[1][ctl]);
      }
    }
    #pragma unroll
    for (int ctl = 0; ctl < 2; ++ctl){
      int col = ((ct0 + ctl) << 4) + r0;
      float bb = b2[k*HH + col];
      #pragma unroll
      for (int rt = 0; rt < 2; ++rt)
        #pragma unroll
        for (int j = 0; j < 4; ++j)
          acc[rt][ctl][j] += tanhf(lacc[rt][ctl][j] + bb);
    }
  }

  // scatter-add into receiver nodes; C/D map: row = rt*16 + kg*4 + j, col = ct*16 + (lane&15)
  #pragma unroll
  for (int rt = 0; rt < 2; ++rt)
    #pragma unroll
    for (int j = 0; j < 4; ++j){
      int row = (rt << 4) + (kg << 2) + j;
      int node = ec[row];
      #pragma unroll
      for (int ctl = 0; ctl < 2; ++ctl){
        int col = ((ct0 + ctl) << 4) + r0;
        atomicAdd(agg + (size_t)node*HH + col, acc[rt][ctl][j]);
      }
    }
}

// ---------------- Node kernel: GRU gates + 3-layer output MLP + prediction.
__global__ __launch_bounds__(256)
void node_kernel(const float* __restrict__ xin, const float* __restrict__ prevpred,
                 const int* __restrict__ burn, int t,
                 const float* __restrict__ agg, float* __restrict__ hid,
                 const float* __restrict__ whr, const float* __restrict__ whi, const float* __restrict__ whh,
                 const float* __restrict__ irw, const float* __restrict__ irb,
                 const float* __restrict__ iiw, const float* __restrict__ iib,
                 const float* __restrict__ inw, const float* __restrict__ inb,
                 const float* __restrict__ o1w, const float* __restrict__ o1b,
                 const float* __restrict__ o2w, const float* __restrict__ o2b,
                 const float* __restrict__ o3w, const float* __restrict__ o3b,
                 float* __restrict__ out){
  __shared__ float aggL[32][136];
  __shared__ float hNL[32][136];
  __shared__ float p1L[32][136];
  __shared__ float p2L[32][136];
  __shared__ float xLs[32][4];
  const int tid = threadIdx.x;
  const int n0 = blockIdx.x << 5;
  const float* __restrict__ xs = (t == 0 || t < burn[0]) ? xin : prevpred;

  #pragma unroll
  for (int it = 0; it < 4; ++it){
    int s = tid + (it << 8);
    int r = s >> 5, c4 = s & 31;
    int node = n0 + r; if (node > NN-1) node = NN-1;
    float4 v = *(const float4*)(agg + (size_t)node*HH + (c4 << 2));
    *(float4*)(&aggL[r][c4 << 2]) = v;
  }
  if (tid < 128){
    int r = tid >> 2, c = tid & 3;
    int node = n0 + r; if (node > NN-1) node = NN-1;
    xLs[r][c] = xs[(size_t)node*CC + c];
  }
  __syncthreads();

  const int ng = tid >> 5, cg = tid & 31;
  float ar[4][4] = {}, ai[4][4] = {}, ah[4][4] = {};
  for (int kk = 0; kk < HH; ++kk){
    float av[4];
    #pragma unroll
    for (int rr = 0; rr < 4; ++rr) av[rr] = aggL[(ng << 2) + rr][kk];
    float4 wR = *(const float4*)(whr + kk*HH + (cg << 2));
    float4 wI = *(const float4*)(whi + kk*HH + (cg << 2));
    float4 wH = *(const float4*)(whh + kk*HH + (cg << 2));
    #pragma unroll
    for (int rr = 0; rr < 4; ++rr){
      ar[rr][0] = fmaf(av[rr], wR.x, ar[rr][0]); ar[rr][1] = fmaf(av[rr], wR.y, ar[rr][1]);
      ar[rr][2] = fmaf(av[rr], wR.z, ar[rr][2]); ar[rr][3] = fmaf(av[rr], wR.w, ar[rr][3]);
      ai[rr][0] = fmaf(av[rr], wI.x, ai[rr][0]); ai[rr][1] = fmaf(av[rr], wI.y, ai[rr][1]);
      ai[rr][2] = fmaf(av[rr], wI.z, ai[rr][2]); ai[rr][3] = fmaf(av[rr], wI.w, ai[rr][3]);
      ah[rr][0] = fmaf(av[rr], wH.x, ah[rr][0]); ah[rr][1] = fmaf(av[rr], wH.y, ah[rr][1]);
      ah[rr][2] = fmaf(av[rr], wH.z, ah[rr][2]); ah[rr][3] = fmaf(av[rr], wH.w, ah[rr][3]);
    }
  }
  {
    float4 wr4[CC], wi4[CC], wn4[CC];
    #pragma unroll
    for (int c = 0; c < CC; ++c){
      wr4[c] = *(const float4*)(irw + c*HH + (cg << 2));
      wi4[c] = *(const float4*)(iiw + c*HH + (cg << 2));
      wn4[c] = *(const float4*)(inw + c*HH + (cg << 2));
    }
    float4 rb = *(const float4*)(irb + (cg << 2));
    float4 ib = *(const float4*)(iib + (cg << 2));
    float4 nb = *(const float4*)(inb + (cg << 2));
    #pragma unroll
    for (int rr = 0; rr < 4; ++rr){
      int row = (ng << 2) + rr;
      int node = n0 + row;
      int nodec = node > NN-1 ? NN-1 : node;
      float xv[CC];
      #pragma unroll
      for (int c = 0; c < CC; ++c) xv[c] = xLs[row][c];
      #pragma unroll
      for (int cc = 0; cc < 4; ++cc){
        int col = (cg << 2) + cc;
        float xr = ((const float*)&rb)[cc], xi = ((const float*)&ib)[cc], xn = ((const float*)&nb)[cc];
        #pragma unroll
        for (int c = 0; c < CC; ++c){
          xr = fmaf(xv[c], ((const float*)&wr4[c])[cc], xr);
          xi = fmaf(xv[c], ((const float*)&wi4[c])[cc], xi);
          xn = fmaf(xv[c], ((const float*)&wn4[c])[cc], xn);
        }
        float r = 1.f / (1.f + expf(-(xr + ar[rr][cc])));
        float i = 1.f / (1.f + expf(-(xi + ai[rr][cc])));
        float n = tanhf(xn + r * ah[rr][cc]);
        float hold = hid[(size_t)nodec*HH + col];
        float hnew = (1.f - i)*n + i*hold;
        if (node < NN) hid[(size_t)node*HH + col] = hnew;
        hNL[row][col] = hnew;
      }
    }
  }
  __syncthreads();

  {
    float q[4][4] = {};
    for (int kk = 0; kk < HH; ++kk){
      float hv[4];
      #pragma unroll
      for (int rr = 0; rr < 4; ++rr) hv[rr] = hNL[(ng << 2) + rr][kk];
      float4 wv = *(const float4*)(o1w + kk*HH + (cg << 2));
      #pragma unroll
      for (int rr = 0; rr < 4; ++rr){
        q[rr][0] = fmaf(hv[rr], wv.x, q[rr][0]); q[rr][1] = fmaf(hv[rr], wv.y, q[rr][1]);
        q[rr][2] = fmaf(hv[rr], wv.z, q[rr][2]); q[rr][3] = fmaf(hv[rr], wv.w, q[rr][3]);
      }
    }
    float4 bb = *(const float4*)(o1b + (cg << 2));
    #pragma unroll
    for (int rr = 0; rr < 4; ++rr){
      p1L[(ng << 2) + rr][(cg << 2) + 0] = fmaxf(q[rr][0] + bb.x, 0.f);
      p1L[(ng << 2) + rr][(cg << 2) + 1] = fmaxf(q[rr][1] + bb.y, 0.f);
      p1L[(ng << 2) + rr][(cg << 2) + 2] = fmaxf(q[rr][2] + bb.z, 0.f);
      p1L[(ng << 2) + rr][(cg << 2) + 3] = fmaxf(q[rr][3] + bb.w, 0.f);
    }
  }
  __syncthreads();

  {
    float q[4][4] = {};
    for (int kk = 0; kk < HH; ++kk){
      float hv[4];
      #pragma unroll
      for (int rr = 0; rr < 4; ++rr) hv[rr] = p1L[(ng << 2) + rr][kk];
      float4 wv = *(const float4*)(o2w + kk*HH + (cg << 2));
      #pragma unroll
      for (int rr = 0; rr < 4; ++rr){
        q[rr][0] = fmaf(hv[rr], wv.x, q[rr][0]); q[rr][1] = fmaf(hv[rr], wv.y, q[rr][1]);
        q[rr][2] = fmaf(hv[rr], wv.z, q[rr][2]); q[rr][3] = fmaf(hv[rr], wv.w, q[rr][3]);
      }
    }
    float4 bb = *(const float4*)(o2b + (cg << 2));
    #pragma unroll
    for (int rr = 0; rr < 4; ++rr){
      p2L[(ng << 2) + rr][(cg << 2) + 0] = fmaxf(q[rr][0] + bb.x, 0.f);
      p2L[(ng << 2) + rr][(cg << 2) + 1] = fmaxf(q[rr][1] + bb.y, 0.f);
      p2L[(ng << 2) + rr][(cg << 2) + 2] = fmaxf(q[rr][2] + bb.z, 0.f);
      p2L[(ng << 2) + rr][(cg << 2) + 3] = fmaxf(q[rr][3] + bb.w, 0.f);
    }
  }
  __syncthreads();

  if (tid < 128){
    int r = tid >> 2, c = tid & 3;
    int node = n0 + r;
    if (node < NN){
      float s = o3b[c];
      for (int kk = 0; kk < HH; ++kk) s = fmaf(p2L[r][kk], o3w[kk*CC + c], s);
      float v = fmaxf(s, 0.f);
      out[((size_t)t*NN + node)*CC + c] = xLs[r][c] + v;
    }
  }
}

extern "C" void kernel_launch(void* const* d_in, const int* in_sizes, int n_in,
                              void* d_out, int out_size, void* d_ws, size_t ws_size,
                              hipStream_t stream){
  const float* inputs = (const float*)d_in[0];
  const float* fc1w = (const float*)d_in[1];
  const float* fc1b = (const float*)d_in[2];
  const float* fc2w = (const float*)d_in[3];
  const float* fc2b = (const float*)d_in[4];
  const float* whr  = (const float*)d_in[5];
  const float* whi  = (const float*)d_in[6];
  const float* whh  = (const float*)d_in[7];
  const float* irw  = (const float*)d_in[8];
  const float* irb  = (const float*)d_in[9];
  const float* iiw  = (const float*)d_in[10];
  const float* iib  = (const float*)d_in[11];
  const float* inw  = (const float*)d_in[12];
  const float* inb  = (const float*)d_in[13];
  const float* o1w  = (const float*)d_in[14];
  const float* o1b  = (const float*)d_in[15];
  const float* o2w  = (const float*)d_in[16];
  const float* o2b  = (const float*)d_in[17];
  const float* o3w  = (const float*)d_in[18];
  const float* o3b  = (const float*)d_in[19];
  const int* edge   = (const int*)d_in[20];
  const int* burn   = (const int*)d_in[21];
  float* out = (float*)d_out;

  u8* ws = (u8*)d_ws;
  float* hid   = (float*)(ws);               // N*H fp32 = 5,120,000 B
  float* agg   = (float*)(ws + 5120000);     // N*H fp32 = 5,120,000 B
  float* UV    = (float*)(ws + 10240000);    // 6*N*H fp32 = 30,720,000 B
  u16*   packs = (u16*)(ws + 40960000);      // 192 frags * 1KB = 196,608 B

  hipMemsetAsync(hid, 0, 5120000, stream);
  hipLaunchKernelGGL(pack_w2, dim3(192), dim3(64), 0, stream, fc2w, packs);

  const int nblk = (NN + 31) / 32;  // 313
  for (int t = 0; t < TT; ++t){
    hipMemsetAsync(agg, 0, 5120000, stream);
    hipLaunchKernelGGL(uv_kernel, dim3(nblk, 6), dim3(256), 0, stream, hid, fc1w, UV);
    hipLaunchKernelGGL(edge_kernel, dim3(EE/32), dim3(256), 0, stream,
                       edge, UV, fc1b, fc2b, packs, agg);
    hipLaunchKernelGGL(node_kernel, dim3(nblk), dim3(256), 0, stream,
                       inputs + (size_t)t*NN*CC, out + (size_t)(t > 0 ? t-1 : 0)*NN*CC, burn, t,
                       agg, hid, whr, whi, whh, irw, irb, iiw, iib, inw, inb,
                       o1w, o1b, o2w, o2b, o3w, o3b, out);
  }
}

// Round 9
// 2287.869 us; speedup vs baseline: 2.3567x; 1.0986x over previous
//
#include <hip/hip_runtime.h>

#define TT 10
#define NN 10000
#define CC 4
#define HH 128
#define EE 160000

typedef unsigned char u8;
typedef unsigned short u16;
typedef unsigned int u32;
typedef __attribute__((ext_vector_type(8))) short bf16x8;
typedef __attribute__((ext_vector_type(4))) float f32x4;

__device__ __forceinline__ u16 f2b(float x){ // f32 -> bf16 RNE
  union { float f; u32 u; } v; v.f = x;
  return (u16)((v.u + 0x7fffu + ((v.u >> 16) & 1u)) >> 16);
}
__device__ __forceinline__ float b2f(u16 b){
  union { u32 u; float f; } v; v.u = ((u32)b) << 16;
  return v.f;
}
// HW-exp tanh: 1 - 2/(exp2(2x*log2e)+1); <=3e-7 rel err, correct saturation.
__device__ __forceinline__ float fast_tanh(float x){
  float e = __builtin_amdgcn_exp2f(x * 2.885390081777927f);
  return 1.f - 2.f * __builtin_amdgcn_rcpf(e + 1.f);
}
__device__ __forceinline__ f32x4 zero4(){ f32x4 z = {0.f,0.f,0.f,0.f}; return z; }
__device__ __forceinline__ f32x4 mfmab(bf16x8 a, bf16x8 b, f32x4 c){
  return __builtin_amdgcn_mfma_f32_16x16x32_bf16(a, b, c, 0, 0, 0);
}
// A-fragment read from XOR-swizzled LDS tile (rows of 128 u16 = 16 slots of 16B)
__device__ __forceinline__ bf16x8 ldA(const u16* L, int row, int sl){
  return *(const bf16x8*)(L + (row << 7) + ((sl ^ (row & 7)) << 3));
}
__device__ __forceinline__ bf16x8 ldB(const u16* packs, int frag, int lane){
  return *(const bf16x8*)(packs + frag*512 + lane*8);
}

// ---------------- W2 -> split-bf16 MFMA B-fragments.
// frag f<96: hi; f>=96: lo residual. g = f%96: br = g>>5, kt = (g&31)>>3, ct = g&7.
// lane l elem j holds W2[br][kt*32 + (l>>4)*8 + j][ct*16 + (l&15)].
__global__ void pack_w2(const float* __restrict__ fc2w, u16* __restrict__ dst){
  int f = blockIdx.x, l = threadIdx.x;
  int lo = f >= 96;
  int g = lo ? f - 96 : f;
  int br = g >> 5, rem = g & 31, kt = rem >> 3, ct = rem & 7;
  int col = (ct << 4) + (l & 15);
  const float* __restrict__ src = fc2w + (size_t)br*HH*HH;
  u16* d = dst + f*512 + l*8;
  #pragma unroll
  for (int j = 0; j < 8; ++j){
    int kk = (kt << 5) + ((l >> 4) << 3) + j;
    float v = src[kk*HH + col];
    u16 h = f2b(v);
    d[j] = lo ? f2b(v - b2f(h)) : h;
  }
}

// ---------------- U/V precompute: U[m=k*2+half][n][:] = h[n] @ W1[k][half*128:+128][:]
__global__ __launch_bounds__(256)
void uv_kernel(const float* __restrict__ hid, const float* __restrict__ fc1w,
               float* __restrict__ UV){
  __shared__ float hL[32][136];
  const int tid = threadIdx.x;
  const int n0 = blockIdx.x << 5;
  const int m = blockIdx.y;
  const float* __restrict__ W = fc1w + (size_t)m * (HH*HH);

  #pragma unroll
  for (int it = 0; it < 4; ++it){
    int s = tid + (it << 8);
    int r = s >> 5, c4 = s & 31;
    int node = n0 + r; if (node > NN-1) node = NN-1;
    float4 v = *(const float4*)(hid + (size_t)node*HH + (c4 << 2));
    *(float4*)(&hL[r][c4 << 2]) = v;
  }
  __syncthreads();

  const int rg = tid >> 5, cg = tid & 31;
  float acc[4][4] = {};
  for (int kk = 0; kk < HH; ++kk){
    float hv[4];
    #pragma unroll
    for (int rr = 0; rr < 4; ++rr) hv[rr] = hL[(rg << 2) + rr][kk];
    float4 wv = *(const float4*)(W + kk*HH + (cg << 2));
    #pragma unroll
    for (int rr = 0; rr < 4; ++rr){
      acc[rr][0] = fmaf(hv[rr], wv.x, acc[rr][0]);
      acc[rr][1] = fmaf(hv[rr], wv.y, acc[rr][1]);
      acc[rr][2] = fmaf(hv[rr], wv.z, acc[rr][2]);
      acc[rr][3] = fmaf(hv[rr], wv.w, acc[rr][3]);
    }
  }
  #pragma unroll
  for (int rr = 0; rr < 4; ++rr){
    int node = n0 + (rg << 2) + rr;
    if (node < NN){
      float4 o = { acc[rr][0], acc[rr][1], acc[rr][2], acc[rr][3] };
      *(float4*)(UV + ((size_t)m*NN + node)*HH + (cg << 2)) = o;
    }
  }
}

// ---------------- Edge kernel: 32 edges/block, layer-2 via split-bf16 MFMA.
// m1 = fast_tanh(U[k][row]+V[k][col]+b1) -> bf16 hi/lo in swizzled LDS;
// lacc = m1hi@W2hi + m1lo@W2hi + m1hi@W2lo (f32 acc); msg += fast_tanh(lacc+b2); scatter.
__global__ __launch_bounds__(256)
void edge_kernel(const int* __restrict__ edge, const float* __restrict__ UV,
                 const float* __restrict__ b1, const float* __restrict__ b2,
                 const u16* __restrict__ packs, float* __restrict__ agg){
  __shared__ __align__(16) u16 m1hi[32*128];
  __shared__ __align__(16) u16 m1lo[32*128];
  __shared__ int er[32], ec[32];
  const int tid = threadIdx.x;
  const int lane = tid & 63, wid = tid >> 6;
  const int e0 = blockIdx.x << 5;

  if (tid < 32) er[tid] = edge[e0 + tid];
  else if (tid < 64) ec[tid - 32] = edge[EE + e0 + tid - 32];

  const int c4 = tid & 31;          // staging float4-col group (invariant)
  const int cOff = c4 << 2;
  const int ct0 = wid << 1;
  const int r0 = lane & 15, r1 = r0 + 16, kg = lane >> 4;

  f32x4 acc[2][2];
  acc[0][0]=zero4(); acc[0][1]=zero4(); acc[1][0]=zero4(); acc[1][1]=zero4();

  for (int k = 0; k < 3; ++k){
    __syncthreads();               // indices ready (k=0) / previous MFMA reads done
    // stage m1 branch k: fast_tanh + split-bf16 pack into swizzled LDS
    {
      float4 b = *(const float4*)(b1 + k*HH + cOff);
      const float* __restrict__ Ub = UV + (size_t)(2*k)*NN*HH;
      const float* __restrict__ Vb = UV + (size_t)(2*k + 1)*NN*HH;
      #pragma unroll
      for (int it = 0; it < 4; ++it){
        int e = (tid >> 5) + (it << 3);
        float4 u = *(const float4*)(Ub + (size_t)er[e]*HH + cOff);
        float4 v = *(const float4*)(Vb + (size_t)ec[e]*HH + cOff);
        float m0 = fast_tanh(u.x + v.x + b.x);
        float m1 = fast_tanh(u.y + v.y + b.y);
        float m2 = fast_tanh(u.z + v.z + b.z);
        float m3 = fast_tanh(u.w + v.w + b.w);
        ushort4 hi, lo;
        hi.x = f2b(m0); lo.x = f2b(m0 - b2f(hi.x));
        hi.y = f2b(m1); lo.y = f2b(m1 - b2f(hi.y));
        hi.z = f2b(m2); lo.z = f2b(m2 - b2f(hi.z));
        hi.w = f2b(m3); lo.w = f2b(m3 - b2f(hi.w));
        int idx = (e << 7) + (((c4 >> 1) ^ (e & 7)) << 3) + ((c4 & 1) << 2);
        *(ushort4*)(m1hi + idx) = hi;
        *(ushort4*)(m1lo + idx) = lo;
      }
    }
    __syncthreads();

    f32x4 lacc[2][2];
    lacc[0][0]=zero4(); lacc[0][1]=zero4(); lacc[1][0]=zero4(); lacc[1][1]=zero4();
    #pragma unroll
    for (int kt = 0; kt < 4; ++kt){
      int sl = (kt << 2) + kg;
      bf16x8 a0h = ldA(m1hi, r0, sl);
      bf16x8 a1h = ldA(m1hi, r1, sl);
      bf16x8 a0l = ldA(m1lo, r0, sl);
      bf16x8 a1l = ldA(m1lo, r1, sl);
      #pragma unroll
      for (int ctl = 0; ctl < 2; ++ctl){
        int fh = k*32 + (kt << 3) + ct0 + ctl;
        bf16x8 bh = ldB(packs, fh, lane);
        bf16x8 bl = ldB(packs, fh + 96, lane);
        lacc[0][ctl] = mfmab(a0h, bh, lacc[0][ctl]);
        lacc[0][ctl] = mfmab(a0l, bh, lacc[0][ctl]);
        lacc[0][ctl] = mfmab(a0h, bl, lacc[0][ctl]);
        lacc[1][ctl] = mfmab(a1h, bh, lacc[1][ctl]);
        lacc[1][ctl] = mfmab(a1l, bh, lacc[1][ctl]);
        lacc[1][ctl] = mfmab(a1h, bl, lacc[1][ctl]);
      }
    }
    #pragma unroll
    for (int ctl = 0; ctl < 2; ++ctl){
      int col = ((ct0 + ctl) << 4) + r0;
      float bb = b2[k*HH + col];
      #pragma unroll
      for (int rt = 0; rt < 2; ++rt)
        #pragma unroll
        for (int j = 0; j < 4; ++j)
          acc[rt][ctl][j] += fast_tanh(lacc[rt][ctl][j] + bb);
    }
  }

  // scatter-add into receiver nodes; C/D map: row = rt*16 + kg*4 + j, col = ct*16 + (lane&15)
  #pragma unroll
  for (int rt = 0; rt < 2; ++rt)
    #pragma unroll
    for (int j = 0; j < 4; ++j){
      int row = (rt << 4) + (kg << 2) + j;
      int node = ec[row];
      #pragma unroll
      for (int ctl = 0; ctl < 2; ++ctl){
        int col = ((ct0 + ctl) << 4) + r0;
        atomicAdd(agg + (size_t)node*HH + col, acc[rt][ctl][j]);
      }
    }
}

// ---------------- Node kernel: GRU gates + 3-layer output MLP + prediction.
__global__ __launch_bounds__(256)
void node_kernel(const float* __restrict__ xin, const float* __restrict__ prevpred,
                 const int* __restrict__ burn, int t,
                 const float* __restrict__ agg, float* __restrict__ hid,
                 const float* __restrict__ whr, const float* __restrict__ whi, const float* __restrict__ whh,
                 const float* __restrict__ irw, const float* __restrict__ irb,
                 const float* __restrict__ iiw, const float* __restrict__ iib,
                 const float* __restrict__ inw, const float* __restrict__ inb,
                 const float* __restrict__ o1w, const float* __restrict__ o1b,
                 const float* __restrict__ o2w, const float* __restrict__ o2b,
                 const float* __restrict__ o3w, const float* __restrict__ o3b,
                 float* __restrict__ out){
  __shared__ float aggL[32][136];
  __shared__ float hNL[32][136];
  __shared__ float p1L[32][136];
  __shared__ float p2L[32][136];
  __shared__ float xLs[32][4];
  const int tid = threadIdx.x;
  const int n0 = blockIdx.x << 5;
  const float* __restrict__ xs = (t == 0 || t < burn[0]) ? xin : prevpred;

  #pragma unroll
  for (int it = 0; it < 4; ++it){
    int s = tid + (it << 8);
    int r = s >> 5, c4 = s & 31;
    int node = n0 + r; if (node > NN-1) node = NN-1;
    float4 v = *(const float4*)(agg + (size_t)node*HH + (c4 << 2));
    *(float4*)(&aggL[r][c4 << 2]) = v;
  }
  if (tid < 128){
    int r = tid >> 2, c = tid & 3;
    int node = n0 + r; if (node > NN-1) node = NN-1;
    xLs[r][c] = xs[(size_t)node*CC + c];
  }
  __syncthreads();

  const int ng = tid >> 5, cg = tid & 31;
  float ar[4][4] = {}, ai[4][4] = {}, ah[4][4] = {};
  for (int kk = 0; kk < HH; ++kk){
    float av[4];
    #pragma unroll
    for (int rr = 0; rr < 4; ++rr) av[rr] = aggL[(ng << 2) + rr][kk];
    float4 wR = *(const float4*)(whr + kk*HH + (cg << 2));
    float4 wI = *(const float4*)(whi + kk*HH + (cg << 2));
    float4 wH = *(const float4*)(whh + kk*HH + (cg << 2));
    #pragma unroll
    for (int rr = 0; rr < 4; ++rr){
      ar[rr][0] = fmaf(av[rr], wR.x, ar[rr][0]); ar[rr][1] = fmaf(av[rr], wR.y, ar[rr][1]);
      ar[rr][2] = fmaf(av[rr], wR.z, ar[rr][2]); ar[rr][3] = fmaf(av[rr], wR.w, ar[rr][3]);
      ai[rr][0] = fmaf(av[rr], wI.x, ai[rr][0]); ai[rr][1] = fmaf(av[rr], wI.y, ai[rr][1]);
      ai[rr][2] = fmaf(av[rr], wI.z, ai[rr][2]); ai[rr][3] = fmaf(av[rr], wI.w, ai[rr][3]);
      ah[rr][0] = fmaf(av[rr], wH.x, ah[rr][0]); ah[rr][1] = fmaf(av[rr], wH.y, ah[rr][1]);
      ah[rr][2] = fmaf(av[rr], wH.z, ah[rr][2]); ah[rr][3] = fmaf(av[rr], wH.w, ah[rr][3]);
    }
  }
  {
    float4 wr4[CC], wi4[CC], wn4[CC];
    #pragma unroll
    for (int c = 0; c < CC; ++c){
      wr4[c] = *(const float4*)(irw + c*HH + (cg << 2));
      wi4[c] = *(const float4*)(iiw + c*HH + (cg << 2));
      wn4[c] = *(const float4*)(inw + c*HH + (cg << 2));
    }
    float4 rb = *(const float4*)(irb + (cg << 2));
    float4 ib = *(const float4*)(iib + (cg << 2));
    float4 nb = *(const float4*)(inb + (cg << 2));
    #pragma unroll
    for (int rr = 0; rr < 4; ++rr){
      int row = (ng << 2) + rr;
      int node = n0 + row;
      int nodec = node > NN-1 ? NN-1 : node;
      float xv[CC];
      #pragma unroll
      for (int c = 0; c < CC; ++c) xv[c] = xLs[row][c];
      #pragma unroll
      for (int cc = 0; cc < 4; ++cc){
        int col = (cg << 2) + cc;
        float xr = ((const float*)&rb)[cc], xi = ((const float*)&ib)[cc], xn = ((const float*)&nb)[cc];
        #pragma unroll
        for (int c = 0; c < CC; ++c){
          xr = fmaf(xv[c], ((const float*)&wr4[c])[cc], xr);
          xi = fmaf(xv[c], ((const float*)&wi4[c])[cc], xi);
          xn = fmaf(xv[c], ((const float*)&wn4[c])[cc], xn);
        }
        float r = 1.f / (1.f + expf(-(xr + ar[rr][cc])));
        float i = 1.f / (1.f + expf(-(xi + ai[rr][cc])));
        float n = tanhf(xn + r * ah[rr][cc]);
        float hold = hid[(size_t)nodec*HH + col];
        float hnew = (1.f - i)*n + i*hold;
        if (node < NN) hid[(size_t)node*HH + col] = hnew;
        hNL[row][col] = hnew;
      }
    }
  }
  __syncthreads();

  {
    float q[4][4] = {};
    for (int kk = 0; kk < HH; ++kk){
      float hv[4];
      #pragma unroll
      for (int rr = 0; rr < 4; ++rr) hv[rr] = hNL[(ng << 2) + rr][kk];
      float4 wv = *(const float4*)(o1w + kk*HH + (cg << 2));
      #pragma unroll
      for (int rr = 0; rr < 4; ++rr){
        q[rr][0] = fmaf(hv[rr], wv.x, q[rr][0]); q[rr][1] = fmaf(hv[rr], wv.y, q[rr][1]);
        q[rr][2] = fmaf(hv[rr], wv.z, q[rr][2]); q[rr][3] = fmaf(hv[rr], wv.w, q[rr][3]);
      }
    }
    float4 bb = *(const float4*)(o1b + (cg << 2));
    #pragma unroll
    for (int rr = 0; rr < 4; ++rr){
      p1L[(ng << 2) + rr][(cg << 2) + 0] = fmaxf(q[rr][0] + bb.x, 0.f);
      p1L[(ng << 2) + rr][(cg << 2) + 1] = fmaxf(q[rr][1] + bb.y, 0.f);
      p1L[(ng << 2) + rr][(cg << 2) + 2] = fmaxf(q[rr][2] + bb.z, 0.f);
      p1L[(ng << 2) + rr][(cg << 2) + 3] = fmaxf(q[rr][3] + bb.w, 0.f);
    }
  }
  __syncthreads();

  {
    float q[4][4] = {};
    for (int kk = 0; kk < HH; ++kk){
      float hv[4];
      #pragma unroll
      for (int rr = 0; rr < 4; ++rr) hv[rr] = p1L[(ng << 2) + rr][kk];
      float4 wv = *(const float4*)(o2w + kk*HH + (cg << 2));
      #pragma unroll
      for (int rr = 0; rr < 4; ++rr){
        q[rr][0] = fmaf(hv[rr], wv.x, q[rr][0]); q[rr][1] = fmaf(hv[rr], wv.y, q[rr][1]);
        q[rr][2] = fmaf(hv[rr], wv.z, q[rr][2]); q[rr][3] = fmaf(hv[rr], wv.w, q[rr][3]);
      }
    }
    float4 bb = *(const float4*)(o2b + (cg << 2));
    #pragma unroll
    for (int rr = 0; rr < 4; ++rr){
      p2L[(ng << 2) + rr][(cg << 2) + 0] = fmaxf(q[rr][0] + bb.x, 0.f);
      p2L[(ng << 2) + rr][(cg << 2) + 1] = fmaxf(q[rr][1] + bb.y, 0.f);
      p2L[(ng << 2) + rr][(cg << 2) + 2] = fmaxf(q[rr][2] + bb.z, 0.f);
      p2L[(ng << 2) + rr][(cg << 2) + 3] = fmaxf(q[rr][3] + bb.w, 0.f);
    }
  }
  __syncthreads();

  if (tid < 128){
    int r = tid >> 2, c = tid & 3;
    int node = n0 + r;
    if (node < NN){
      float s = o3b[c];
      for (int kk = 0; kk < HH; ++kk) s = fmaf(p2L[r][kk], o3w[kk*CC + c], s);
      float v = fmaxf(s, 0.f);
      out[((size_t)t*NN + node)*CC + c] = xLs[r][c] + v;
    }
  }
}

extern "C" void kernel_launch(void* const* d_in, const int* in_sizes, int n_in,
                              void* d_out, int out_size, void* d_ws, size_t ws_size,
                              hipStream_t stream){
  const float* inputs = (const float*)d_in[0];
  const float* fc1w = (const float*)d_in[1];
  const float* fc1b = (const float*)d_in[2];
  const float* fc2w = (const float*)d_in[3];
  const float* fc2b = (const float*)d_in[4];
  const float* whr  = (const float*)d_in[5];
  const float* whi  = (const float*)d_in[6];
  const float* whh  = (const float*)d_in[7];
  const float* irw  = (const float*)d_in[8];
  const float* irb  = (const float*)d_in[9];
  const float* iiw  = (const float*)d_in[10];
  const float* iib  = (const float*)d_in[11];
  const float* inw  = (const float*)d_in[12];
  const float* inb  = (const float*)d_in[13];
  const float* o1w  = (const float*)d_in[14];
  const float* o1b  = (const float*)d_in[15];
  const float* o2w  = (const float*)d_in[16];
  const float* o2b  = (const float*)d_in[17];
  const float* o3w  = (const float*)d_in[18];
  const float* o3b  = (const float*)d_in[19];
  const int* edge   = (const int*)d_in[20];
  const int* burn   = (const int*)d_in[21];
  float* out = (float*)d_out;

  u8* ws = (u8*)d_ws;
  float* hid   = (float*)(ws);               // N*H fp32 = 5,120,000 B
  float* agg   = (float*)(ws + 5120000);     // N*H fp32 = 5,120,000 B
  float* UV    = (float*)(ws + 10240000);    // 6*N*H fp32 = 30,720,000 B
  u16*   packs = (u16*)(ws + 40960000);      // 192 frags * 1KB = 196,608 B

  hipMemsetAsync(hid, 0, 5120000, stream);
  hipLaunchKernelGGL(pack_w2, dim3(192), dim3(64), 0, stream, fc2w, packs);

  const int nblk = (NN + 31) / 32;  // 313
  for (int t = 0; t < TT; ++t){
    hipMemsetAsync(agg, 0, 5120000, stream);
    hipLaunchKernelGGL(uv_kernel, dim3(nblk, 6), dim3(256), 0, stream, hid, fc1w, UV);
    hipLaunchKernelGGL(edge_kernel, dim3(EE/32), dim3(256), 0, stream,
                       edge, UV, fc1b, fc2b, packs, agg);
    hipLaunchKernelGGL(node_kernel, dim3(nblk), dim3(256), 0, stream,
                       inputs + (size_t)t*NN*CC, out + (size_t)(t > 0 ? t-1 : 0)*NN*CC, burn, t,
                       agg, hid, whr, whi, whh, irw, irb, iiw, iib, inw, inb,
                       o1w, o1b, o2w, o2b, o3w, o3b, out);
  }
}

// Round 10
// 2013.639 us; speedup vs baseline: 2.6777x; 1.1362x over previous
//
#include <hip/hip_runtime.h>

#define TT 10
#define NN 10000
#define CC 4
#define HH 128
#define EE 160000

typedef unsigned char u8;
typedef unsigned short u16;
typedef unsigned int u32;
typedef __attribute__((ext_vector_type(8))) short bf16x8;
typedef __attribute__((ext_vector_type(4))) float f32x4;

// packed fragment regions (each frag = 64 lanes * 16B = 1KB)
#define FW2 0      // W2: 96 hi + 96 lo
#define FW1 192    // W1: 6 matrices * 3 comps * 32
#define FO  768    // O1 hi/lo (32+32), O2 hi/lo (32+32)
#define NFRAG 896

__device__ __forceinline__ u16 f2b(float x){ // f32 -> bf16 RNE
  union { float f; u32 u; } v; v.f = x;
  return (u16)((v.u + 0x7fffu + ((v.u >> 16) & 1u)) >> 16);
}
__device__ __forceinline__ float b2f(u16 b){
  union { u32 u; float f; } v; v.u = ((u32)b) << 16;
  return v.f;
}
// HW-exp tanh: 1 - 2/(exp2(2x*log2e)+1); <=3e-7 rel err, correct saturation.
__device__ __forceinline__ float fast_tanh(float x){
  float e = __builtin_amdgcn_exp2f(x * 2.885390081777927f);
  return 1.f - 2.f * __builtin_amdgcn_rcpf(e + 1.f);
}
__device__ __forceinline__ f32x4 zero4(){ f32x4 z = {0.f,0.f,0.f,0.f}; return z; }
__device__ __forceinline__ f32x4 mfmab(bf16x8 a, bf16x8 b, f32x4 c){
  return __builtin_amdgcn_mfma_f32_16x16x32_bf16(a, b, c, 0, 0, 0);
}
// A-fragment read from XOR-swizzled LDS tile (rows of 128 u16 = 16 slots of 16B)
__device__ __forceinline__ bf16x8 ldA(const u16* L, int row, int sl){
  return *(const bf16x8*)(L + (row << 7) + ((sl ^ (row & 7)) << 3));
}
__device__ __forceinline__ bf16x8 ldB(const u16* packs, int frag, int lane){
  return *(const bf16x8*)(packs + frag*512 + lane*8);
}

struct PSrc { const float* w2; const float* w1; const float* o1; const float* o2; };

// ---------------- All weights -> bf16-component MFMA B-fragments.
// lane l elem j holds B[kt*32 + (l>>4)*8 + j][ct*16 + (l&15)] (component comp).
__global__ void pack_weights(PSrc ps, u16* __restrict__ dst){
  int f = blockIdx.x, l = threadIdx.x;
  const float* src; int comp, kt, ct;
  if (f < 192){
    comp = f / 96; int g = f % 96;
    int br = g >> 5, rem = g & 31; kt = rem >> 3; ct = rem & 7;
    src = ps.w2 + (size_t)br*HH*HH;
  } else if (f < 768){
    int g = f - 192; int m = g / 96; int rem = g % 96;
    comp = rem >> 5; int idx = rem & 31; kt = idx >> 3; ct = idx & 7;
    src = ps.w1 + (size_t)m*HH*HH;
  } else {
    int g = f - 768; int mat = g >> 6; int rem = g & 63;
    comp = rem >> 5; int idx = rem & 31; kt = idx >> 3; ct = idx & 7;
    src = mat ? ps.o2 : ps.o1;
  }
  int col = (ct << 4) + (l & 15);
  u16* d = dst + f*512 + l*8;
  #pragma unroll
  for (int j = 0; j < 8; ++j){
    int kk = (kt << 5) + ((l >> 4) << 3) + j;
    float v = src[kk*HH + col];
    u16 c0 = f2b(v); float r = v - b2f(c0);
    u16 c1 = f2b(r); r -= b2f(c1);
    u16 c2 = f2b(r);
    d[j] = comp == 0 ? c0 : (comp == 1 ? c1 : c2);
  }
}

// ---------------- U/V precompute via MFMA, 3-component split (f32-faithful, ~2^-26).
// One block per 32 nodes; loops all 6 matrices m. U[m][node][:] = h[node] @ W1[m].
__global__ __launch_bounds__(256)
void uv_kernel(const float* __restrict__ hid, const u16* __restrict__ packs,
               float* __restrict__ UV){
  __shared__ __align__(16) u16 h0[32*128], h1[32*128], h2[32*128];
  const int tid = threadIdx.x;
  const int lane = tid & 63, wid = tid >> 6;
  const int n0 = blockIdx.x << 5;

  #pragma unroll
  for (int it = 0; it < 4; ++it){
    int s = tid + (it << 8);
    int r = s >> 5, c4 = s & 31;
    int node = n0 + r; if (node > NN-1) node = NN-1;
    float4 v = *(const float4*)(hid + (size_t)node*HH + (c4 << 2));
    ushort4 q0, q1, q2;
    const float* pv = (const float*)&v;
    u16* q0p = (u16*)&q0; u16* q1p = (u16*)&q1; u16* q2p = (u16*)&q2;
    #pragma unroll
    for (int e = 0; e < 4; ++e){
      float x = pv[e];
      u16 a0 = f2b(x); float rr = x - b2f(a0);
      u16 a1 = f2b(rr); rr -= b2f(a1);
      q0p[e] = a0; q1p[e] = a1; q2p[e] = f2b(rr);
    }
    int idx = (r << 7) + (((c4 >> 1) ^ (r & 7)) << 3) + ((c4 & 1) << 2);
    *(ushort4*)(h0 + idx) = q0;
    *(ushort4*)(h1 + idx) = q1;
    *(ushort4*)(h2 + idx) = q2;
  }
  __syncthreads();

  const int ct0 = wid << 1;
  const int r0 = lane & 15, r1 = r0 + 16, kg = lane >> 4;

  for (int m = 0; m < 6; ++m){
    f32x4 acc[2][2];
    acc[0][0]=zero4(); acc[0][1]=zero4(); acc[1][0]=zero4(); acc[1][1]=zero4();
    #pragma unroll
    for (int kt = 0; kt < 4; ++kt){
      int sl = (kt << 2) + kg;
      bf16x8 a00 = ldA(h0, r0, sl), a01 = ldA(h1, r0, sl), a02 = ldA(h2, r0, sl);
      bf16x8 a10 = ldA(h0, r1, sl), a11 = ldA(h1, r1, sl), a12 = ldA(h2, r1, sl);
      #pragma unroll
      for (int ctl = 0; ctl < 2; ++ctl){
        int fb = FW1 + m*96 + (kt << 3) + ct0 + ctl;
        bf16x8 b0 = ldB(packs, fb,      lane);
        bf16x8 b1 = ldB(packs, fb + 32, lane);
        bf16x8 b2 = ldB(packs, fb + 64, lane);
        acc[0][ctl] = mfmab(a00, b0, acc[0][ctl]);
        acc[0][ctl] = mfmab(a01, b0, acc[0][ctl]);
        acc[0][ctl] = mfmab(a00, b1, acc[0][ctl]);
        acc[0][ctl] = mfmab(a02, b0, acc[0][ctl]);
        acc[0][ctl] = mfmab(a01, b1, acc[0][ctl]);
        acc[0][ctl] = mfmab(a00, b2, acc[0][ctl]);
        acc[1][ctl] = mfmab(a10, b0, acc[1][ctl]);
        acc[1][ctl] = mfmab(a11, b0, acc[1][ctl]);
        acc[1][ctl] = mfmab(a10, b1, acc[1][ctl]);
        acc[1][ctl] = mfmab(a12, b0, acc[1][ctl]);
        acc[1][ctl] = mfmab(a11, b1, acc[1][ctl]);
        acc[1][ctl] = mfmab(a10, b2, acc[1][ctl]);
      }
    }
    #pragma unroll
    for (int ctl = 0; ctl < 2; ++ctl)
      #pragma unroll
      for (int rt = 0; rt < 2; ++rt)
        #pragma unroll
        for (int j = 0; j < 4; ++j){
          int row = (rt << 4) + (kg << 2) + j;
          int col = ((ct0 + ctl) << 4) + r0;
          int node = n0 + row;
          if (node < NN) UV[((size_t)m*NN + node)*HH + col] = acc[rt][ctl][j];
        }
  }
}

// ---------------- Edge kernel: 32 edges/block, layer-2 via split-bf16 MFMA. (unchanged)
__global__ __launch_bounds__(256)
void edge_kernel(const int* __restrict__ edge, const float* __restrict__ UV,
                 const float* __restrict__ b1, const float* __restrict__ b2,
                 const u16* __restrict__ packs, float* __restrict__ agg){
  __shared__ __align__(16) u16 m1hi[32*128];
  __shared__ __align__(16) u16 m1lo[32*128];
  __shared__ int er[32], ec[32];
  const int tid = threadIdx.x;
  const int lane = tid & 63, wid = tid >> 6;
  const int e0 = blockIdx.x << 5;

  if (tid < 32) er[tid] = edge[e0 + tid];
  else if (tid < 64) ec[tid - 32] = edge[EE + e0 + tid - 32];

  const int c4 = tid & 31;
  const int cOff = c4 << 2;
  const int ct0 = wid << 1;
  const int r0 = lane & 15, r1 = r0 + 16, kg = lane >> 4;

  f32x4 acc[2][2];
  acc[0][0]=zero4(); acc[0][1]=zero4(); acc[1][0]=zero4(); acc[1][1]=zero4();

  for (int k = 0; k < 3; ++k){
    __syncthreads();
    {
      float4 b = *(const float4*)(b1 + k*HH + cOff);
      const float* __restrict__ Ub = UV + (size_t)(2*k)*NN*HH;
      const float* __restrict__ Vb = UV + (size_t)(2*k + 1)*NN*HH;
      #pragma unroll
      for (int it = 0; it < 4; ++it){
        int e = (tid >> 5) + (it << 3);
        float4 u = *(const float4*)(Ub + (size_t)er[e]*HH + cOff);
        float4 v = *(const float4*)(Vb + (size_t)ec[e]*HH + cOff);
        float m0 = fast_tanh(u.x + v.x + b.x);
        float m1 = fast_tanh(u.y + v.y + b.y);
        float m2 = fast_tanh(u.z + v.z + b.z);
        float m3 = fast_tanh(u.w + v.w + b.w);
        ushort4 hi, lo;
        hi.x = f2b(m0); lo.x = f2b(m0 - b2f(hi.x));
        hi.y = f2b(m1); lo.y = f2b(m1 - b2f(hi.y));
        hi.z = f2b(m2); lo.z = f2b(m2 - b2f(hi.z));
        hi.w = f2b(m3); lo.w = f2b(m3 - b2f(hi.w));
        int idx = (e << 7) + (((c4 >> 1) ^ (e & 7)) << 3) + ((c4 & 1) << 2);
        *(ushort4*)(m1hi + idx) = hi;
        *(ushort4*)(m1lo + idx) = lo;
      }
    }
    __syncthreads();

    f32x4 lacc[2][2];
    lacc[0][0]=zero4(); lacc[0][1]=zero4(); lacc[1][0]=zero4(); lacc[1][1]=zero4();
    #pragma unroll
    for (int kt = 0; kt < 4; ++kt){
      int sl = (kt << 2) + kg;
      bf16x8 a0h = ldA(m1hi, r0, sl);
      bf16x8 a1h = ldA(m1hi, r1, sl);
      bf16x8 a0l = ldA(m1lo, r0, sl);
      bf16x8 a1l = ldA(m1lo, r1, sl);
      #pragma unroll
      for (int ctl = 0; ctl < 2; ++ctl){
        int fh = FW2 + k*32 + (kt << 3) + ct0 + ctl;
        bf16x8 bh = ldB(packs, fh, lane);
        bf16x8 bl = ldB(packs, fh + 96, lane);
        lacc[0][ctl] = mfmab(a0h, bh, lacc[0][ctl]);
        lacc[0][ctl] = mfmab(a0l, bh, lacc[0][ctl]);
        lacc[0][ctl] = mfmab(a0h, bl, lacc[0][ctl]);
        lacc[1][ctl] = mfmab(a1h, bh, lacc[1][ctl]);
        lacc[1][ctl] = mfmab(a1l, bh, lacc[1][ctl]);
        lacc[1][ctl] = mfmab(a1h, bl, lacc[1][ctl]);
      }
    }
    #pragma unroll
    for (int ctl = 0; ctl < 2; ++ctl){
      int col = ((ct0 + ctl) << 4) + r0;
      float bb = b2[k*HH + col];
      #pragma unroll
      for (int rt = 0; rt < 2; ++rt)
        #pragma unroll
        for (int j = 0; j < 4; ++j)
          acc[rt][ctl][j] += fast_tanh(lacc[rt][ctl][j] + bb);
    }
  }

  #pragma unroll
  for (int rt = 0; rt < 2; ++rt)
    #pragma unroll
    for (int j = 0; j < 4; ++j){
      int row = (rt << 4) + (kg << 2) + j;
      int node = ec[row];
      #pragma unroll
      for (int ctl = 0; ctl < 2; ++ctl){
        int col = ((ct0 + ctl) << 4) + r0;
        atomicAdd(agg + (size_t)node*HH + col, acc[rt][ctl][j]);
      }
    }
}

// ---------------- Node kernel: GRU gates (f32) + out1/out2 via split-bf16 MFMA + out3.
__global__ __launch_bounds__(256)
void node_kernel(const float* __restrict__ xin, const float* __restrict__ prevpred,
                 const int* __restrict__ burn, int t,
                 const float* __restrict__ agg, float* __restrict__ hid,
                 const float* __restrict__ whr, const float* __restrict__ whi, const float* __restrict__ whh,
                 const float* __restrict__ irw, const float* __restrict__ irb,
                 const float* __restrict__ iiw, const float* __restrict__ iib,
                 const float* __restrict__ inw, const float* __restrict__ inb,
                 const float* __restrict__ o1b, const float* __restrict__ o2b,
                 const float* __restrict__ o3w, const float* __restrict__ o3b,
                 const u16* __restrict__ packs, float* __restrict__ out){
  __shared__ float aggL[32][136];
  __shared__ __align__(16) u16 hHi[32*128], hLo[32*128];
  __shared__ __align__(16) u16 p1Hi[32*128], p1Lo[32*128];
  __shared__ float p2L[32][136];
  __shared__ float xLs[32][4];
  const int tid = threadIdx.x;
  const int n0 = blockIdx.x << 5;
  const float* __restrict__ xs = (t == 0 || t < burn[0]) ? xin : prevpred;

  #pragma unroll
  for (int it = 0; it < 4; ++it){
    int s = tid + (it << 8);
    int r = s >> 5, c4 = s & 31;
    int node = n0 + r; if (node > NN-1) node = NN-1;
    float4 v = *(const float4*)(agg + (size_t)node*HH + (c4 << 2));
    *(float4*)(&aggL[r][c4 << 2]) = v;
  }
  if (tid < 128){
    int r = tid >> 2, c = tid & 3;
    int node = n0 + r; if (node > NN-1) node = NN-1;
    xLs[r][c] = xs[(size_t)node*CC + c];
  }
  __syncthreads();

  const int ng = tid >> 5, cg = tid & 31;
  float ar[4][4] = {}, ai[4][4] = {}, ah[4][4] = {};
  for (int kk = 0; kk < HH; ++kk){
    float av[4];
    #pragma unroll
    for (int rr = 0; rr < 4; ++rr) av[rr] = aggL[(ng << 2) + rr][kk];
    float4 wR = *(const float4*)(whr + kk*HH + (cg << 2));
    float4 wI = *(const float4*)(whi + kk*HH + (cg << 2));
    float4 wH = *(const float4*)(whh + kk*HH + (cg << 2));
    #pragma unroll
    for (int rr = 0; rr < 4; ++rr){
      ar[rr][0] = fmaf(av[rr], wR.x, ar[rr][0]); ar[rr][1] = fmaf(av[rr], wR.y, ar[rr][1]);
      ar[rr][2] = fmaf(av[rr], wR.z, ar[rr][2]); ar[rr][3] = fmaf(av[rr], wR.w, ar[rr][3]);
      ai[rr][0] = fmaf(av[rr], wI.x, ai[rr][0]); ai[rr][1] = fmaf(av[rr], wI.y, ai[rr][1]);
      ai[rr][2] = fmaf(av[rr], wI.z, ai[rr][2]); ai[rr][3] = fmaf(av[rr], wI.w, ai[rr][3]);
      ah[rr][0] = fmaf(av[rr], wH.x, ah[rr][0]); ah[rr][1] = fmaf(av[rr], wH.y, ah[rr][1]);
      ah[rr][2] = fmaf(av[rr], wH.z, ah[rr][2]); ah[rr][3] = fmaf(av[rr], wH.w, ah[rr][3]);
    }
  }
  {
    float4 wr4[CC], wi4[CC], wn4[CC];
    #pragma unroll
    for (int c = 0; c < CC; ++c){
      wr4[c] = *(const float4*)(irw + c*HH + (cg << 2));
      wi4[c] = *(const float4*)(iiw + c*HH + (cg << 2));
      wn4[c] = *(const float4*)(inw + c*HH + (cg << 2));
    }
    float4 rb = *(const float4*)(irb + (cg << 2));
    float4 ib = *(const float4*)(iib + (cg << 2));
    float4 nb = *(const float4*)(inb + (cg << 2));
    #pragma unroll
    for (int rr = 0; rr < 4; ++rr){
      int row = (ng << 2) + rr;
      int node = n0 + row;
      int nodec = node > NN-1 ? NN-1 : node;
      float xv[CC];
      #pragma unroll
      for (int c = 0; c < CC; ++c) xv[c] = xLs[row][c];
      float hv4[4];
      #pragma unroll
      for (int cc = 0; cc < 4; ++cc){
        int col = (cg << 2) + cc;
        float xr = ((const float*)&rb)[cc], xi = ((const float*)&ib)[cc], xn = ((const float*)&nb)[cc];
        #pragma unroll
        for (int c = 0; c < CC; ++c){
          xr = fmaf(xv[c], ((const float*)&wr4[c])[cc], xr);
          xi = fmaf(xv[c], ((const float*)&wi4[c])[cc], xi);
          xn = fmaf(xv[c], ((const float*)&wn4[c])[cc], xn);
        }
        float r = 1.f / (1.f + expf(-(xr + ar[rr][cc])));
        float i = 1.f / (1.f + expf(-(xi + ai[rr][cc])));
        float n = tanhf(xn + r * ah[rr][cc]);
        float hold = hid[(size_t)nodec*HH + col];
        float hnew = (1.f - i)*n + i*hold;
        if (node < NN) hid[(size_t)node*HH + col] = hnew;
        hv4[cc] = hnew;
      }
      ushort4 hhi, hlo;
      u16* hp = (u16*)&hhi; u16* lp = (u16*)&hlo;
      #pragma unroll
      for (int cc = 0; cc < 4; ++cc){
        u16 a = f2b(hv4[cc]);
        hp[cc] = a; lp[cc] = f2b(hv4[cc] - b2f(a));
      }
      int idx = (row << 7) + (((cg >> 1) ^ (row & 7)) << 3) + ((cg & 1) << 2);
      *(ushort4*)(hHi + idx) = hhi;
      *(ushort4*)(hLo + idx) = hlo;
    }
  }
  __syncthreads();

  const int lane = tid & 63, wid = tid >> 6;
  const int ct0 = wid << 1;
  const int r0 = lane & 15, r1 = r0 + 16, kg = lane >> 4;

  // out1: relu(h @ O1 + b1) via 3-term split MFMA -> p1 hi/lo
  {
    f32x4 q[2][2];
    q[0][0]=zero4(); q[0][1]=zero4(); q[1][0]=zero4(); q[1][1]=zero4();
    #pragma unroll
    for (int kt = 0; kt < 4; ++kt){
      int sl = (kt << 2) + kg;
      bf16x8 ah0 = ldA(hHi, r0, sl), al0 = ldA(hLo, r0, sl);
      bf16x8 ah1 = ldA(hHi, r1, sl), al1 = ldA(hLo, r1, sl);
      #pragma unroll
      for (int ctl = 0; ctl < 2; ++ctl){
        int fo = FO + (kt << 3) + ct0 + ctl;
        bf16x8 bh = ldB(packs, fo, lane);
        bf16x8 bl = ldB(packs, fo + 32, lane);
        q[0][ctl] = mfmab(ah0, bh, q[0][ctl]);
        q[0][ctl] = mfmab(al0, bh, q[0][ctl]);
        q[0][ctl] = mfmab(ah0, bl, q[0][ctl]);
        q[1][ctl] = mfmab(ah1, bh, q[1][ctl]);
        q[1][ctl] = mfmab(al1, bh, q[1][ctl]);
        q[1][ctl] = mfmab(ah1, bl, q[1][ctl]);
      }
    }
    #pragma unroll
    for (int ctl = 0; ctl < 2; ++ctl){
      int col = ((ct0 + ctl) << 4) + r0;
      float bb = o1b[col];
      #pragma unroll
      for (int rt = 0; rt < 2; ++rt)
        #pragma unroll
        for (int j = 0; j < 4; ++j){
          int row = (rt << 4) + (kg << 2) + j;
          float v = q[rt][ctl][j] + bb; v = v > 0.f ? v : 0.f;
          u16 a = f2b(v);
          int idx = (row << 7) + ((((col >> 3)) ^ (row & 7)) << 3) + (col & 7);
          p1Hi[idx] = a;
          p1Lo[idx] = f2b(v - b2f(a));
        }
    }
  }
  __syncthreads();

  // out2: relu(p1 @ O2 + b2) via 3-term split MFMA -> p2 f32
  {
    f32x4 q[2][2];
    q[0][0]=zero4(); q[0][1]=zero4(); q[1][0]=zero4(); q[1][1]=zero4();
    #pragma unroll
    for (int kt = 0; kt < 4; ++kt){
      int sl = (kt << 2) + kg;
      bf16x8 ah0 = ldA(p1Hi, r0, sl), al0 = ldA(p1Lo, r0, sl);
      bf16x8 ah1 = ldA(p1Hi, r1, sl), al1 = ldA(p1Lo, r1, sl);
      #pragma unroll
      for (int ctl = 0; ctl < 2; ++ctl){
        int fo = FO + 64 + (kt << 3) + ct0 + ctl;
        bf16x8 bh = ldB(packs, fo, lane);
        bf16x8 bl = ldB(packs, fo + 32, lane);
        q[0][ctl] = mfmab(ah0, bh, q[0][ctl]);
        q[0][ctl] = mfmab(al0, bh, q[0][ctl]);
        q[0][ctl] = mfmab(ah0, bl, q[0][ctl]);
        q[1][ctl] = mfmab(ah1, bh, q[1][ctl]);
        q[1][ctl] = mfmab(al1, bh, q[1][ctl]);
        q[1][ctl] = mfmab(ah1, bl, q[1][ctl]);
      }
    }
    #pragma unroll
    for (int ctl = 0; ctl < 2; ++ctl){
      int col = ((ct0 + ctl) << 4) + r0;
      float bb = o2b[col];
      #pragma unroll
      for (int rt = 0; rt < 2; ++rt)
        #pragma unroll
        for (int j = 0; j < 4; ++j){
          int row = (rt << 4) + (kg << 2) + j;
          float v = q[rt][ctl][j] + bb; v = v > 0.f ? v : 0.f;
          p2L[row][col] = v;
        }
    }
  }
  __syncthreads();

  // out3: H -> 4, then pred = x + relu(...)
  if (tid < 128){
    int r = tid >> 2, c = tid & 3;
    int node = n0 + r;
    if (node < NN){
      float s = o3b[c];
      for (int kk = 0; kk < HH; ++kk) s = fmaf(p2L[r][kk], o3w[kk*CC + c], s);
      float v = fmaxf(s, 0.f);
      out[((size_t)t*NN + node)*CC + c] = xLs[r][c] + v;
    }
  }
}

extern "C" void kernel_launch(void* const* d_in, const int* in_sizes, int n_in,
                              void* d_out, int out_size, void* d_ws, size_t ws_size,
                              hipStream_t stream){
  const float* inputs = (const float*)d_in[0];
  const float* fc1w = (const float*)d_in[1];
  const float* fc1b = (const float*)d_in[2];
  const float* fc2w = (const float*)d_in[3];
  const float* fc2b = (const float*)d_in[4];
  const float* whr  = (const float*)d_in[5];
  const float* whi  = (const float*)d_in[6];
  const float* whh  = (const float*)d_in[7];
  const float* irw  = (const float*)d_in[8];
  const float* irb  = (const float*)d_in[9];
  const float* iiw  = (const float*)d_in[10];
  const float* iib  = (const float*)d_in[11];
  const float* inw  = (const float*)d_in[12];
  const float* inb  = (const float*)d_in[13];
  const float* o1w  = (const float*)d_in[14];
  const float* o1b  = (const float*)d_in[15];
  const float* o2w  = (const float*)d_in[16];
  const float* o2b  = (const float*)d_in[17];
  const float* o3w  = (const float*)d_in[18];
  const float* o3b  = (const float*)d_in[19];
  const int* edge   = (const int*)d_in[20];
  const int* burn   = (const int*)d_in[21];
  float* out = (float*)d_out;

  u8* ws = (u8*)d_ws;
  float* hid   = (float*)(ws);               // N*H fp32 = 5,120,000 B
  float* agg   = (float*)(ws + 5120000);     // N*H fp32 = 5,120,000 B
  float* UV    = (float*)(ws + 10240000);    // 6*N*H fp32 = 30,720,000 B
  u16*   packs = (u16*)(ws + 40960000);      // 896 frags * 1KB = 917,504 B

  hipMemsetAsync(hid, 0, 5120000, stream);
  PSrc ps; ps.w2 = fc2w; ps.w1 = fc1w; ps.o1 = o1w; ps.o2 = o2w;
  hipLaunchKernelGGL(pack_weights, dim3(NFRAG), dim3(64), 0, stream, ps, packs);

  const int nblk = (NN + 31) / 32;  // 313
  for (int t = 0; t < TT; ++t){
    hipMemsetAsync(agg, 0, 5120000, stream);
    hipLaunchKernelGGL(uv_kernel, dim3(nblk), dim3(256), 0, stream, hid, packs, UV);
    hipLaunchKernelGGL(edge_kernel, dim3(EE/32), dim3(256), 0, stream,
                       edge, UV, fc1b, fc2b, packs, agg);
    hipLaunchKernelGGL(node_kernel, dim3(nblk), dim3(256), 0, stream,
                       inputs + (size_t)t*NN*CC, out + (size_t)(t > 0 ? t-1 : 0)*NN*CC, burn, t,
                       agg, hid, whr, whi, whh, irw, irb, iiw, iib, inw, inb,
                       o1b, o2b, o3w, o3b, packs, out);
  }
}

// Round 11
// 1917.469 us; speedup vs baseline: 2.8120x; 1.0502x over previous
//
#include <hip/hip_runtime.h>

#define TT 10
#define NN 10000
#define CC 4
#define HH 128
#define EE 160000

typedef unsigned char u8;
typedef unsigned short u16;
typedef unsigned int u32;
typedef __attribute__((ext_vector_type(8))) short bf16x8;
typedef __attribute__((ext_vector_type(4))) float f32x4;

// packed fragment regions (each frag = 64 lanes * 16B = 1KB)
#define FW2 0      // W2: 96 hi + 96 lo
#define FW1 192    // W1: 6 matrices * 3 comps * 32
#define FO  768    // O1 hi/lo (32+32), O2 hi/lo (32+32)
#define NFRAG 896

__device__ __forceinline__ u16 f2b(float x){ // f32 -> bf16 RNE
  union { float f; u32 u; } v; v.f = x;
  return (u16)((v.u + 0x7fffu + ((v.u >> 16) & 1u)) >> 16);
}
__device__ __forceinline__ float b2f(u16 b){
  union { u32 u; float f; } v; v.u = ((u32)b) << 16;
  return v.f;
}
// HW-exp tanh: 1 - 2/(exp2(2x*log2e)+1); <=3e-7 rel err, correct saturation.
__device__ __forceinline__ float fast_tanh(float x){
  float e = __builtin_amdgcn_exp2f(x * 2.885390081777927f);
  return 1.f - 2.f * __builtin_amdgcn_rcpf(e + 1.f);
}
__device__ __forceinline__ f32x4 zero4(){ f32x4 z = {0.f,0.f,0.f,0.f}; return z; }
__device__ __forceinline__ f32x4 mfmab(bf16x8 a, bf16x8 b, f32x4 c){
  return __builtin_amdgcn_mfma_f32_16x16x32_bf16(a, b, c, 0, 0, 0);
}
// A-fragment read from XOR-swizzled LDS tile (rows of 128 u16 = 16 slots of 16B)
__device__ __forceinline__ bf16x8 ldA(const u16* L, int row, int sl){
  return *(const bf16x8*)(L + (row << 7) + ((sl ^ (row & 7)) << 3));
}
__device__ __forceinline__ bf16x8 ldB(const u16* packs, int frag, int lane){
  return *(const bf16x8*)(packs + frag*512 + lane*8);
}

struct PSrc { const float* w2; const float* w1; const float* o1; const float* o2; };

// ---------------- All weights -> bf16-component MFMA B-fragments.
__global__ void pack_weights(PSrc ps, u16* __restrict__ dst){
  int f = blockIdx.x, l = threadIdx.x;
  const float* src; int comp, kt, ct;
  if (f < 192){
    comp = f / 96; int g = f % 96;
    int br = g >> 5, rem = g & 31; kt = rem >> 3; ct = rem & 7;
    src = ps.w2 + (size_t)br*HH*HH;
  } else if (f < 768){
    int g = f - 192; int m = g / 96; int rem = g % 96;
    comp = rem >> 5; int idx = rem & 31; kt = idx >> 3; ct = idx & 7;
    src = ps.w1 + (size_t)m*HH*HH;
  } else {
    int g = f - 768; int mat = g >> 6; int rem = g & 63;
    comp = rem >> 5; int idx = rem & 31; kt = idx >> 3; ct = idx & 7;
    src = mat ? ps.o2 : ps.o1;
  }
  int col = (ct << 4) + (l & 15);
  u16* d = dst + f*512 + l*8;
  #pragma unroll
  for (int j = 0; j < 8; ++j){
    int kk = (kt << 5) + ((l >> 4) << 3) + j;
    float v = src[kk*HH + col];
    u16 c0 = f2b(v); float r = v - b2f(c0);
    u16 c1 = f2b(r); r -= b2f(c1);
    u16 c2 = f2b(r);
    d[j] = comp == 0 ? c0 : (comp == 1 ? c1 : c2);
  }
}

// ---------------- Edge sort by receiver (counting sort), once per call; reused all T steps.
__global__ void hist_kernel(const int* __restrict__ edge, int* __restrict__ hist){
  int i = blockIdx.x*256 + threadIdx.x;
  if (i < EE) atomicAdd(&hist[edge[EE + i]], 1);
}
__global__ void scan_kernel(const int* __restrict__ hist, int* __restrict__ cursor){
  __shared__ int part[256];
  __shared__ int partx[256];
  int tid = threadIdx.x;
  int base = tid*40;                 // 256*40 = 10240 >= NN
  int s = 0;
  for (int j = 0; j < 40; ++j){ int b = base+j; if (b < NN) s += hist[b]; }
  part[tid] = s;
  __syncthreads();
  if (tid == 0){ int acc = 0; for (int i = 0; i < 256; ++i){ partx[i] = acc; acc += part[i]; } }
  __syncthreads();
  int acc = partx[tid];
  for (int j = 0; j < 40; ++j){ int b = base+j; if (b < NN){ cursor[b] = acc; acc += hist[b]; } }
}
__global__ void scatter_kernel(const int* __restrict__ edge, int* __restrict__ cursor,
                               int* __restrict__ pr, int* __restrict__ pc){
  int i = blockIdx.x*256 + threadIdx.x;
  if (i < EE){
    int r = edge[i], c = edge[EE + i];
    int pos = atomicAdd(&cursor[c], 1);
    pr[pos] = r; pc[pos] = c;
  }
}

// ---------------- U/V precompute via MFMA, 3-component split (f32-faithful, ~2^-26).
__global__ __launch_bounds__(256)
void uv_kernel(const float* __restrict__ hid, const u16* __restrict__ packs,
               float* __restrict__ UV){
  __shared__ __align__(16) u16 h0[32*128], h1[32*128], h2[32*128];
  const int tid = threadIdx.x;
  const int lane = tid & 63, wid = tid >> 6;
  const int n0 = blockIdx.x << 5;

  #pragma unroll
  for (int it = 0; it < 4; ++it){
    int s = tid + (it << 8);
    int r = s >> 5, c4 = s & 31;
    int node = n0 + r; if (node > NN-1) node = NN-1;
    float4 v = *(const float4*)(hid + (size_t)node*HH + (c4 << 2));
    ushort4 q0, q1, q2;
    const float* pv = (const float*)&v;
    u16* q0p = (u16*)&q0; u16* q1p = (u16*)&q1; u16* q2p = (u16*)&q2;
    #pragma unroll
    for (int e = 0; e < 4; ++e){
      float x = pv[e];
      u16 a0 = f2b(x); float rr = x - b2f(a0);
      u16 a1 = f2b(rr); rr -= b2f(a1);
      q0p[e] = a0; q1p[e] = a1; q2p[e] = f2b(rr);
    }
    int idx = (r << 7) + (((c4 >> 1) ^ (r & 7)) << 3) + ((c4 & 1) << 2);
    *(ushort4*)(h0 + idx) = q0;
    *(ushort4*)(h1 + idx) = q1;
    *(ushort4*)(h2 + idx) = q2;
  }
  __syncthreads();

  const int ct0 = wid << 1;
  const int r0 = lane & 15, r1 = r0 + 16, kg = lane >> 4;

  for (int m = 0; m < 6; ++m){
    f32x4 acc[2][2];
    acc[0][0]=zero4(); acc[0][1]=zero4(); acc[1][0]=zero4(); acc[1][1]=zero4();
    #pragma unroll
    for (int kt = 0; kt < 4; ++kt){
      int sl = (kt << 2) + kg;
      bf16x8 a00 = ldA(h0, r0, sl), a01 = ldA(h1, r0, sl), a02 = ldA(h2, r0, sl);
      bf16x8 a10 = ldA(h0, r1, sl), a11 = ldA(h1, r1, sl), a12 = ldA(h2, r1, sl);
      #pragma unroll
      for (int ctl = 0; ctl < 2; ++ctl){
        int fb = FW1 + m*96 + (kt << 3) + ct0 + ctl;
        bf16x8 b0 = ldB(packs, fb,      lane);
        bf16x8 b1 = ldB(packs, fb + 32, lane);
        bf16x8 b2 = ldB(packs, fb + 64, lane);
        acc[0][ctl] = mfmab(a00, b0, acc[0][ctl]);
        acc[0][ctl] = mfmab(a01, b0, acc[0][ctl]);
        acc[0][ctl] = mfmab(a00, b1, acc[0][ctl]);
        acc[0][ctl] = mfmab(a02, b0, acc[0][ctl]);
        acc[0][ctl] = mfmab(a01, b1, acc[0][ctl]);
        acc[0][ctl] = mfmab(a00, b2, acc[0][ctl]);
        acc[1][ctl] = mfmab(a10, b0, acc[1][ctl]);
        acc[1][ctl] = mfmab(a11, b0, acc[1][ctl]);
        acc[1][ctl] = mfmab(a10, b1, acc[1][ctl]);
        acc[1][ctl] = mfmab(a12, b0, acc[1][ctl]);
        acc[1][ctl] = mfmab(a11, b1, acc[1][ctl]);
        acc[1][ctl] = mfmab(a10, b2, acc[1][ctl]);
      }
    }
    #pragma unroll
    for (int ctl = 0; ctl < 2; ++ctl)
      #pragma unroll
      for (int rt = 0; rt < 2; ++rt)
        #pragma unroll
        for (int j = 0; j < 4; ++j){
          int row = (rt << 4) + (kg << 2) + j;
          int col = ((ct0 + ctl) << 4) + r0;
          int node = n0 + row;
          if (node < NN) UV[((size_t)m*NN + node)*HH + col] = acc[rt][ctl][j];
        }
  }
}

// ---------------- Edge kernel: 32 sorted edges/block; merged atomic flush per receiver run.
__global__ __launch_bounds__(256)
void edge_kernel(const int* __restrict__ pr, const int* __restrict__ pc,
                 const float* __restrict__ UV,
                 const float* __restrict__ b1, const float* __restrict__ b2,
                 const u16* __restrict__ packs, float* __restrict__ agg){
  __shared__ __align__(16) u16 m1hi[32*128];
  __shared__ __align__(16) u16 m1lo[32*128];
  __shared__ int er[32], ec[32];
  const int tid = threadIdx.x;
  const int lane = tid & 63, wid = tid >> 6;
  const int e0 = blockIdx.x << 5;

  if (tid < 32) er[tid] = pr[e0 + tid];
  else if (tid < 64) ec[tid - 32] = pc[e0 + tid - 32];

  const int c4 = tid & 31;
  const int cOff = c4 << 2;
  const int ct0 = wid << 1;
  const int r0 = lane & 15, r1 = r0 + 16, kg = lane >> 4;

  f32x4 acc[2][2];
  acc[0][0]=zero4(); acc[0][1]=zero4(); acc[1][0]=zero4(); acc[1][1]=zero4();

  for (int k = 0; k < 3; ++k){
    __syncthreads();
    {
      float4 b = *(const float4*)(b1 + k*HH + cOff);
      const float* __restrict__ Ub = UV + (size_t)(2*k)*NN*HH;
      const float* __restrict__ Vb = UV + (size_t)(2*k + 1)*NN*HH;
      #pragma unroll
      for (int it = 0; it < 4; ++it){
        int e = (tid >> 5) + (it << 3);
        float4 u = *(const float4*)(Ub + (size_t)er[e]*HH + cOff);
        float4 v = *(const float4*)(Vb + (size_t)ec[e]*HH + cOff);
        float m0 = fast_tanh(u.x + v.x + b.x);
        float m1 = fast_tanh(u.y + v.y + b.y);
        float m2 = fast_tanh(u.z + v.z + b.z);
        float m3 = fast_tanh(u.w + v.w + b.w);
        ushort4 hi, lo;
        hi.x = f2b(m0); lo.x = f2b(m0 - b2f(hi.x));
        hi.y = f2b(m1); lo.y = f2b(m1 - b2f(hi.y));
        hi.z = f2b(m2); lo.z = f2b(m2 - b2f(hi.z));
        hi.w = f2b(m3); lo.w = f2b(m3 - b2f(hi.w));
        int idx = (e << 7) + (((c4 >> 1) ^ (e & 7)) << 3) + ((c4 & 1) << 2);
        *(ushort4*)(m1hi + idx) = hi;
        *(ushort4*)(m1lo + idx) = lo;
      }
    }
    __syncthreads();

    f32x4 lacc[2][2];
    lacc[0][0]=zero4(); lacc[0][1]=zero4(); lacc[1][0]=zero4(); lacc[1][1]=zero4();
    #pragma unroll
    for (int kt = 0; kt < 4; ++kt){
      int sl = (kt << 2) + kg;
      bf16x8 a0h = ldA(m1hi, r0, sl);
      bf16x8 a1h = ldA(m1hi, r1, sl);
      bf16x8 a0l = ldA(m1lo, r0, sl);
      bf16x8 a1l = ldA(m1lo, r1, sl);
      #pragma unroll
      for (int ctl = 0; ctl < 2; ++ctl){
        int fh = FW2 + k*32 + (kt << 3) + ct0 + ctl;
        bf16x8 bh = ldB(packs, fh, lane);
        bf16x8 bl = ldB(packs, fh + 96, lane);
        lacc[0][ctl] = mfmab(a0h, bh, lacc[0][ctl]);
        lacc[0][ctl] = mfmab(a0l, bh, lacc[0][ctl]);
        lacc[0][ctl] = mfmab(a0h, bl, lacc[0][ctl]);
        lacc[1][ctl] = mfmab(a1h, bh, lacc[1][ctl]);
        lacc[1][ctl] = mfmab(a1l, bh, lacc[1][ctl]);
        lacc[1][ctl] = mfmab(a1h, bl, lacc[1][ctl]);
      }
    }
    #pragma unroll
    for (int ctl = 0; ctl < 2; ++ctl){
      int col = ((ct0 + ctl) << 4) + r0;
      float bb = b2[k*HH + col];
      #pragma unroll
      for (int rt = 0; rt < 2; ++rt)
        #pragma unroll
        for (int j = 0; j < 4; ++j)
          acc[rt][ctl][j] += fast_tanh(lacc[rt][ctl][j] + bb);
    }
  }

  // merged scatter: sorted ec -> run-length accumulate, flush once per receiver run
  {
    int col0 = (ct0 << 4) + r0;
    int col1 = ((ct0 + 1) << 4) + r0;
    int prevNode = -1;
    float s0 = 0.f, s1 = 0.f;
    #pragma unroll
    for (int rt = 0; rt < 2; ++rt)
      #pragma unroll
      for (int j = 0; j < 4; ++j){
        int row = (rt << 4) + (kg << 2) + j;
        int node = ec[row];
        float v0 = acc[rt][0][j], v1 = acc[rt][1][j];
        if (node != prevNode){
          if (prevNode >= 0){
            atomicAdd(agg + (size_t)prevNode*HH + col0, s0);
            atomicAdd(agg + (size_t)prevNode*HH + col1, s1);
          }
          prevNode = node; s0 = v0; s1 = v1;
        } else { s0 += v0; s1 += v1; }
      }
    atomicAdd(agg + (size_t)prevNode*HH + col0, s0);
    atomicAdd(agg + (size_t)prevNode*HH + col1, s1);
  }
}

// ---------------- Node kernel: GRU gates (f32) + out1/out2 via split-bf16 MFMA + out3.
__global__ __launch_bounds__(256)
void node_kernel(const float* __restrict__ xin, const float* __restrict__ prevpred,
                 const int* __restrict__ burn, int t,
                 const float* __restrict__ agg, float* __restrict__ hid,
                 const float* __restrict__ whr, const float* __restrict__ whi, const float* __restrict__ whh,
                 const float* __restrict__ irw, const float* __restrict__ irb,
                 const float* __restrict__ iiw, const float* __restrict__ iib,
                 const float* __restrict__ inw, const float* __restrict__ inb,
                 const float* __restrict__ o1b, const float* __restrict__ o2b,
                 const float* __restrict__ o3w, const float* __restrict__ o3b,
                 const u16* __restrict__ packs, float* __restrict__ out){
  __shared__ float aggL[32][136];
  __shared__ __align__(16) u16 hHi[32*128], hLo[32*128];
  __shared__ __align__(16) u16 p1Hi[32*128], p1Lo[32*128];
  __shared__ float p2L[32][136];
  __shared__ float xLs[32][4];
  const int tid = threadIdx.x;
  const int n0 = blockIdx.x << 5;
  const float* __restrict__ xs = (t == 0 || t < burn[0]) ? xin : prevpred;

  #pragma unroll
  for (int it = 0; it < 4; ++it){
    int s = tid + (it << 8);
    int r = s >> 5, c4 = s & 31;
    int node = n0 + r; if (node > NN-1) node = NN-1;
    float4 v = *(const float4*)(agg + (size_t)node*HH + (c4 << 2));
    *(float4*)(&aggL[r][c4 << 2]) = v;
  }
  if (tid < 128){
    int r = tid >> 2, c = tid & 3;
    int node = n0 + r; if (node > NN-1) node = NN-1;
    xLs[r][c] = xs[(size_t)node*CC + c];
  }
  __syncthreads();

  const int ng = tid >> 5, cg = tid & 31;
  float ar[4][4] = {}, ai[4][4] = {}, ah[4][4] = {};
  for (int kk = 0; kk < HH; ++kk){
    float av[4];
    #pragma unroll
    for (int rr = 0; rr < 4; ++rr) av[rr] = aggL[(ng << 2) + rr][kk];
    float4 wR = *(const float4*)(whr + kk*HH + (cg << 2));
    float4 wI = *(const float4*)(whi + kk*HH + (cg << 2));
    float4 wH = *(const float4*)(whh + kk*HH + (cg << 2));
    #pragma unroll
    for (int rr = 0; rr < 4; ++rr){
      ar[rr][0] = fmaf(av[rr], wR.x, ar[rr][0]); ar[rr][1] = fmaf(av[rr], wR.y, ar[rr][1]);
      ar[rr][2] = fmaf(av[rr], wR.z, ar[rr][2]); ar[rr][3] = fmaf(av[rr], wR.w, ar[rr][3]);
      ai[rr][0] = fmaf(av[rr], wI.x, ai[rr][0]); ai[rr][1] = fmaf(av[rr], wI.y, ai[rr][1]);
      ai[rr][2] = fmaf(av[rr], wI.z, ai[rr][2]); ai[rr][3] = fmaf(av[rr], wI.w, ai[rr][3]);
      ah[rr][0] = fmaf(av[rr], wH.x, ah[rr][0]); ah[rr][1] = fmaf(av[rr], wH.y, ah[rr][1]);
      ah[rr][2] = fmaf(av[rr], wH.z, ah[rr][2]); ah[rr][3] = fmaf(av[rr], wH.w, ah[rr][3]);
    }
  }
  {
    float4 wr4[CC], wi4[CC], wn4[CC];
    #pragma unroll
    for (int c = 0; c < CC; ++c){
      wr4[c] = *(const float4*)(irw + c*HH + (cg << 2));
      wi4[c] = *(const float4*)(iiw + c*HH + (cg << 2));
      wn4[c] = *(const float4*)(inw + c*HH + (cg << 2));
    }
    float4 rb = *(const float4*)(irb + (cg << 2));
    float4 ib = *(const float4*)(iib + (cg << 2));
    float4 nb = *(const float4*)(inb + (cg << 2));
    #pragma unroll
    for (int rr = 0; rr < 4; ++rr){
      int row = (ng << 2) + rr;
      int node = n0 + row;
      int nodec = node > NN-1 ? NN-1 : node;
      float xv[CC];
      #pragma unroll
      for (int c = 0; c < CC; ++c) xv[c] = xLs[row][c];
      float hv4[4];
      #pragma unroll
      for (int cc = 0; cc < 4; ++cc){
        int col = (cg << 2) + cc;
        float xr = ((const float*)&rb)[cc], xi = ((const float*)&ib)[cc], xn = ((const float*)&nb)[cc];
        #pragma unroll
        for (int c = 0; c < CC; ++c){
          xr = fmaf(xv[c], ((const float*)&wr4[c])[cc], xr);
          xi = fmaf(xv[c], ((const float*)&wi4[c])[cc], xi);
          xn = fmaf(xv[c], ((const float*)&wn4[c])[cc], xn);
        }
        float r = 1.f / (1.f + expf(-(xr + ar[rr][cc])));
        float i = 1.f / (1.f + expf(-(xi + ai[rr][cc])));
        float n = tanhf(xn + r * ah[rr][cc]);
        float hold = hid[(size_t)nodec*HH + col];
        float hnew = (1.f - i)*n + i*hold;
        if (node < NN) hid[(size_t)node*HH + col] = hnew;
        hv4[cc] = hnew;
      }
      ushort4 hhi, hlo;
      u16* hp = (u16*)&hhi; u16* lp = (u16*)&hlo;
      #pragma unroll
      for (int cc = 0; cc < 4; ++cc){
        u16 a = f2b(hv4[cc]);
        hp[cc] = a; lp[cc] = f2b(hv4[cc] - b2f(a));
      }
      int idx = (row << 7) + (((cg >> 1) ^ (row & 7)) << 3) + ((cg & 1) << 2);
      *(ushort4*)(hHi + idx) = hhi;
      *(ushort4*)(hLo + idx) = hlo;
    }
  }
  __syncthreads();

  const int lane = tid & 63, wid = tid >> 6;
  const int ct0 = wid << 1;
  const int r0 = lane & 15, r1 = r0 + 16, kg = lane >> 4;

  // out1: relu(h @ O1 + b1) via 3-term split MFMA -> p1 hi/lo
  {
    f32x4 q[2][2];
    q[0][0]=zero4(); q[0][1]=zero4(); q[1][0]=zero4(); q[1][1]=zero4();
    #pragma unroll
    for (int kt = 0; kt < 4; ++kt){
      int sl = (kt << 2) + kg;
      bf16x8 ah0 = ldA(hHi, r0, sl), al0 = ldA(hLo, r0, sl);
      bf16x8 ah1 = ldA(hHi, r1, sl), al1 = ldA(hLo, r1, sl);
      #pragma unroll
      for (int ctl = 0; ctl < 2; ++ctl){
        int fo = FO + (kt << 3) + ct0 + ctl;
        bf16x8 bh = ldB(packs, fo, lane);
        bf16x8 bl = ldB(packs, fo + 32, lane);
        q[0][ctl] = mfmab(ah0, bh, q[0][ctl]);
        q[0][ctl] = mfmab(al0, bh, q[0][ctl]);
        q[0][ctl] = mfmab(ah0, bl, q[0][ctl]);
        q[1][ctl] = mfmab(ah1, bh, q[1][ctl]);
        q[1][ctl] = mfmab(al1, bh, q[1][ctl]);
        q[1][ctl] = mfmab(ah1, bl, q[1][ctl]);
      }
    }
    #pragma unroll
    for (int ctl = 0; ctl < 2; ++ctl){
      int col = ((ct0 + ctl) << 4) + r0;
      float bb = o1b[col];
      #pragma unroll
      for (int rt = 0; rt < 2; ++rt)
        #pragma unroll
        for (int j = 0; j < 4; ++j){
          int row = (rt << 4) + (kg << 2) + j;
          float v = q[rt][ctl][j] + bb; v = v > 0.f ? v : 0.f;
          u16 a = f2b(v);
          int idx = (row << 7) + ((((col >> 3)) ^ (row & 7)) << 3) + (col & 7);
          p1Hi[idx] = a;
          p1Lo[idx] = f2b(v - b2f(a));
        }
    }
  }
  __syncthreads();

  // out2: relu(p1 @ O2 + b2) via 3-term split MFMA -> p2 f32
  {
    f32x4 q[2][2];
    q[0][0]=zero4(); q[0][1]=zero4(); q[1][0]=zero4(); q[1][1]=zero4();
    #pragma unroll
    for (int kt = 0; kt < 4; ++kt){
      int sl = (kt << 2) + kg;
      bf16x8 ah0 = ldA(p1Hi, r0, sl), al0 = ldA(p1Lo, r0, sl);
      bf16x8 ah1 = ldA(p1Hi, r1, sl), al1 = ldA(p1Lo, r1, sl);
      #pragma unroll
      for (int ctl = 0; ctl < 2; ++ctl){
        int fo = FO + 64 + (kt << 3) + ct0 + ctl;
        bf16x8 bh = ldB(packs, fo, lane);
        bf16x8 bl = ldB(packs, fo + 32, lane);
        q[0][ctl] = mfmab(ah0, bh, q[0][ctl]);
        q[0][ctl] = mfmab(al0, bh, q[0][ctl]);
        q[0][ctl] = mfmab(ah0, bl, q[0][ctl]);
        q[1][ctl] = mfmab(ah1, bh, q[1][ctl]);
        q[1][ctl] = mfmab(al1, bh, q[1][ctl]);
        q[1][ctl] = mfmab(ah1, bl, q[1][ctl]);
      }
    }
    #pragma unroll
    for (int ctl = 0; ctl < 2; ++ctl){
      int col = ((ct0 + ctl) << 4) + r0;
      float bb = o2b[col];
      #pragma unroll
      for (int rt = 0; rt < 2; ++rt)
        #pragma unroll
        for (int j = 0; j < 4; ++j){
          int row = (rt << 4) + (kg << 2) + j;
          float v = q[rt][ctl][j] + bb; v = v > 0.f ? v : 0.f;
          p2L[row][col] = v;
        }
    }
  }
  __syncthreads();

  // out3: H -> 4, then pred = x + relu(...)
  if (tid < 128){
    int r = tid >> 2, c = tid & 3;
    int node = n0 + r;
    if (node < NN){
      float s = o3b[c];
      for (int kk = 0; kk < HH; ++kk) s = fmaf(p2L[r][kk], o3w[kk*CC + c], s);
      float v = fmaxf(s, 0.f);
      out[((size_t)t*NN + node)*CC + c] = xLs[r][c] + v;
    }
  }
}

extern "C" void kernel_launch(void* const* d_in, const int* in_sizes, int n_in,
                              void* d_out, int out_size, void* d_ws, size_t ws_size,
                              hipStream_t stream){
  const float* inputs = (const float*)d_in[0];
  const float* fc1w = (const float*)d_in[1];
  const float* fc1b = (const float*)d_in[2];
  const float* fc2w = (const float*)d_in[3];
  const float* fc2b = (const float*)d_in[4];
  const float* whr  = (const float*)d_in[5];
  const float* whi  = (const float*)d_in[6];
  const float* whh  = (const float*)d_in[7];
  const float* irw  = (const float*)d_in[8];
  const float* irb  = (const float*)d_in[9];
  const float* iiw  = (const float*)d_in[10];
  const float* iib  = (const float*)d_in[11];
  const float* inw  = (const float*)d_in[12];
  const float* inb  = (const float*)d_in[13];
  const float* o1w  = (const float*)d_in[14];
  const float* o1b  = (const float*)d_in[15];
  const float* o2w  = (const float*)d_in[16];
  const float* o2b  = (const float*)d_in[17];
  const float* o3w  = (const float*)d_in[18];
  const float* o3b  = (const float*)d_in[19];
  const int* edge   = (const int*)d_in[20];
  const int* burn   = (const int*)d_in[21];
  float* out = (float*)d_out;

  u8* ws = (u8*)d_ws;
  float* hid   = (float*)(ws);               // N*H fp32 = 5,120,000 B
  float* agg   = (float*)(ws + 5120000);     // N*H fp32 = 5,120,000 B
  float* UV    = (float*)(ws + 10240000);    // 6*N*H fp32 = 30,720,000 B
  u16*   packs = (u16*)(ws + 40960000);      // 896 frags = 917,504 B
  int*   pr    = (int*)(ws + 41877504);      // 640,000 B
  int*   pc    = (int*)(ws + 42517504);      // 640,000 B
  int*   hist  = (int*)(ws + 43157504);      // 40,000 B
  int*   cursor= (int*)(ws + 43197504);      // 40,000 B

  hipMemsetAsync(hid, 0, 5120000, stream);
  hipMemsetAsync(hist, 0, 40000, stream);

  PSrc ps; ps.w2 = fc2w; ps.w1 = fc1w; ps.o1 = o1w; ps.o2 = o2w;
  hipLaunchKernelGGL(pack_weights, dim3(NFRAG), dim3(64), 0, stream, ps, packs);
  hipLaunchKernelGGL(hist_kernel, dim3((EE+255)/256), dim3(256), 0, stream, edge, hist);
  hipLaunchKernelGGL(scan_kernel, dim3(1), dim3(256), 0, stream, hist, cursor);
  hipLaunchKernelGGL(scatter_kernel, dim3((EE+255)/256), dim3(256), 0, stream, edge, cursor, pr, pc);

  const int nblk = (NN + 31) / 32;  // 313
  for (int t = 0; t < TT; ++t){
    hipMemsetAsync(agg, 0, 5120000, stream);
    hipLaunchKernelGGL(uv_kernel, dim3(nblk), dim3(256), 0, stream, hid, packs, UV);
    hipLaunchKernelGGL(edge_kernel, dim3(EE/32), dim3(256), 0, stream,
                       pr, pc, UV, fc1b, fc2b, packs, agg);
    hipLaunchKernelGGL(node_kernel, dim3(nblk), dim3(256), 0, stream,
                       inputs + (size_t)t*NN*CC, out + (size_t)(t > 0 ? t-1 : 0)*NN*CC, burn, t,
                       agg, hid, whr, whi, whh, irw, irb, iiw, iib, inw, inb,
                       o1b, o2b, o3w, o3b, packs, out);
  }
}

// Round 13
// 1894.940 us; speedup vs baseline: 2.8454x; 1.0119x over previous
//
#include <hip/hip_runtime.h>

#define TT 10
#define NN 10000
#define CC 4
#define HH 128
#define EE 160000

typedef unsigned char u8;
typedef unsigned short u16;
typedef unsigned int u32;
typedef __attribute__((ext_vector_type(8))) short bf16x8;
typedef __attribute__((ext_vector_type(4))) float f32x4;

// packed fragment regions (each frag = 64 lanes * 16B = 1KB)
#define FW2 0      // W2: 96 hi + 96 lo
#define FW1 192    // W1: 6 matrices * 3 comps * 32
#define FO  768    // O1 hi/lo (32+32), O2 hi/lo (32+32)
#define FG  896    // GRU whr/whi/whh: 3 matrices * 3 comps * 32
#define NFRAG 1184

__device__ __forceinline__ u16 f2b(float x){ // f32 -> bf16 RNE
  union { float f; u32 u; } v; v.f = x;
  return (u16)((v.u + 0x7fffu + ((v.u >> 16) & 1u)) >> 16);
}
__device__ __forceinline__ float b2f(u16 b){
  union { u32 u; float f; } v; v.u = ((u32)b) << 16;
  return v.f;
}
// HW-exp tanh: 1 - 2/(exp2(2x*log2e)+1); <=3e-7 rel err, correct saturation.
__device__ __forceinline__ float fast_tanh(float x){
  float e = __builtin_amdgcn_exp2f(x * 2.885390081777927f);
  return 1.f - 2.f * __builtin_amdgcn_rcpf(e + 1.f);
}
__device__ __forceinline__ f32x4 zero4(){ f32x4 z = {0.f,0.f,0.f,0.f}; return z; }
__device__ __forceinline__ f32x4 mfmab(bf16x8 a, bf16x8 b, f32x4 c){
  return __builtin_amdgcn_mfma_f32_16x16x32_bf16(a, b, c, 0, 0, 0);
}
// A-fragment read from XOR-swizzled LDS tile (rows of 128 u16 = 16 slots of 16B)
__device__ __forceinline__ bf16x8 ldA(const u16* L, int row, int sl){
  return *(const bf16x8*)(L + (row << 7) + ((sl ^ (row & 7)) << 3));
}
__device__ __forceinline__ bf16x8 ldB(const u16* packs, int frag, int lane){
  return *(const bf16x8*)(packs + frag*512 + lane*8);
}

struct PSrc { const float* w2; const float* w1; const float* o1; const float* o2;
              const float* gr; const float* gi; const float* gh; };

// ---------------- All weights -> bf16-component MFMA B-fragments.
__global__ void pack_weights(PSrc ps, u16* __restrict__ dst){
  int f = blockIdx.x, l = threadIdx.x;
  const float* src; int comp, kt, ct;
  if (f < 192){
    comp = f / 96; int g = f % 96;
    int br = g >> 5, rem = g & 31; kt = rem >> 3; ct = rem & 7;
    src = ps.w2 + (size_t)br*HH*HH;
  } else if (f < 768){
    int g = f - 192; int m = g / 96; int rem = g % 96;
    comp = rem >> 5; int idx = rem & 31; kt = idx >> 3; ct = idx & 7;
    src = ps.w1 + (size_t)m*HH*HH;
  } else if (f < 896){
    int g = f - 768; int mat = g >> 6; int rem = g & 63;
    comp = rem >> 5; int idx = rem & 31; kt = idx >> 3; ct = idx & 7;
    src = mat ? ps.o2 : ps.o1;
  } else {
    int g = f - 896; int mat = g / 96; int rem = g % 96;
    comp = rem >> 5; int idx = rem & 31; kt = idx >> 3; ct = idx & 7;
    src = mat == 0 ? ps.gr : (mat == 1 ? ps.gi : ps.gh);
  }
  int col = (ct << 4) + (l & 15);
  u16* d = dst + f*512 + l*8;
  #pragma unroll
  for (int j = 0; j < 8; ++j){
    int kk = (kt << 5) + ((l >> 4) << 3) + j;
    float v = src[kk*HH + col];
    u16 c0 = f2b(v); float r = v - b2f(c0);
    u16 c1 = f2b(r); r -= b2f(c1);
    u16 c2 = f2b(r);
    d[j] = comp == 0 ? c0 : (comp == 1 ? c1 : c2);
  }
}

// ---------------- Edge sort by receiver (counting sort), once per call.
__global__ void hist_kernel(const int* __restrict__ edge, int* __restrict__ hist){
  int i = blockIdx.x*256 + threadIdx.x;
  if (i < EE) atomicAdd(&hist[edge[EE + i]], 1);
}
__global__ void scan_kernel(const int* __restrict__ hist, int* __restrict__ cursor){
  __shared__ int part[256];
  __shared__ int partx[256];
  int tid = threadIdx.x;
  int base = tid*40;
  int s = 0;
  for (int j = 0; j < 40; ++j){ int b = base+j; if (b < NN) s += hist[b]; }
  part[tid] = s;
  __syncthreads();
  if (tid == 0){ int acc = 0; for (int i = 0; i < 256; ++i){ partx[i] = acc; acc += part[i]; } }
  __syncthreads();
  int acc = partx[tid];
  for (int j = 0; j < 40; ++j){ int b = base+j; if (b < NN){ cursor[b] = acc; acc += hist[b]; } }
}
__global__ void scatter_kernel(const int* __restrict__ edge, int* __restrict__ cursor,
                               int* __restrict__ pr, int* __restrict__ pc){
  int i = blockIdx.x*256 + threadIdx.x;
  if (i < EE){
    int r = edge[i], c = edge[EE + i];
    int pos = atomicAdd(&cursor[c], 1);
    pr[pos] = r; pc[pos] = c;
  }
}

// ---------------- U/V precompute via MFMA, 3-component split (f32-faithful, ~2^-26).
__global__ __launch_bounds__(256)
void uv_kernel(const float* __restrict__ hid, const u16* __restrict__ packs,
               float* __restrict__ UV){
  __shared__ __align__(16) u16 h0[32*128], h1[32*128], h2[32*128];
  const int tid = threadIdx.x;
  const int lane = tid & 63, wid = tid >> 6;
  const int n0 = blockIdx.x << 5;

  #pragma unroll
  for (int it = 0; it < 4; ++it){
    int s = tid + (it << 8);
    int r = s >> 5, c4 = s & 31;
    int node = n0 + r; if (node > NN-1) node = NN-1;
    float4 v = *(const float4*)(hid + (size_t)node*HH + (c4 << 2));
    ushort4 q0, q1, q2;
    const float* pv = (const float*)&v;
    u16* q0p = (u16*)&q0; u16* q1p = (u16*)&q1; u16* q2p = (u16*)&q2;
    #pragma unroll
    for (int e = 0; e < 4; ++e){
      float x = pv[e];
      u16 a0 = f2b(x); float rr = x - b2f(a0);
      u16 a1 = f2b(rr); rr -= b2f(a1);
      q0p[e] = a0; q1p[e] = a1; q2p[e] = f2b(rr);
    }
    int idx = (r << 7) + (((c4 >> 1) ^ (r & 7)) << 3) + ((c4 & 1) << 2);
    *(ushort4*)(h0 + idx) = q0;
    *(ushort4*)(h1 + idx) = q1;
    *(ushort4*)(h2 + idx) = q2;
  }
  __syncthreads();

  const int ct0 = wid << 1;
  const int r0 = lane & 15, r1 = r0 + 16, kg = lane >> 4;

  for (int m = 0; m < 6; ++m){
    f32x4 acc[2][2];
    acc[0][0]=zero4(); acc[0][1]=zero4(); acc[1][0]=zero4(); acc[1][1]=zero4();
    #pragma unroll
    for (int kt = 0; kt < 4; ++kt){
      int sl = (kt << 2) + kg;
      bf16x8 a00 = ldA(h0, r0, sl), a01 = ldA(h1, r0, sl), a02 = ldA(h2, r0, sl);
      bf16x8 a10 = ldA(h0, r1, sl), a11 = ldA(h1, r1, sl), a12 = ldA(h2, r1, sl);
      #pragma unroll
      for (int ctl = 0; ctl < 2; ++ctl){
        int fb = FW1 + m*96 + (kt << 3) + ct0 + ctl;
        bf16x8 b0 = ldB(packs, fb,      lane);
        bf16x8 b1 = ldB(packs, fb + 32, lane);
        bf16x8 b2 = ldB(packs, fb + 64, lane);
        acc[0][ctl] = mfmab(a00, b0, acc[0][ctl]);
        acc[0][ctl] = mfmab(a01, b0, acc[0][ctl]);
        acc[0][ctl] = mfmab(a00, b1, acc[0][ctl]);
        acc[0][ctl] = mfmab(a02, b0, acc[0][ctl]);
        acc[0][ctl] = mfmab(a01, b1, acc[0][ctl]);
        acc[0][ctl] = mfmab(a00, b2, acc[0][ctl]);
        acc[1][ctl] = mfmab(a10, b0, acc[1][ctl]);
        acc[1][ctl] = mfmab(a11, b0, acc[1][ctl]);
        acc[1][ctl] = mfmab(a10, b1, acc[1][ctl]);
        acc[1][ctl] = mfmab(a12, b0, acc[1][ctl]);
        acc[1][ctl] = mfmab(a11, b1, acc[1][ctl]);
        acc[1][ctl] = mfmab(a10, b2, acc[1][ctl]);
      }
    }
    #pragma unroll
    for (int ctl = 0; ctl < 2; ++ctl)
      #pragma unroll
      for (int rt = 0; rt < 2; ++rt)
        #pragma unroll
        for (int j = 0; j < 4; ++j){
          int row = (rt << 4) + (kg << 2) + j;
          int col = ((ct0 + ctl) << 4) + r0;
          int node = n0 + row;
          if (node < NN) UV[((size_t)m*NN + node)*HH + col] = acc[rt][ctl][j];
        }
  }
}

// ---------------- Edge kernel: 64 sorted edges/block (4 MFMA row-tiles).
__global__ __launch_bounds__(256)
void edge_kernel(const int* __restrict__ pr, const int* __restrict__ pc,
                 const float* __restrict__ UV,
                 const float* __restrict__ b1, const float* __restrict__ b2,
                 const u16* __restrict__ packs, float* __restrict__ agg){
  __shared__ __align__(16) u16 m1hi[64*128];
  __shared__ __align__(16) u16 m1lo[64*128];
  __shared__ int er[64], ec[64];
  const int tid = threadIdx.x;
  const int lane = tid & 63, wid = tid >> 6;
  const int e0 = blockIdx.x << 6;

  if (tid < 64) er[tid] = pr[e0 + tid];
  else if (tid < 128) ec[tid - 64] = pc[e0 + tid - 64];

  const int c4 = tid & 31;
  const int cOff = c4 << 2;
  const int ct0 = wid << 1;
  const int r0 = lane & 15, kg = lane >> 4;

  f32x4 acc[4][2];
  #pragma unroll
  for (int rt = 0; rt < 4; ++rt){ acc[rt][0] = zero4(); acc[rt][1] = zero4(); }

  for (int k = 0; k < 3; ++k){
    __syncthreads();
    {
      float4 b = *(const float4*)(b1 + k*HH + cOff);
      const float* __restrict__ Ub = UV + (size_t)(2*k)*NN*HH;
      const float* __restrict__ Vb = UV + (size_t)(2*k + 1)*NN*HH;
      #pragma unroll
      for (int it = 0; it < 8; ++it){
        int e = (tid >> 5) + (it << 3);
        float4 u = *(const float4*)(Ub + (size_t)er[e]*HH + cOff);
        float4 v = *(const float4*)(Vb + (size_t)ec[e]*HH + cOff);
        float m0 = fast_tanh(u.x + v.x + b.x);
        float m1 = fast_tanh(u.y + v.y + b.y);
        float m2 = fast_tanh(u.z + v.z + b.z);
        float m3 = fast_tanh(u.w + v.w + b.w);
        ushort4 hi, lo;
        hi.x = f2b(m0); lo.x = f2b(m0 - b2f(hi.x));
        hi.y = f2b(m1); lo.y = f2b(m1 - b2f(hi.y));
        hi.z = f2b(m2); lo.z = f2b(m2 - b2f(hi.z));
        hi.w = f2b(m3); lo.w = f2b(m3 - b2f(hi.w));
        int idx = (e << 7) + (((c4 >> 1) ^ (e & 7)) << 3) + ((c4 & 1) << 2);
        *(ushort4*)(m1hi + idx) = hi;
        *(ushort4*)(m1lo + idx) = lo;
      }
    }
    __syncthreads();

    f32x4 lacc[4][2];
    #pragma unroll
    for (int rt = 0; rt < 4; ++rt){ lacc[rt][0] = zero4(); lacc[rt][1] = zero4(); }
    #pragma unroll
    for (int kt = 0; kt < 4; ++kt){
      int sl = (kt << 2) + kg;
      bf16x8 aH[4], aL[4];
      #pragma unroll
      for (int rt = 0; rt < 4; ++rt){
        aH[rt] = ldA(m1hi, (rt << 4) + r0, sl);
        aL[rt] = ldA(m1lo, (rt << 4) + r0, sl);
      }
      #pragma unroll
      for (int ctl = 0; ctl < 2; ++ctl){
        int fh = FW2 + k*32 + (kt << 3) + ct0 + ctl;
        bf16x8 bh = ldB(packs, fh, lane);
        bf16x8 bl = ldB(packs, fh + 96, lane);
        #pragma unroll
        for (int rt = 0; rt < 4; ++rt){
          lacc[rt][ctl] = mfmab(aH[rt], bh, lacc[rt][ctl]);
          lacc[rt][ctl] = mfmab(aL[rt], bh, lacc[rt][ctl]);
          lacc[rt][ctl] = mfmab(aH[rt], bl, lacc[rt][ctl]);
        }
      }
    }
    #pragma unroll
    for (int ctl = 0; ctl < 2; ++ctl){
      int col = ((ct0 + ctl) << 4) + r0;
      float bb = b2[k*HH + col];
      #pragma unroll
      for (int rt = 0; rt < 4; ++rt)
        #pragma unroll
        for (int j = 0; j < 4; ++j)
          acc[rt][ctl][j] += fast_tanh(lacc[rt][ctl][j] + bb);
    }
  }

  // merged scatter: sorted ec -> run-length accumulate, flush once per receiver run
  {
    int col0 = (ct0 << 4) + r0;
    int col1 = ((ct0 + 1) << 4) + r0;
    int prevNode = -1;
    float s0 = 0.f, s1 = 0.f;
    #pragma unroll
    for (int rt = 0; rt < 4; ++rt)
      #pragma unroll
      for (int j = 0; j < 4; ++j){
        int row = (rt << 4) + (kg << 2) + j;
        int node = ec[row];
        float v0 = acc[rt][0][j], v1 = acc[rt][1][j];
        if (node != prevNode){
          if (prevNode >= 0){
            atomicAdd(agg + (size_t)prevNode*HH + col0, s0);
            atomicAdd(agg + (size_t)prevNode*HH + col1, s1);
          }
          prevNode = node; s0 = v0; s1 = v1;
        } else { s0 += v0; s1 += v1; }
      }
    atomicAdd(agg + (size_t)prevNode*HH + col0, s0);
    atomicAdd(agg + (size_t)prevNode*HH + col1, s1);
  }
}

// ---------------- Node kernel: GRU matmuls via 3-comp split MFMA + gates + out MLP.
__global__ __launch_bounds__(256)
void node_kernel(const float* __restrict__ xin, const float* __restrict__ prevpred,
                 const int* __restrict__ burn, int t,
                 const float* __restrict__ agg, float* __restrict__ hid,
                 const float* __restrict__ irw, const float* __restrict__ irb,
                 const float* __restrict__ iiw, const float* __restrict__ iib,
                 const float* __restrict__ inw, const float* __restrict__ inb,
                 const float* __restrict__ o1b, const float* __restrict__ o2b,
                 const float* __restrict__ o3w, const float* __restrict__ o3b,
                 const u16* __restrict__ packs, float* __restrict__ out){
  __shared__ __align__(16) u16 ag0[32*128], ag1[32*128], ag2[32*128];
  __shared__ __align__(16) u16 hHi[32*128], hLo[32*128];
  __shared__ __align__(16) u16 p1Hi[32*128], p1Lo[32*128];
  __shared__ float p2L[32][136];
  __shared__ float xLs[32][4];
  const int tid = threadIdx.x;
  const int n0 = blockIdx.x << 5;
  const float* __restrict__ xs = (t == 0 || t < burn[0]) ? xin : prevpred;

  #pragma unroll
  for (int it = 0; it < 4; ++it){
    int s = tid + (it << 8);
    int r = s >> 5, c4 = s & 31;
    int node = n0 + r; if (node > NN-1) node = NN-1;
    float4 v = *(const float4*)(agg + (size_t)node*HH + (c4 << 2));
    ushort4 q0, q1, q2;
    const float* pv = (const float*)&v;
    u16* q0p = (u16*)&q0; u16* q1p = (u16*)&q1; u16* q2p = (u16*)&q2;
    #pragma unroll
    for (int e = 0; e < 4; ++e){
      float x = pv[e];
      u16 a0 = f2b(x); float rr = x - b2f(a0);
      u16 a1 = f2b(rr); rr -= b2f(a1);
      q0p[e] = a0; q1p[e] = a1; q2p[e] = f2b(rr);
    }
    int idx = (r << 7) + (((c4 >> 1) ^ (r & 7)) << 3) + ((c4 & 1) << 2);
    *(ushort4*)(ag0 + idx) = q0;
    *(ushort4*)(ag1 + idx) = q1;
    *(ushort4*)(ag2 + idx) = q2;
  }
  if (tid < 128){
    int r = tid >> 2, c = tid & 3;
    int node = n0 + r; if (node > NN-1) node = NN-1;
    xLs[r][c] = xs[(size_t)node*CC + c];
  }
  __syncthreads();

  const int lane = tid & 63, wid = tid >> 6;
  const int ct0 = wid << 1;
  const int r0 = lane & 15, r1 = r0 + 16, kg = lane >> 4;

  // GRU matmuls via 3-comp split MFMA: aR/aI/aH = agg @ {whr, whi, whh}
  f32x4 aR[2][2], aI[2][2], aH[2][2];
  #pragma unroll
  for (int a = 0; a < 2; ++a){
    aR[a][0]=zero4(); aR[a][1]=zero4(); aI[a][0]=zero4(); aI[a][1]=zero4();
    aH[a][0]=zero4(); aH[a][1]=zero4();
  }
  #pragma unroll
  for (int kt = 0; kt < 4; ++kt){
    int sl = (kt << 2) + kg;
    bf16x8 a00 = ldA(ag0, r0, sl), a01 = ldA(ag1, r0, sl), a02 = ldA(ag2, r0, sl);
    bf16x8 a10 = ldA(ag0, r1, sl), a11 = ldA(ag1, r1, sl), a12 = ldA(ag2, r1, sl);
    #pragma unroll
    for (int ctl = 0; ctl < 2; ++ctl){
      #pragma unroll
      for (int m = 0; m < 3; ++m){
        int fb = FG + m*96 + (kt << 3) + ct0 + ctl;
        bf16x8 b0 = ldB(packs, fb,      lane);
        bf16x8 b1 = ldB(packs, fb + 32, lane);
        bf16x8 b2 = ldB(packs, fb + 64, lane);
        f32x4* A0 = m == 0 ? &aR[0][ctl] : (m == 1 ? &aI[0][ctl] : &aH[0][ctl]);
        f32x4* A1 = m == 0 ? &aR[1][ctl] : (m == 1 ? &aI[1][ctl] : &aH[1][ctl]);
        *A0 = mfmab(a00, b0, *A0);
        *A0 = mfmab(a01, b0, *A0);
        *A0 = mfmab(a00, b1, *A0);
        *A0 = mfmab(a02, b0, *A0);
        *A0 = mfmab(a01, b1, *A0);
        *A0 = mfmab(a00, b2, *A0);
        *A1 = mfmab(a10, b0, *A1);
        *A1 = mfmab(a11, b0, *A1);
        *A1 = mfmab(a10, b1, *A1);
        *A1 = mfmab(a12, b0, *A1);
        *A1 = mfmab(a11, b1, *A1);
        *A1 = mfmab(a10, b2, *A1);
      }
    }
  }

  // gates + hidden update, in MFMA C/D layout: row = rt*16+kg*4+j, col = (ct0+ctl)*16+r0
  #pragma unroll
  for (int ctl = 0; ctl < 2; ++ctl){
    int col = ((ct0 + ctl) << 4) + r0;
    float wr[CC], wi[CC], wn[CC];
    #pragma unroll
    for (int c = 0; c < CC; ++c){ wr[c]=irw[c*HH+col]; wi[c]=iiw[c*HH+col]; wn[c]=inw[c*HH+col]; }
    float rb = irb[col], ib = iib[col], nb = inb[col];
    #pragma unroll
    for (int rt = 0; rt < 2; ++rt)
      #pragma unroll
      for (int j = 0; j < 4; ++j){
        int row = (rt << 4) + (kg << 2) + j;
        int node = n0 + row;
        int nodec = node > NN-1 ? NN-1 : node;
        float xr = rb, xi = ib, xn = nb;
        #pragma unroll
        for (int c = 0; c < CC; ++c){
          float xv = xLs[row][c];
          xr = fmaf(xv, wr[c], xr); xi = fmaf(xv, wi[c], xi); xn = fmaf(xv, wn[c], xn);
        }
        float r = 1.f / (1.f + expf(-(xr + aR[rt][ctl][j])));
        float i = 1.f / (1.f + expf(-(xi + aI[rt][ctl][j])));
        float n = tanhf(xn + r * aH[rt][ctl][j]);
        float hold = hid[(size_t)nodec*HH + col];
        float hnew = (1.f - i)*n + i*hold;
        if (node < NN) hid[(size_t)node*HH + col] = hnew;
        u16 a = f2b(hnew);
        int idx = (row << 7) + (((col >> 3) ^ (row & 7)) << 3) + (col & 7);
        hHi[idx] = a;
        hLo[idx] = f2b(hnew - b2f(a));
      }
  }
  __syncthreads();

  // out1: relu(h @ O1 + b1) via 3-term split MFMA -> p1 hi/lo
  {
    f32x4 q[2][2];
    q[0][0]=zero4(); q[0][1]=zero4(); q[1][0]=zero4(); q[1][1]=zero4();
    #pragma unroll
    for (int kt = 0; kt < 4; ++kt){
      int sl = (kt << 2) + kg;
      bf16x8 ah0 = ldA(hHi, r0, sl), al0 = ldA(hLo, r0, sl);
      bf16x8 ah1 = ldA(hHi, r1, sl), al1 = ldA(hLo, r1, sl);
      #pragma unroll
      for (int ctl = 0; ctl < 2; ++ctl){
        int fo = FO + (kt << 3) + ct0 + ctl;
        bf16x8 bh = ldB(packs, fo, lane);
        bf16x8 bl = ldB(packs, fo + 32, lane);
        q[0][ctl] = mfmab(ah0, bh, q[0][ctl]);
        q[0][ctl] = mfmab(al0, bh, q[0][ctl]);
        q[0][ctl] = mfmab(ah0, bl, q[0][ctl]);
        q[1][ctl] = mfmab(ah1, bh, q[1][ctl]);
        q[1][ctl] = mfmab(al1, bh, q[1][ctl]);
        q[1][ctl] = mfmab(ah1, bl, q[1][ctl]);
      }
    }
    #pragma unroll
    for (int ctl = 0; ctl < 2; ++ctl){
      int col = ((ct0 + ctl) << 4) + r0;
      float bb = o1b[col];
      #pragma unroll
      for (int rt = 0; rt < 2; ++rt)
        #pragma unroll
        for (int j = 0; j < 4; ++j){
          int row = (rt << 4) + (kg << 2) + j;
          float v = q[rt][ctl][j] + bb; v = v > 0.f ? v : 0.f;
          u16 a = f2b(v);
          int idx = (row << 7) + (((col >> 3) ^ (row & 7)) << 3) + (col & 7);
          p1Hi[idx] = a;
          p1Lo[idx] = f2b(v - b2f(a));
        }
    }
  }
  __syncthreads();

  // out2: relu(p1 @ O2 + b2) via 3-term split MFMA -> p2 f32
  {
    f32x4 q[2][2];
    q[0][0]=zero4(); q[0][1]=zero4(); q[1][0]=zero4(); q[1][1]=zero4();
    #pragma unroll
    for (int kt = 0; kt < 4; ++kt){
      int sl = (kt << 2) + kg;
      bf16x8 ah0 = ldA(p1Hi, r0, sl), al0 = ldA(p1Lo, r0, sl);
      bf16x8 ah1 = ldA(p1Hi, r1, sl), al1 = ldA(p1Lo, r1, sl);
      #pragma unroll
      for (int ctl = 0; ctl < 2; ++ctl){
        int fo = FO + 64 + (kt << 3) + ct0 + ctl;
        bf16x8 bh = ldB(packs, fo, lane);
        bf16x8 bl = ldB(packs, fo + 32, lane);
        q[0][ctl] = mfmab(ah0, bh, q[0][ctl]);
        q[0][ctl] = mfmab(al0, bh, q[0][ctl]);
        q[0][ctl] = mfmab(ah0, bl, q[0][ctl]);
        q[1][ctl] = mfmab(ah1, bh, q[1][ctl]);
        q[1][ctl] = mfmab(al1, bh, q[1][ctl]);
        q[1][ctl] = mfmab(ah1, bl, q[1][ctl]);
      }
    }
    #pragma unroll
    for (int ctl = 0; ctl < 2; ++ctl){
      int col = ((ct0 + ctl) << 4) + r0;
      float bb = o2b[col];
      #pragma unroll
      for (int rt = 0; rt < 2; ++rt)
        #pragma unroll
        for (int j = 0; j < 4; ++j){
          int row = (rt << 4) + (kg << 2) + j;
          float v = q[rt][ctl][j] + bb; v = v > 0.f ? v : 0.f;
          p2L[row][col] = v;
        }
    }
  }
  __syncthreads();

  // out3: H -> 4, then pred = x + relu(...)
  if (tid < 128){
    int r = tid >> 2, c = tid & 3;
    int node = n0 + r;
    if (node < NN){
      float s = o3b[c];
      for (int kk = 0; kk < HH; ++kk) s = fmaf(p2L[r][kk], o3w[kk*CC + c], s);
      float v = fmaxf(s, 0.f);
      out[((size_t)t*NN + node)*CC + c] = xLs[r][c] + v;
    }
  }
}

extern "C" void kernel_launch(void* const* d_in, const int* in_sizes, int n_in,
                              void* d_out, int out_size, void* d_ws, size_t ws_size,
                              hipStream_t stream){
  const float* inputs = (const float*)d_in[0];
  const float* fc1w = (const float*)d_in[1];
  const float* fc1b = (const float*)d_in[2];
  const float* fc2w = (const float*)d_in[3];
  const float* fc2b = (const float*)d_in[4];
  const float* whr  = (const float*)d_in[5];
  const float* whi  = (const float*)d_in[6];
  const float* whh  = (const float*)d_in[7];
  const float* irw  = (const float*)d_in[8];
  const float* irb  = (const float*)d_in[9];
  const float* iiw  = (const float*)d_in[10];
  const float* iib  = (const float*)d_in[11];
  const float* inw  = (const float*)d_in[12];
  const float* inb  = (const float*)d_in[13];
  const float* o1w  = (const float*)d_in[14];
  const float* o1b  = (const float*)d_in[15];
  const float* o2w  = (const float*)d_in[16];
  const float* o2b  = (const float*)d_in[17];
  const float* o3w  = (const float*)d_in[18];
  const float* o3b  = (const float*)d_in[19];
  const int* edge   = (const int*)d_in[20];
  const int* burn   = (const int*)d_in[21];
  float* out = (float*)d_out;

  u8* ws = (u8*)d_ws;
  float* hid   = (float*)(ws);               // N*H fp32 = 5,120,000 B
  float* agg   = (float*)(ws + 5120000);     // N*H fp32 = 5,120,000 B
  float* UV    = (float*)(ws + 10240000);    // 6*N*H fp32 = 30,720,000 B
  u16*   packs = (u16*)(ws + 40960000);      // 1184 frags = 1,212,416 B
  int*   pr    = (int*)(ws + 42172416);      // 640,000 B
  int*   pc    = (int*)(ws + 42812416);      // 640,000 B
  int*   hist  = (int*)(ws + 43452416);      // 40,000 B
  int*   cursor= (int*)(ws + 43492416);      // 40,000 B

  hipMemsetAsync(hid, 0, 5120000, stream);
  hipMemsetAsync(hist, 0, 40000, stream);

  PSrc ps; ps.w2 = fc2w; ps.w1 = fc1w; ps.o1 = o1w; ps.o2 = o2w;
  ps.gr = whr; ps.gi = whi; ps.gh = whh;
  hipLaunchKernelGGL(pack_weights, dim3(NFRAG), dim3(64), 0, stream, ps, packs);
  hipLaunchKernelGGL(hist_kernel, dim3((EE+255)/256), dim3(256), 0, stream, edge, hist);
  hipLaunchKernelGGL(scan_kernel, dim3(1), dim3(256), 0, stream, hist, cursor);
  hipLaunchKernelGGL(scatter_kernel, dim3((EE+255)/256), dim3(256), 0, stream, edge, cursor, pr, pc);

  const int nblk = (NN + 31) / 32;  // 313
  for (int t = 0; t < TT; ++t){
    hipMemsetAsync(agg, 0, 5120000, stream);
    hipLaunchKernelGGL(uv_kernel, dim3(nblk), dim3(256), 0, stream, hid, packs, UV);
    hipLaunchKernelGGL(edge_kernel, dim3(EE/64), dim3(256), 0, stream,
                       pr, pc, UV, fc1b, fc2b, packs, agg);
    hipLaunchKernelGGL(node_kernel, dim3(nblk), dim3(256), 0, stream,
                       inputs + (size_t)t*NN*CC, out + (size_t)(t > 0 ? t-1 : 0)*NN*CC, burn, t,
                       agg, hid, irw, irb, iiw, iib, inw, inb,
                       o1b, o2b, o3w, o3b, packs, out);
  }
}

// Round 14
// 1727.960 us; speedup vs baseline: 3.1203x; 1.0966x over previous
//
#include <hip/hip_runtime.h>

#define TT 10
#define NN 10000
#define CC 4
#define HH 128
#define EE 160000

typedef unsigned char u8;
typedef unsigned short u16;
typedef unsigned int u32;
typedef __attribute__((ext_vector_type(8))) short bf16x8;
typedef __attribute__((ext_vector_type(4))) float f32x4;

// packed fragment regions (each frag = 64 lanes * 16B = 1KB)
#define FW2 0      // W2: 96 hi + 96 lo
#define FW1 192    // W1: 6 matrices * 3 comps * 32
#define FO  768    // O1 hi/lo (32+32), O2 hi/lo (32+32)
#define FG  896    // GRU whr/whi/whh: 3 matrices * 3 comps * 32
#define NFRAG 1184

__device__ __forceinline__ u16 f2b(float x){ // f32 -> bf16 RNE
  union { float f; u32 u; } v; v.f = x;
  return (u16)((v.u + 0x7fffu + ((v.u >> 16) & 1u)) >> 16);
}
__device__ __forceinline__ float b2f(u16 b){
  union { u32 u; float f; } v; v.u = ((u32)b) << 16;
  return v.f;
}
// HW-exp tanh: 1 - 2/(exp2(2x*log2e)+1); <=3e-7 rel err, correct saturation.
__device__ __forceinline__ float fast_tanh(float x){
  float e = __builtin_amdgcn_exp2f(x * 2.885390081777927f);
  return 1.f - 2.f * __builtin_amdgcn_rcpf(e + 1.f);
}
__device__ __forceinline__ f32x4 zero4(){ f32x4 z = {0.f,0.f,0.f,0.f}; return z; }
__device__ __forceinline__ f32x4 mfmab(bf16x8 a, bf16x8 b, f32x4 c){
  return __builtin_amdgcn_mfma_f32_16x16x32_bf16(a, b, c, 0, 0, 0);
}
// A-fragment read from XOR-swizzled LDS tile (rows of 128 u16 = 16 slots of 16B)
__device__ __forceinline__ bf16x8 ldA(const u16* L, int row, int sl){
  return *(const bf16x8*)(L + (row << 7) + ((sl ^ (row & 7)) << 3));
}
__device__ __forceinline__ bf16x8 ldB(const u16* packs, int frag, int lane){
  return *(const bf16x8*)(packs + frag*512 + lane*8);
}

struct PSrc { const float* w2; const float* w1; const float* o1; const float* o2;
              const float* gr; const float* gi; const float* gh; };

// ---------------- All weights -> bf16-component MFMA B-fragments.
__global__ void pack_weights(PSrc ps, u16* __restrict__ dst){
  int f = blockIdx.x, l = threadIdx.x;
  const float* src; int comp, kt, ct;
  if (f < 192){
    comp = f / 96; int g = f % 96;
    int br = g >> 5, rem = g & 31; kt = rem >> 3; ct = rem & 7;
    src = ps.w2 + (size_t)br*HH*HH;
  } else if (f < 768){
    int g = f - 192; int m = g / 96; int rem = g % 96;
    comp = rem >> 5; int idx = rem & 31; kt = idx >> 3; ct = idx & 7;
    src = ps.w1 + (size_t)m*HH*HH;
  } else if (f < 896){
    int g = f - 768; int mat = g >> 6; int rem = g & 63;
    comp = rem >> 5; int idx = rem & 31; kt = idx >> 3; ct = idx & 7;
    src = mat ? ps.o2 : ps.o1;
  } else {
    int g = f - 896; int mat = g / 96; int rem = g % 96;
    comp = rem >> 5; int idx = rem & 31; kt = idx >> 3; ct = idx & 7;
    src = mat == 0 ? ps.gr : (mat == 1 ? ps.gi : ps.gh);
  }
  int col = (ct << 4) + (l & 15);
  u16* d = dst + f*512 + l*8;
  #pragma unroll
  for (int j = 0; j < 8; ++j){
    int kk = (kt << 5) + ((l >> 4) << 3) + j;
    float v = src[kk*HH + col];
    u16 c0 = f2b(v); float r = v - b2f(c0);
    u16 c1 = f2b(r); r -= b2f(c1);
    u16 c2 = f2b(r);
    d[j] = comp == 0 ? c0 : (comp == 1 ? c1 : c2);
  }
}

// ---------------- Edge sort by receiver (counting sort), once per call.
__global__ void hist_kernel(const int* __restrict__ edge, int* __restrict__ hist){
  int i = blockIdx.x*256 + threadIdx.x;
  if (i < EE) atomicAdd(&hist[edge[EE + i]], 1);
}
__global__ void scan_kernel(const int* __restrict__ hist, int* __restrict__ cursor){
  __shared__ int part[256];
  __shared__ int partx[256];
  int tid = threadIdx.x;
  int base = tid*40;
  int s = 0;
  for (int j = 0; j < 40; ++j){ int b = base+j; if (b < NN) s += hist[b]; }
  part[tid] = s;
  __syncthreads();
  if (tid == 0){ int acc = 0; for (int i = 0; i < 256; ++i){ partx[i] = acc; acc += part[i]; } }
  __syncthreads();
  int acc = partx[tid];
  for (int j = 0; j < 40; ++j){ int b = base+j; if (b < NN){ cursor[b] = acc; acc += hist[b]; } }
}
__global__ void scatter_kernel(const int* __restrict__ edge, int* __restrict__ cursor,
                               int* __restrict__ pr, int* __restrict__ pc){
  int i = blockIdx.x*256 + threadIdx.x;
  if (i < EE){
    int r = edge[i], c = edge[EE + i];
    int pos = atomicAdd(&cursor[c], 1);
    pr[pos] = r; pc[pos] = c;
  }
}

// ---------------- U/V precompute via MFMA, 3-component split (f32-faithful, ~2^-26).
__global__ __launch_bounds__(256)
void uv_kernel(const float* __restrict__ hid, const u16* __restrict__ packs,
               float* __restrict__ UV){
  __shared__ __align__(16) u16 h0[32*128], h1[32*128], h2[32*128];
  const int tid = threadIdx.x;
  const int lane = tid & 63, wid = tid >> 6;
  const int n0 = blockIdx.x << 5;

  #pragma unroll
  for (int it = 0; it < 4; ++it){
    int s = tid + (it << 8);
    int r = s >> 5, c4 = s & 31;
    int node = n0 + r; if (node > NN-1) node = NN-1;
    float4 v = *(const float4*)(hid + (size_t)node*HH + (c4 << 2));
    ushort4 q0, q1, q2;
    const float* pv = (const float*)&v;
    u16* q0p = (u16*)&q0; u16* q1p = (u16*)&q1; u16* q2p = (u16*)&q2;
    #pragma unroll
    for (int e = 0; e < 4; ++e){
      float x = pv[e];
      u16 a0 = f2b(x); float rr = x - b2f(a0);
      u16 a1 = f2b(rr); rr -= b2f(a1);
      q0p[e] = a0; q1p[e] = a1; q2p[e] = f2b(rr);
    }
    int idx = (r << 7) + (((c4 >> 1) ^ (r & 7)) << 3) + ((c4 & 1) << 2);
    *(ushort4*)(h0 + idx) = q0;
    *(ushort4*)(h1 + idx) = q1;
    *(ushort4*)(h2 + idx) = q2;
  }
  __syncthreads();

  const int ct0 = wid << 1;
  const int r0 = lane & 15, r1 = r0 + 16, kg = lane >> 4;

  for (int m = 0; m < 6; ++m){
    f32x4 acc[2][2];
    acc[0][0]=zero4(); acc[0][1]=zero4(); acc[1][0]=zero4(); acc[1][1]=zero4();
    #pragma unroll
    for (int kt = 0; kt < 4; ++kt){
      int sl = (kt << 2) + kg;
      bf16x8 a00 = ldA(h0, r0, sl), a01 = ldA(h1, r0, sl), a02 = ldA(h2, r0, sl);
      bf16x8 a10 = ldA(h0, r1, sl), a11 = ldA(h1, r1, sl), a12 = ldA(h2, r1, sl);
      #pragma unroll
      for (int ctl = 0; ctl < 2; ++ctl){
        int fb = FW1 + m*96 + (kt << 3) + ct0 + ctl;
        bf16x8 b0 = ldB(packs, fb,      lane);
        bf16x8 b1 = ldB(packs, fb + 32, lane);
        bf16x8 b2 = ldB(packs, fb + 64, lane);
        acc[0][ctl] = mfmab(a00, b0, acc[0][ctl]);
        acc[0][ctl] = mfmab(a01, b0, acc[0][ctl]);
        acc[0][ctl] = mfmab(a00, b1, acc[0][ctl]);
        acc[0][ctl] = mfmab(a02, b0, acc[0][ctl]);
        acc[0][ctl] = mfmab(a01, b1, acc[0][ctl]);
        acc[0][ctl] = mfmab(a00, b2, acc[0][ctl]);
        acc[1][ctl] = mfmab(a10, b0, acc[1][ctl]);
        acc[1][ctl] = mfmab(a11, b0, acc[1][ctl]);
        acc[1][ctl] = mfmab(a10, b1, acc[1][ctl]);
        acc[1][ctl] = mfmab(a12, b0, acc[1][ctl]);
        acc[1][ctl] = mfmab(a11, b1, acc[1][ctl]);
        acc[1][ctl] = mfmab(a10, b2, acc[1][ctl]);
      }
    }
    #pragma unroll
    for (int ctl = 0; ctl < 2; ++ctl)
      #pragma unroll
      for (int rt = 0; rt < 2; ++rt)
        #pragma unroll
        for (int j = 0; j < 4; ++j){
          int row = (rt << 4) + (kg << 2) + j;
          int col = ((ct0 + ctl) << 4) + r0;
          int node = n0 + row;
          if (node < NN) UV[((size_t)m*NN + node)*HH + col] = acc[rt][ctl][j];
        }
  }
}

// ---------------- Edge kernel: 32 sorted edges/block (round-11 geometry: VGPR~60, LDS 17KB).
__global__ __launch_bounds__(256)
void edge_kernel(const int* __restrict__ pr, const int* __restrict__ pc,
                 const float* __restrict__ UV,
                 const float* __restrict__ b1, const float* __restrict__ b2,
                 const u16* __restrict__ packs, float* __restrict__ agg){
  __shared__ __align__(16) u16 m1hi[32*128];
  __shared__ __align__(16) u16 m1lo[32*128];
  __shared__ int er[32], ec[32];
  const int tid = threadIdx.x;
  const int lane = tid & 63, wid = tid >> 6;
  const int e0 = blockIdx.x << 5;

  if (tid < 32) er[tid] = pr[e0 + tid];
  else if (tid < 64) ec[tid - 32] = pc[e0 + tid - 32];

  const int c4 = tid & 31;
  const int cOff = c4 << 2;
  const int ct0 = wid << 1;
  const int r0 = lane & 15, r1 = r0 + 16, kg = lane >> 4;

  f32x4 acc[2][2];
  acc[0][0]=zero4(); acc[0][1]=zero4(); acc[1][0]=zero4(); acc[1][1]=zero4();

  for (int k = 0; k < 3; ++k){
    __syncthreads();
    {
      float4 b = *(const float4*)(b1 + k*HH + cOff);
      const float* __restrict__ Ub = UV + (size_t)(2*k)*NN*HH;
      const float* __restrict__ Vb = UV + (size_t)(2*k + 1)*NN*HH;
      #pragma unroll
      for (int it = 0; it < 4; ++it){
        int e = (tid >> 5) + (it << 3);
        float4 u = *(const float4*)(Ub + (size_t)er[e]*HH + cOff);
        float4 v = *(const float4*)(Vb + (size_t)ec[e]*HH + cOff);
        float m0 = fast_tanh(u.x + v.x + b.x);
        float m1 = fast_tanh(u.y + v.y + b.y);
        float m2 = fast_tanh(u.z + v.z + b.z);
        float m3 = fast_tanh(u.w + v.w + b.w);
        ushort4 hi, lo;
        hi.x = f2b(m0); lo.x = f2b(m0 - b2f(hi.x));
        hi.y = f2b(m1); lo.y = f2b(m1 - b2f(hi.y));
        hi.z = f2b(m2); lo.z = f2b(m2 - b2f(hi.z));
        hi.w = f2b(m3); lo.w = f2b(m3 - b2f(hi.w));
        int idx = (e << 7) + (((c4 >> 1) ^ (e & 7)) << 3) + ((c4 & 1) << 2);
        *(ushort4*)(m1hi + idx) = hi;
        *(ushort4*)(m1lo + idx) = lo;
      }
    }
    __syncthreads();

    f32x4 lacc[2][2];
    lacc[0][0]=zero4(); lacc[0][1]=zero4(); lacc[1][0]=zero4(); lacc[1][1]=zero4();
    #pragma unroll
    for (int kt = 0; kt < 4; ++kt){
      int sl = (kt << 2) + kg;
      bf16x8 a0h = ldA(m1hi, r0, sl);
      bf16x8 a1h = ldA(m1hi, r1, sl);
      bf16x8 a0l = ldA(m1lo, r0, sl);
      bf16x8 a1l = ldA(m1lo, r1, sl);
      #pragma unroll
      for (int ctl = 0; ctl < 2; ++ctl){
        int fh = FW2 + k*32 + (kt << 3) + ct0 + ctl;
        bf16x8 bh = ldB(packs, fh, lane);
        bf16x8 bl = ldB(packs, fh + 96, lane);
        lacc[0][ctl] = mfmab(a0h, bh, lacc[0][ctl]);
        lacc[0][ctl] = mfmab(a0l, bh, lacc[0][ctl]);
        lacc[0][ctl] = mfmab(a0h, bl, lacc[0][ctl]);
        lacc[1][ctl] = mfmab(a1h, bh, lacc[1][ctl]);
        lacc[1][ctl] = mfmab(a1l, bh, lacc[1][ctl]);
        lacc[1][ctl] = mfmab(a1h, bl, lacc[1][ctl]);
      }
    }
    #pragma unroll
    for (int ctl = 0; ctl < 2; ++ctl){
      int col = ((ct0 + ctl) << 4) + r0;
      float bb = b2[k*HH + col];
      #pragma unroll
      for (int rt = 0; rt < 2; ++rt)
        #pragma unroll
        for (int j = 0; j < 4; ++j)
          acc[rt][ctl][j] += fast_tanh(lacc[rt][ctl][j] + bb);
    }
  }

  // merged scatter: sorted ec -> run-length accumulate, flush once per receiver run
  {
    int col0 = (ct0 << 4) + r0;
    int col1 = ((ct0 + 1) << 4) + r0;
    int prevNode = -1;
    float s0 = 0.f, s1 = 0.f;
    #pragma unroll
    for (int rt = 0; rt < 2; ++rt)
      #pragma unroll
      for (int j = 0; j < 4; ++j){
        int row = (rt << 4) + (kg << 2) + j;
        int node = ec[row];
        float v0 = acc[rt][0][j], v1 = acc[rt][1][j];
        if (node != prevNode){
          if (prevNode >= 0){
            atomicAdd(agg + (size_t)prevNode*HH + col0, s0);
            atomicAdd(agg + (size_t)prevNode*HH + col1, s1);
          }
          prevNode = node; s0 = v0; s1 = v1;
        } else { s0 += v0; s1 += v1; }
      }
    atomicAdd(agg + (size_t)prevNode*HH + col0, s0);
    atomicAdd(agg + (size_t)prevNode*HH + col1, s1);
  }
}

// ---------------- Node kernel: GRU matmuls via 3-comp split MFMA + gates + out MLP.
__global__ __launch_bounds__(256)
void node_kernel(const float* __restrict__ xin, const float* __restrict__ prevpred,
                 const int* __restrict__ burn, int t,
                 const float* __restrict__ agg, float* __restrict__ hid,
                 const float* __restrict__ irw, const float* __restrict__ irb,
                 const float* __restrict__ iiw, const float* __restrict__ iib,
                 const float* __restrict__ inw, const float* __restrict__ inb,
                 const float* __restrict__ o1b, const float* __restrict__ o2b,
                 const float* __restrict__ o3w, const float* __restrict__ o3b,
                 const u16* __restrict__ packs, float* __restrict__ out){
  __shared__ __align__(16) u16 ag0[32*128], ag1[32*128], ag2[32*128];
  __shared__ __align__(16) u16 hHi[32*128], hLo[32*128];
  __shared__ __align__(16) u16 p1Hi[32*128], p1Lo[32*128];
  __shared__ float p2L[32][136];
  __shared__ float xLs[32][4];
  const int tid = threadIdx.x;
  const int n0 = blockIdx.x << 5;
  const float* __restrict__ xs = (t == 0 || t < burn[0]) ? xin : prevpred;

  #pragma unroll
  for (int it = 0; it < 4; ++it){
    int s = tid + (it << 8);
    int r = s >> 5, c4 = s & 31;
    int node = n0 + r; if (node > NN-1) node = NN-1;
    float4 v = *(const float4*)(agg + (size_t)node*HH + (c4 << 2));
    ushort4 q0, q1, q2;
    const float* pv = (const float*)&v;
    u16* q0p = (u16*)&q0; u16* q1p = (u16*)&q1; u16* q2p = (u16*)&q2;
    #pragma unroll
    for (int e = 0; e < 4; ++e){
      float x = pv[e];
      u16 a0 = f2b(x); float rr = x - b2f(a0);
      u16 a1 = f2b(rr); rr -= b2f(a1);
      q0p[e] = a0; q1p[e] = a1; q2p[e] = f2b(rr);
    }
    int idx = (r << 7) + (((c4 >> 1) ^ (r & 7)) << 3) + ((c4 & 1) << 2);
    *(ushort4*)(ag0 + idx) = q0;
    *(ushort4*)(ag1 + idx) = q1;
    *(ushort4*)(ag2 + idx) = q2;
  }
  if (tid < 128){
    int r = tid >> 2, c = tid & 3;
    int node = n0 + r; if (node > NN-1) node = NN-1;
    xLs[r][c] = xs[(size_t)node*CC + c];
  }
  __syncthreads();

  const int lane = tid & 63, wid = tid >> 6;
  const int ct0 = wid << 1;
  const int r0 = lane & 15, r1 = r0 + 16, kg = lane >> 4;

  // GRU matmuls via 3-comp split MFMA: aR/aI/aH = agg @ {whr, whi, whh}
  f32x4 aR[2][2], aI[2][2], aH[2][2];
  #pragma unroll
  for (int a = 0; a < 2; ++a){
    aR[a][0]=zero4(); aR[a][1]=zero4(); aI[a][0]=zero4(); aI[a][1]=zero4();
    aH[a][0]=zero4(); aH[a][1]=zero4();
  }
  #pragma unroll
  for (int kt = 0; kt < 4; ++kt){
    int sl = (kt << 2) + kg;
    bf16x8 a00 = ldA(ag0, r0, sl), a01 = ldA(ag1, r0, sl), a02 = ldA(ag2, r0, sl);
    bf16x8 a10 = ldA(ag0, r1, sl), a11 = ldA(ag1, r1, sl), a12 = ldA(ag2, r1, sl);
    #pragma unroll
    for (int ctl = 0; ctl < 2; ++ctl){
      #pragma unroll
      for (int m = 0; m < 3; ++m){
        int fb = FG + m*96 + (kt << 3) + ct0 + ctl;
        bf16x8 b0 = ldB(packs, fb,      lane);
        bf16x8 b1 = ldB(packs, fb + 32, lane);
        bf16x8 b2 = ldB(packs, fb + 64, lane);
        f32x4* A0 = m == 0 ? &aR[0][ctl] : (m == 1 ? &aI[0][ctl] : &aH[0][ctl]);
        f32x4* A1 = m == 0 ? &aR[1][ctl] : (m == 1 ? &aI[1][ctl] : &aH[1][ctl]);
        *A0 = mfmab(a00, b0, *A0);
        *A0 = mfmab(a01, b0, *A0);
        *A0 = mfmab(a00, b1, *A0);
        *A0 = mfmab(a02, b0, *A0);
        *A0 = mfmab(a01, b1, *A0);
        *A0 = mfmab(a00, b2, *A0);
        *A1 = mfmab(a10, b0, *A1);
        *A1 = mfmab(a11, b0, *A1);
        *A1 = mfmab(a10, b1, *A1);
        *A1 = mfmab(a12, b0, *A1);
        *A1 = mfmab(a11, b1, *A1);
        *A1 = mfmab(a10, b2, *A1);
      }
    }
  }

  // gates + hidden update, in MFMA C/D layout: row = rt*16+kg*4+j, col = (ct0+ctl)*16+r0
  #pragma unroll
  for (int ctl = 0; ctl < 2; ++ctl){
    int col = ((ct0 + ctl) << 4) + r0;
    float wr[CC], wi[CC], wn[CC];
    #pragma unroll
    for (int c = 0; c < CC; ++c){ wr[c]=irw[c*HH+col]; wi[c]=iiw[c*HH+col]; wn[c]=inw[c*HH+col]; }
    float rb = irb[col], ib = iib[col], nb = inb[col];
    #pragma unroll
    for (int rt = 0; rt < 2; ++rt)
      #pragma unroll
      for (int j = 0; j < 4; ++j){
        int row = (rt << 4) + (kg << 2) + j;
        int node = n0 + row;
        int nodec = node > NN-1 ? NN-1 : node;
        float xr = rb, xi = ib, xn = nb;
        #pragma unroll
        for (int c = 0; c < CC; ++c){
          float xv = xLs[row][c];
          xr = fmaf(xv, wr[c], xr); xi = fmaf(xv, wi[c], xi); xn = fmaf(xv, wn[c], xn);
        }
        float r = 1.f / (1.f + expf(-(xr + aR[rt][ctl][j])));
        float i = 1.f / (1.f + expf(-(xi + aI[rt][ctl][j])));
        float n = tanhf(xn + r * aH[rt][ctl][j]);
        float hold = hid[(size_t)nodec*HH + col];
        float hnew = (1.f - i)*n + i*hold;
        if (node < NN) hid[(size_t)node*HH + col] = hnew;
        u16 a = f2b(hnew);
        int idx = (row << 7) + (((col >> 3) ^ (row & 7)) << 3) + (col & 7);
        hHi[idx] = a;
        hLo[idx] = f2b(hnew - b2f(a));
      }
  }
  __syncthreads();

  // out1: relu(h @ O1 + b1) via 3-term split MFMA -> p1 hi/lo
  {
    f32x4 q[2][2];
    q[0][0]=zero4(); q[0][1]=zero4(); q[1][0]=zero4(); q[1][1]=zero4();
    #pragma unroll
    for (int kt = 0; kt < 4; ++kt){
      int sl = (kt << 2) + kg;
      bf16x8 ah0 = ldA(hHi, r0, sl), al0 = ldA(hLo, r0, sl);
      bf16x8 ah1 = ldA(hHi, r1, sl), al1 = ldA(hLo, r1, sl);
      #pragma unroll
      for (int ctl = 0; ctl < 2; ++ctl){
        int fo = FO + (kt << 3) + ct0 + ctl;
        bf16x8 bh = ldB(packs, fo, lane);
        bf16x8 bl = ldB(packs, fo + 32, lane);
        q[0][ctl] = mfmab(ah0, bh, q[0][ctl]);
        q[0][ctl] = mfmab(al0, bh, q[0][ctl]);
        q[0][ctl] = mfmab(ah0, bl, q[0][ctl]);
        q[1][ctl] = mfmab(ah1, bh, q[1][ctl]);
        q[1][ctl] = mfmab(al1, bh, q[1][ctl]);
        q[1][ctl] = mfmab(ah1, bl, q[1][ctl]);
      }
    }
    #pragma unroll
    for (int ctl = 0; ctl < 2; ++ctl){
      int col = ((ct0 + ctl) << 4) + r0;
      float bb = o1b[col];
      #pragma unroll
      for (int rt = 0; rt < 2; ++rt)
        #pragma unroll
        for (int j = 0; j < 4; ++j){
          int row = (rt << 4) + (kg << 2) + j;
          float v = q[rt][ctl][j] + bb; v = v > 0.f ? v : 0.f;
          u16 a = f2b(v);
          int idx = (row << 7) + (((col >> 3) ^ (row & 7)) << 3) + (col & 7);
          p1Hi[idx] = a;
          p1Lo[idx] = f2b(v - b2f(a));
        }
    }
  }
  __syncthreads();

  // out2: relu(p1 @ O2 + b2) via 3-term split MFMA -> p2 f32
  {
    f32x4 q[2][2];
    q[0][0]=zero4(); q[0][1]=zero4(); q[1][0]=zero4(); q[1][1]=zero4();
    #pragma unroll
    for (int kt = 0; kt < 4; ++kt){
      int sl = (kt << 2) + kg;
      bf16x8 ah0 = ldA(p1Hi, r0, sl), al0 = ldA(p1Lo, r0, sl);
      bf16x8 ah1 = ldA(p1Hi, r1, sl), al1 = ldA(p1Lo, r1, sl);
      #pragma unroll
      for (int ctl = 0; ctl < 2; ++ctl){
        int fo = FO + 64 + (kt << 3) + ct0 + ctl;
        bf16x8 bh = ldB(packs, fo, lane);
        bf16x8 bl = ldB(packs, fo + 32, lane);
        q[0][ctl] = mfmab(ah0, bh, q[0][ctl]);
        q[0][ctl] = mfmab(al0, bh, q[0][ctl]);
        q[0][ctl] = mfmab(ah0, bl, q[0][ctl]);
        q[1][ctl] = mfmab(ah1, bh, q[1][ctl]);
        q[1][ctl] = mfmab(al1, bh, q[1][ctl]);
        q[1][ctl] = mfmab(ah1, bl, q[1][ctl]);
      }
    }
    #pragma unroll
    for (int ctl = 0; ctl < 2; ++ctl){
      int col = ((ct0 + ctl) << 4) + r0;
      float bb = o2b[col];
      #pragma unroll
      for (int rt = 0; rt < 2; ++rt)
        #pragma unroll
        for (int j = 0; j < 4; ++j){
          int row = (rt << 4) + (kg << 2) + j;
          float v = q[rt][ctl][j] + bb; v = v > 0.f ? v : 0.f;
          p2L[row][col] = v;
        }
    }
  }
  __syncthreads();

  // out3: H -> 4, then pred = x + relu(...)
  if (tid < 128){
    int r = tid >> 2, c = tid & 3;
    int node = n0 + r;
    if (node < NN){
      float s = o3b[c];
      for (int kk = 0; kk < HH; ++kk) s = fmaf(p2L[r][kk], o3w[kk*CC + c], s);
      float v = fmaxf(s, 0.f);
      out[((size_t)t*NN + node)*CC + c] = xLs[r][c] + v;
    }
  }
}

extern "C" void kernel_launch(void* const* d_in, const int* in_sizes, int n_in,
                              void* d_out, int out_size, void* d_ws, size_t ws_size,
                              hipStream_t stream){
  const float* inputs = (const float*)d_in[0];
  const float* fc1w = (const float*)d_in[1];
  const float* fc1b = (const float*)d_in[2];
  const float* fc2w = (const float*)d_in[3];
  const float* fc2b = (const float*)d_in[4];
  const float* whr  = (const float*)d_in[5];
  const float* whi  = (const float*)d_in[6];
  const float* whh  = (const float*)d_in[7];
  const float* irw  = (const float*)d_in[8];
  const float* irb  = (const float*)d_in[9];
  const float* iiw  = (const float*)d_in[10];
  const float* iib  = (const float*)d_in[11];
  const float* inw  = (const float*)d_in[12];
  const float* inb  = (const float*)d_in[13];
  const float* o1w  = (const float*)d_in[14];
  const float* o1b  = (const float*)d_in[15];
  const float* o2w  = (const float*)d_in[16];
  const float* o2b  = (const float*)d_in[17];
  const float* o3w  = (const float*)d_in[18];
  const float* o3b  = (const float*)d_in[19];
  const int* edge   = (const int*)d_in[20];
  const int* burn   = (const int*)d_in[21];
  float* out = (float*)d_out;

  u8* ws = (u8*)d_ws;
  float* hid   = (float*)(ws);               // N*H fp32 = 5,120,000 B
  float* agg   = (float*)(ws + 5120000);     // N*H fp32 = 5,120,000 B
  float* UV    = (float*)(ws + 10240000);    // 6*N*H fp32 = 30,720,000 B
  u16*   packs = (u16*)(ws + 40960000);      // 1184 frags = 1,212,416 B
  int*   pr    = (int*)(ws + 42172416);      // 640,000 B
  int*   pc    = (int*)(ws + 42812416);      // 640,000 B
  int*   hist  = (int*)(ws + 43452416);      // 40,000 B
  int*   cursor= (int*)(ws + 43492416);      // 40,000 B

  hipMemsetAsync(hid, 0, 5120000, stream);
  hipMemsetAsync(hist, 0, 40000, stream);

  PSrc ps; ps.w2 = fc2w; ps.w1 = fc1w; ps.o1 = o1w; ps.o2 = o2w;
  ps.gr = whr; ps.gi = whi; ps.gh = whh;
  hipLaunchKernelGGL(pack_weights, dim3(NFRAG), dim3(64), 0, stream, ps, packs);
  hipLaunchKernelGGL(hist_kernel, dim3((EE+255)/256), dim3(256), 0, stream, edge, hist);
  hipLaunchKernelGGL(scan_kernel, dim3(1), dim3(256), 0, stream, hist, cursor);
  hipLaunchKernelGGL(scatter_kernel, dim3((EE+255)/256), dim3(256), 0, stream, edge, cursor, pr, pc);

  const int nblk = (NN + 31) / 32;  // 313
  for (int t = 0; t < TT; ++t){
    hipMemsetAsync(agg, 0, 5120000, stream);
    hipLaunchKernelGGL(uv_kernel, dim3(nblk), dim3(256), 0, stream, hid, packs, UV);
    hipLaunchKernelGGL(edge_kernel, dim3(EE/32), dim3(256), 0, stream,
                       pr, pc, UV, fc1b, fc2b, packs, agg);
    hipLaunchKernelGGL(node_kernel, dim3(nblk), dim3(256), 0, stream,
                       inputs + (size_t)t*NN*CC, out + (size_t)(t > 0 ? t-1 : 0)*NN*CC, burn, t,
                       agg, hid, irw, irb, iiw, iib, inw, inb,
                       o1b, o2b, o3w, o3b, packs, out);
  }
}

// Round 16
// 1567.665 us; speedup vs baseline: 3.4394x; 1.1023x over previous
//
#include <hip/hip_runtime.h>

#define TT 10
#define NN 10000
#define CC 4
#define HH 128
#define EE 160000

typedef unsigned char u8;
typedef unsigned short u16;
typedef unsigned int u32;
typedef __attribute__((ext_vector_type(8))) short bf16x8;
typedef __attribute__((ext_vector_type(4))) float f32x4;

// packed fragment regions (each frag = 64 lanes * 16B = 1KB)
#define FW2 0      // W2: 96 hi + 96 lo
#define FW1 192    // W1: 6 matrices * 3 comps * 32
#define FO  768    // O1 hi/lo (32+32), O2 hi/lo (32+32)
#define FG  896    // GRU whr/whi/whh: 3 matrices * 3 comps * 32
#define NFRAG 1184

__device__ __forceinline__ u16 f2b(float x){ // f32 -> bf16 RNE
  union { float f; u32 u; } v; v.f = x;
  return (u16)((v.u + 0x7fffu + ((v.u >> 16) & 1u)) >> 16);
}
__device__ __forceinline__ float b2f(u16 b){
  union { u32 u; float f; } v; v.u = ((u32)b) << 16;
  return v.f;
}
// HW-exp tanh: 1 - 2/(exp2(2x*log2e)+1); <=3e-7 rel err, correct saturation.
__device__ __forceinline__ float fast_tanh(float x){
  float e = __builtin_amdgcn_exp2f(x * 2.885390081777927f);
  return 1.f - 2.f * __builtin_amdgcn_rcpf(e + 1.f);
}
__device__ __forceinline__ f32x4 zero4(){ f32x4 z = {0.f,0.f,0.f,0.f}; return z; }
__device__ __forceinline__ f32x4 mfmab(bf16x8 a, bf16x8 b, f32x4 c){
  return __builtin_amdgcn_mfma_f32_16x16x32_bf16(a, b, c, 0, 0, 0);
}
// A-fragment read from XOR-swizzled LDS tile (rows of 128 u16 = 16 slots of 16B)
__device__ __forceinline__ bf16x8 ldA(const u16* L, int row, int sl){
  return *(const bf16x8*)(L + (row << 7) + ((sl ^ (row & 7)) << 3));
}
__device__ __forceinline__ bf16x8 ldB(const u16* packs, int frag, int lane){
  return *(const bf16x8*)(packs + frag*512 + lane*8);
}

struct PSrc { const float* w2; const float* w1; const float* o1; const float* o2;
              const float* gr; const float* gi; const float* gh; };

// ---------------- All weights -> bf16-component MFMA B-fragments.
__global__ void pack_weights(PSrc ps, u16* __restrict__ dst){
  int f = blockIdx.x, l = threadIdx.x;
  const float* src; int comp, kt, ct;
  if (f < 192){
    comp = f / 96; int g = f % 96;
    int br = g >> 5, rem = g & 31; kt = rem >> 3; ct = rem & 7;
    src = ps.w2 + (size_t)br*HH*HH;
  } else if (f < 768){
    int g = f - 192; int m = g / 96; int rem = g % 96;
    comp = rem >> 5; int idx = rem & 31; kt = idx >> 3; ct = idx & 7;
    src = ps.w1 + (size_t)m*HH*HH;
  } else if (f < 896){
    int g = f - 768; int mat = g >> 6; int rem = g & 63;
    comp = rem >> 5; int idx = rem & 31; kt = idx >> 3; ct = idx & 7;
    src = mat ? ps.o2 : ps.o1;
  } else {
    int g = f - 896; int mat = g / 96; int rem = g % 96;
    comp = rem >> 5; int idx = rem & 31; kt = idx >> 3; ct = idx & 7;
    src = mat == 0 ? ps.gr : (mat == 1 ? ps.gi : ps.gh);
  }
  int col = (ct << 4) + (l & 15);
  u16* d = dst + f*512 + l*8;
  #pragma unroll
  for (int j = 0; j < 8; ++j){
    int kk = (kt << 5) + ((l >> 4) << 3) + j;
    float v = src[kk*HH + col];
    u16 c0 = f2b(v); float r = v - b2f(c0);
    u16 c1 = f2b(r); r -= b2f(c1);
    u16 c2 = f2b(r);
    d[j] = comp == 0 ? c0 : (comp == 1 ? c1 : c2);
  }
}

// ---------------- Edge sort by receiver (counting sort), once per call.
__global__ void hist_kernel(const int* __restrict__ edge, int* __restrict__ hist){
  int i = blockIdx.x*256 + threadIdx.x;
  if (i < EE) atomicAdd(&hist[edge[EE + i]], 1);
}
__global__ void scan_kernel(const int* __restrict__ hist, int* __restrict__ cursor){
  __shared__ int part[256];
  __shared__ int partx[256];
  int tid = threadIdx.x;
  int base = tid*40;
  int s = 0;
  for (int j = 0; j < 40; ++j){ int b = base+j; if (b < NN) s += hist[b]; }
  part[tid] = s;
  __syncthreads();
  if (tid == 0){ int acc = 0; for (int i = 0; i < 256; ++i){ partx[i] = acc; acc += part[i]; } }
  __syncthreads();
  int acc = partx[tid];
  for (int j = 0; j < 40; ++j){ int b = base+j; if (b < NN){ cursor[b] = acc; acc += hist[b]; } }
}
__global__ void scatter_kernel(const int* __restrict__ edge, int* __restrict__ cursor,
                               int* __restrict__ pr, int* __restrict__ pc){
  int i = blockIdx.x*256 + threadIdx.x;
  if (i < EE){
    int r = edge[i], c = edge[EE + i];
    int pos = atomicAdd(&cursor[c], 1);
    pr[pos] = r; pc[pos] = c;
  }
}

// ---------------- Edge kernel: 32 sorted edges/block, double-buffered m1 LDS.
// stage(k+1) and MFMA(k) share a barrier interval -> gather latency hides under MFMA.
__global__ __launch_bounds__(256)
void edge_kernel(const int* __restrict__ pr, const int* __restrict__ pc,
                 const float* __restrict__ UV,
                 const float* __restrict__ b1, const float* __restrict__ b2,
                 const u16* __restrict__ packs, float* __restrict__ agg){
  __shared__ __align__(16) u16 m1hi[2][32*128];
  __shared__ __align__(16) u16 m1lo[2][32*128];
  __shared__ int er[32], ec[32];
  const int tid = threadIdx.x;
  const int lane = tid & 63, wid = tid >> 6;
  const int e0 = blockIdx.x << 5;

  if (tid < 32) er[tid] = pr[e0 + tid];
  else if (tid < 64) ec[tid - 32] = pc[e0 + tid - 32];
  __syncthreads();

  const int c4 = tid & 31;
  const int cOff = c4 << 2;
  const int ct0 = wid << 1;
  const int r0 = lane & 15, r1 = r0 + 16, kg = lane >> 4;

  auto stage = [&](int k, int b){
    float4 bb = *(const float4*)(b1 + k*HH + cOff);
    const float* __restrict__ Ub = UV + (size_t)(2*k)*NN*HH;
    const float* __restrict__ Vb = UV + (size_t)(2*k + 1)*NN*HH;
    u16* hiB = &m1hi[b][0];
    u16* loB = &m1lo[b][0];
    #pragma unroll
    for (int it = 0; it < 4; ++it){
      int e = (tid >> 5) + (it << 3);
      float4 u = *(const float4*)(Ub + (size_t)er[e]*HH + cOff);
      float4 v = *(const float4*)(Vb + (size_t)ec[e]*HH + cOff);
      float m0 = fast_tanh(u.x + v.x + bb.x);
      float m1 = fast_tanh(u.y + v.y + bb.y);
      float m2 = fast_tanh(u.z + v.z + bb.z);
      float m3 = fast_tanh(u.w + v.w + bb.w);
      ushort4 hi, lo;
      hi.x = f2b(m0); lo.x = f2b(m0 - b2f(hi.x));
      hi.y = f2b(m1); lo.y = f2b(m1 - b2f(hi.y));
      hi.z = f2b(m2); lo.z = f2b(m2 - b2f(hi.z));
      hi.w = f2b(m3); lo.w = f2b(m3 - b2f(hi.w));
      int idx = (e << 7) + (((c4 >> 1) ^ (e & 7)) << 3) + ((c4 & 1) << 2);
      *(ushort4*)(hiB + idx) = hi;
      *(ushort4*)(loB + idx) = lo;
    }
  };

  f32x4 acc[2][2];
  acc[0][0]=zero4(); acc[0][1]=zero4(); acc[1][0]=zero4(); acc[1][1]=zero4();

  stage(0, 0);
  __syncthreads();

  for (int k = 0; k < 3; ++k){
    int cur = k & 1;
    if (k < 2) stage(k + 1, cur ^ 1);   // gathers overlap this branch's MFMA (cross-wave)

    const u16* hiB = &m1hi[cur][0];
    const u16* loB = &m1lo[cur][0];
    f32x4 lacc[2][2];
    lacc[0][0]=zero4(); lacc[0][1]=zero4(); lacc[1][0]=zero4(); lacc[1][1]=zero4();
    #pragma unroll
    for (int kt = 0; kt < 4; ++kt){
      int sl = (kt << 2) + kg;
      bf16x8 a0h = ldA(hiB, r0, sl);
      bf16x8 a1h = ldA(hiB, r1, sl);
      bf16x8 a0l = ldA(loB, r0, sl);
      bf16x8 a1l = ldA(loB, r1, sl);
      #pragma unroll
      for (int ctl = 0; ctl < 2; ++ctl){
        int fh = FW2 + k*32 + (kt << 3) + ct0 + ctl;
        bf16x8 bh = ldB(packs, fh, lane);
        bf16x8 bl = ldB(packs, fh + 96, lane);
        lacc[0][ctl] = mfmab(a0h, bh, lacc[0][ctl]);
        lacc[0][ctl] = mfmab(a0l, bh, lacc[0][ctl]);
        lacc[0][ctl] = mfmab(a0h, bl, lacc[0][ctl]);
        lacc[1][ctl] = mfmab(a1h, bh, lacc[1][ctl]);
        lacc[1][ctl] = mfmab(a1l, bh, lacc[1][ctl]);
        lacc[1][ctl] = mfmab(a1h, bl, lacc[1][ctl]);
      }
    }
    #pragma unroll
    for (int ctl = 0; ctl < 2; ++ctl){
      int col = ((ct0 + ctl) << 4) + r0;
      float bb = b2[k*HH + col];
      #pragma unroll
      for (int rt = 0; rt < 2; ++rt)
        #pragma unroll
        for (int j = 0; j < 4; ++j)
          acc[rt][ctl][j] += fast_tanh(lacc[rt][ctl][j] + bb);
    }
    __syncthreads();   // next-branch buffer writes visible; current buffer free for k+2
  }

  // merged scatter: sorted ec -> run-length accumulate, flush once per receiver run
  {
    int col0 = (ct0 << 4) + r0;
    int col1 = ((ct0 + 1) << 4) + r0;
    int prevNode = -1;
    float s0 = 0.f, s1 = 0.f;
    #pragma unroll
    for (int rt = 0; rt < 2; ++rt)
      #pragma unroll
      for (int j = 0; j < 4; ++j){
        int row = (rt << 4) + (kg << 2) + j;
        int node = ec[row];
        float v0 = acc[rt][0][j], v1 = acc[rt][1][j];
        if (node != prevNode){
          if (prevNode >= 0){
            atomicAdd(agg + (size_t)prevNode*HH + col0, s0);
            atomicAdd(agg + (size_t)prevNode*HH + col1, s1);
          }
          prevNode = node; s0 = v0; s1 = v1;
        } else { s0 += v0; s1 += v1; }
      }
    atomicAdd(agg + (size_t)prevNode*HH + col0, s0);
    atomicAdd(agg + (size_t)prevNode*HH + col1, s1);
  }
}

// ---------------- Node kernel: GRU (split-MFMA) + gates + out-MLP + fused UV for t+1.
__global__ __launch_bounds__(256)
void node_kernel(const float* __restrict__ xin, const float* __restrict__ prevpred,
                 const int* __restrict__ burn, int t,
                 const float* __restrict__ agg, float* __restrict__ hid,
                 const float* __restrict__ irw, const float* __restrict__ irb,
                 const float* __restrict__ iiw, const float* __restrict__ iib,
                 const float* __restrict__ inw, const float* __restrict__ inb,
                 const float* __restrict__ o1b, const float* __restrict__ o2b,
                 const float* __restrict__ o3w, const float* __restrict__ o3b,
                 const u16* __restrict__ packs, float* __restrict__ UV,
                 float* __restrict__ out){
  __shared__ __align__(16) u16 ag0[32*128], ag1[32*128], ag2[32*128]; // agg splits, then h splits
  __shared__ __align__(16) u16 p1Hi[32*128], p1Lo[32*128];
  __shared__ float p2L[32][136];
  __shared__ float xLs[32][4];
  const int tid = threadIdx.x;
  const int n0 = blockIdx.x << 5;
  const float* __restrict__ xs = (t == 0 || t < burn[0]) ? xin : prevpred;

  #pragma unroll
  for (int it = 0; it < 4; ++it){
    int s = tid + (it << 8);
    int r = s >> 5, c4 = s & 31;
    int node = n0 + r; if (node > NN-1) node = NN-1;
    float4 v = *(const float4*)(agg + (size_t)node*HH + (c4 << 2));
    ushort4 q0, q1, q2;
    const float* pv = (const float*)&v;
    u16* q0p = (u16*)&q0; u16* q1p = (u16*)&q1; u16* q2p = (u16*)&q2;
    #pragma unroll
    for (int e = 0; e < 4; ++e){
      float x = pv[e];
      u16 a0 = f2b(x); float rr = x - b2f(a0);
      u16 a1 = f2b(rr); rr -= b2f(a1);
      q0p[e] = a0; q1p[e] = a1; q2p[e] = f2b(rr);
    }
    int idx = (r << 7) + (((c4 >> 1) ^ (r & 7)) << 3) + ((c4 & 1) << 2);
    *(ushort4*)(ag0 + idx) = q0;
    *(ushort4*)(ag1 + idx) = q1;
    *(ushort4*)(ag2 + idx) = q2;
  }
  if (tid < 128){
    int r = tid >> 2, c = tid & 3;
    int node = n0 + r; if (node > NN-1) node = NN-1;
    xLs[r][c] = xs[(size_t)node*CC + c];
  }
  __syncthreads();

  const int lane = tid & 63, wid = tid >> 6;
  const int ct0 = wid << 1;
  const int r0 = lane & 15, r1 = r0 + 16, kg = lane >> 4;

  // GRU matmuls via 3-comp split MFMA: aR/aI/aH = agg @ {whr, whi, whh}
  f32x4 aR[2][2], aI[2][2], aH[2][2];
  #pragma unroll
  for (int a = 0; a < 2; ++a){
    aR[a][0]=zero4(); aR[a][1]=zero4(); aI[a][0]=zero4(); aI[a][1]=zero4();
    aH[a][0]=zero4(); aH[a][1]=zero4();
  }
  #pragma unroll
  for (int kt = 0; kt < 4; ++kt){
    int sl = (kt << 2) + kg;
    bf16x8 a00 = ldA(ag0, r0, sl), a01 = ldA(ag1, r0, sl), a02 = ldA(ag2, r0, sl);
    bf16x8 a10 = ldA(ag0, r1, sl), a11 = ldA(ag1, r1, sl), a12 = ldA(ag2, r1, sl);
    #pragma unroll
    for (int ctl = 0; ctl < 2; ++ctl){
      #pragma unroll
      for (int m = 0; m < 3; ++m){
        int fb = FG + m*96 + (kt << 3) + ct0 + ctl;
        bf16x8 b0 = ldB(packs, fb,      lane);
        bf16x8 b1 = ldB(packs, fb + 32, lane);
        bf16x8 b2 = ldB(packs, fb + 64, lane);
        f32x4* A0 = m == 0 ? &aR[0][ctl] : (m == 1 ? &aI[0][ctl] : &aH[0][ctl]);
        f32x4* A1 = m == 0 ? &aR[1][ctl] : (m == 1 ? &aI[1][ctl] : &aH[1][ctl]);
        *A0 = mfmab(a00, b0, *A0);
        *A0 = mfmab(a01, b0, *A0);
        *A0 = mfmab(a00, b1, *A0);
        *A0 = mfmab(a02, b0, *A0);
        *A0 = mfmab(a01, b1, *A0);
        *A0 = mfmab(a00, b2, *A0);
        *A1 = mfmab(a10, b0, *A1);
        *A1 = mfmab(a11, b0, *A1);
        *A1 = mfmab(a10, b1, *A1);
        *A1 = mfmab(a12, b0, *A1);
        *A1 = mfmab(a11, b1, *A1);
        *A1 = mfmab(a10, b2, *A1);
      }
    }
  }
  __syncthreads();   // all waves done reading agg splits before h splits overwrite ag*

  // gates + hidden update; write 3-comp split of hnew into ag0/ag1/ag2
  #pragma unroll
  for (int ctl = 0; ctl < 2; ++ctl){
    int col = ((ct0 + ctl) << 4) + r0;
    float wr[CC], wi[CC], wn[CC];
    #pragma unroll
    for (int c = 0; c < CC; ++c){ wr[c]=irw[c*HH+col]; wi[c]=iiw[c*HH+col]; wn[c]=inw[c*HH+col]; }
    float rb = irb[col], ib = iib[col], nb = inb[col];
    #pragma unroll
    for (int rt = 0; rt < 2; ++rt)
      #pragma unroll
      for (int j = 0; j < 4; ++j){
        int row = (rt << 4) + (kg << 2) + j;
        int node = n0 + row;
        int nodec = node > NN-1 ? NN-1 : node;
        float xr = rb, xi = ib, xn = nb;
        #pragma unroll
        for (int c = 0; c < CC; ++c){
          float xv = xLs[row][c];
          xr = fmaf(xv, wr[c], xr); xi = fmaf(xv, wi[c], xi); xn = fmaf(xv, wn[c], xn);
        }
        float r = 1.f / (1.f + expf(-(xr + aR[rt][ctl][j])));
        float i = 1.f / (1.f + expf(-(xi + aI[rt][ctl][j])));
        float n = tanhf(xn + r * aH[rt][ctl][j]);
        float hold = hid[(size_t)nodec*HH + col];
        float hnew = (1.f - i)*n + i*hold;
        if (node < NN) hid[(size_t)node*HH + col] = hnew;
        u16 a = f2b(hnew); float rr = hnew - b2f(a);
        u16 b = f2b(rr);   rr -= b2f(b);
        int idx = (row << 7) + (((col >> 3) ^ (row & 7)) << 3) + (col & 7);
        ag0[idx] = a;
        ag1[idx] = b;
        ag2[idx] = f2b(rr);
      }
  }
  __syncthreads();

  // out1: relu(h @ O1 + b1) via 3-term split MFMA (h hi/lo = ag0/ag1) -> p1 hi/lo
  {
    f32x4 q[2][2];
    q[0][0]=zero4(); q[0][1]=zero4(); q[1][0]=zero4(); q[1][1]=zero4();
    #pragma unroll
    for (int kt = 0; kt < 4; ++kt){
      int sl = (kt << 2) + kg;
      bf16x8 ah0 = ldA(ag0, r0, sl), al0 = ldA(ag1, r0, sl);
      bf16x8 ah1 = ldA(ag0, r1, sl), al1 = ldA(ag1, r1, sl);
      #pragma unroll
      for (int ctl = 0; ctl < 2; ++ctl){
        int fo = FO + (kt << 3) + ct0 + ctl;
        bf16x8 bh = ldB(packs, fo, lane);
        bf16x8 bl = ldB(packs, fo + 32, lane);
        q[0][ctl] = mfmab(ah0, bh, q[0][ctl]);
        q[0][ctl] = mfmab(al0, bh, q[0][ctl]);
        q[0][ctl] = mfmab(ah0, bl, q[0][ctl]);
        q[1][ctl] = mfmab(ah1, bh, q[1][ctl]);
        q[1][ctl] = mfmab(al1, bh, q[1][ctl]);
        q[1][ctl] = mfmab(ah1, bl, q[1][ctl]);
      }
    }
    #pragma unroll
    for (int ctl = 0; ctl < 2; ++ctl){
      int col = ((ct0 + ctl) << 4) + r0;
      float bb = o1b[col];
      #pragma unroll
      for (int rt = 0; rt < 2; ++rt)
        #pragma unroll
        for (int j = 0; j < 4; ++j){
          int row = (rt << 4) + (kg << 2) + j;
          float v = q[rt][ctl][j] + bb; v = v > 0.f ? v : 0.f;
          u16 a = f2b(v);
          int idx = (row << 7) + (((col >> 3) ^ (row & 7)) << 3) + (col & 7);
          p1Hi[idx] = a;
          p1Lo[idx] = f2b(v - b2f(a));
        }
    }
  }
  __syncthreads();

  // out2: relu(p1 @ O2 + b2) via 3-term split MFMA -> p2 f32
  {
    f32x4 q[2][2];
    q[0][0]=zero4(); q[0][1]=zero4(); q[1][0]=zero4(); q[1][1]=zero4();
    #pragma unroll
    for (int kt = 0; kt < 4; ++kt){
      int sl = (kt << 2) + kg;
      bf16x8 ah0 = ldA(p1Hi, r0, sl), al0 = ldA(p1Lo, r0, sl);
      bf16x8 ah1 = ldA(p1Hi, r1, sl), al1 = ldA(p1Lo, r1, sl);
      #pragma unroll
      for (int ctl = 0; ctl < 2; ++ctl){
        int fo = FO + 64 + (kt << 3) + ct0 + ctl;
        bf16x8 bh = ldB(packs, fo, lane);
        bf16x8 bl = ldB(packs, fo + 32, lane);
        q[0][ctl] = mfmab(ah0, bh, q[0][ctl]);
        q[0][ctl] = mfmab(al0, bh, q[0][ctl]);
        q[0][ctl] = mfmab(ah0, bl, q[0][ctl]);
        q[1][ctl] = mfmab(ah1, bh, q[1][ctl]);
        q[1][ctl] = mfmab(al1, bh, q[1][ctl]);
        q[1][ctl] = mfmab(ah1, bl, q[1][ctl]);
      }
    }
    #pragma unroll
    for (int ctl = 0; ctl < 2; ++ctl){
      int col = ((ct0 + ctl) << 4) + r0;
      float bb = o2b[col];
      #pragma unroll
      for (int rt = 0; rt < 2; ++rt)
        #pragma unroll
        for (int j = 0; j < 4; ++j){
          int row = (rt << 4) + (kg << 2) + j;
          float v = q[rt][ctl][j] + bb; v = v > 0.f ? v : 0.f;
          p2L[row][col] = v;
        }
    }
  }
  __syncthreads();

  // fused UV for step t+1: UV[m] = h @ W1[m], 3-comp split (identical math to uv_kernel)
  if (t < TT-1){
    for (int m = 0; m < 6; ++m){
      f32x4 acc[2][2];
      acc[0][0]=zero4(); acc[0][1]=zero4(); acc[1][0]=zero4(); acc[1][1]=zero4();
      #pragma unroll
      for (int kt = 0; kt < 4; ++kt){
        int sl = (kt << 2) + kg;
        bf16x8 a00 = ldA(ag0, r0, sl), a01 = ldA(ag1, r0, sl), a02 = ldA(ag2, r0, sl);
        bf16x8 a10 = ldA(ag0, r1, sl), a11 = ldA(ag1, r1, sl), a12 = ldA(ag2, r1, sl);
        #pragma unroll
        for (int ctl = 0; ctl < 2; ++ctl){
          int fb = FW1 + m*96 + (kt << 3) + ct0 + ctl;
          bf16x8 b0 = ldB(packs, fb,      lane);
          bf16x8 b1 = ldB(packs, fb + 32, lane);
          bf16x8 b2 = ldB(packs, fb + 64, lane);
          acc[0][ctl] = mfmab(a00, b0, acc[0][ctl]);
          acc[0][ctl] = mfmab(a01, b0, acc[0][ctl]);
          acc[0][ctl] = mfmab(a00, b1, acc[0][ctl]);
          acc[0][ctl] = mfmab(a02, b0, acc[0][ctl]);
          acc[0][ctl] = mfmab(a01, b1, acc[0][ctl]);
          acc[0][ctl] = mfmab(a00, b2, acc[0][ctl]);
          acc[1][ctl] = mfmab(a10, b0, acc[1][ctl]);
          acc[1][ctl] = mfmab(a11, b0, acc[1][ctl]);
          acc[1][ctl] = mfmab(a10, b1, acc[1][ctl]);
          acc[1][ctl] = mfmab(a12, b0, acc[1][ctl]);
          acc[1][ctl] = mfmab(a11, b1, acc[1][ctl]);
          acc[1][ctl] = mfmab(a10, b2, acc[1][ctl]);
        }
      }
      #pragma unroll
      for (int ctl = 0; ctl < 2; ++ctl)
        #pragma unroll
        for (int rt = 0; rt < 2; ++rt)
          #pragma unroll
          for (int j = 0; j < 4; ++j){
            int row = (rt << 4) + (kg << 2) + j;
            int col = ((ct0 + ctl) << 4) + r0;
            int node = n0 + row;
            if (node < NN) UV[((size_t)m*NN + node)*HH + col] = acc[rt][ctl][j];
          }
    }
  }

  // out3: H -> 4, then pred = x + relu(...)
  if (tid < 128){
    int r = tid >> 2, c = tid & 3;
    int node = n0 + r;
    if (node < NN){
      float s = o3b[c];
      for (int kk = 0; kk < HH; ++kk) s = fmaf(p2L[r][kk], o3w[kk*CC + c], s);
      float v = fmaxf(s, 0.f);
      out[((size_t)t*NN + node)*CC + c] = xLs[r][c] + v;
    }
  }
}

extern "C" void kernel_launch(void* const* d_in, const int* in_sizes, int n_in,
                              void* d_out, int out_size, void* d_ws, size_t ws_size,
                              hipStream_t stream){
  const float* inputs = (const float*)d_in[0];
  const float* fc1w = (const float*)d_in[1];
  const float* fc1b = (const float*)d_in[2];
  const float* fc2w = (const float*)d_in[3];
  const float* fc2b = (const float*)d_in[4];
  const float* whr  = (const float*)d_in[5];
  const float* whi  = (const float*)d_in[6];
  const float* whh  = (const float*)d_in[7];
  const float* irw  = (const float*)d_in[8];
  const float* irb  = (const float*)d_in[9];
  const float* iiw  = (const float*)d_in[10];
  const float* iib  = (const float*)d_in[11];
  const float* inw  = (const float*)d_in[12];
  const float* inb  = (const float*)d_in[13];
  const float* o1w  = (const float*)d_in[14];
  const float* o1b  = (const float*)d_in[15];
  const float* o2w  = (const float*)d_in[16];
  const float* o2b  = (const float*)d_in[17];
  const float* o3w  = (const float*)d_in[18];
  const float* o3b  = (const float*)d_in[19];
  const int* edge   = (const int*)d_in[20];
  const int* burn   = (const int*)d_in[21];
  float* out = (float*)d_out;

  u8* ws = (u8*)d_ws;
  float* hid   = (float*)(ws);               // N*H fp32 = 5,120,000 B
  float* agg   = (float*)(ws + 5120000);     // N*H fp32 = 5,120,000 B
  float* UV    = (float*)(ws + 10240000);    // 6*N*H fp32 = 30,720,000 B
  u16*   packs = (u16*)(ws + 40960000);      // 1184 frags = 1,212,416 B
  int*   pr    = (int*)(ws + 42172416);      // 640,000 B
  int*   pc    = (int*)(ws + 42812416);      // 640,000 B
  int*   hist  = (int*)(ws + 43452416);      // 40,000 B
  int*   cursor= (int*)(ws + 43492416);      // 40,000 B

  hipMemsetAsync(hid, 0, 5120000, stream);
  hipMemsetAsync(UV, 0, 30720000, stream);   // h(0)=0 -> UV(0)=0
  hipMemsetAsync(hist, 0, 40000, stream);

  PSrc ps; ps.w2 = fc2w; ps.w1 = fc1w; ps.o1 = o1w; ps.o2 = o2w;
  ps.gr = whr; ps.gi = whi; ps.gh = whh;
  hipLaunchKernelGGL(pack_weights, dim3(NFRAG), dim3(64), 0, stream, ps, packs);
  hipLaunchKernelGGL(hist_kernel, dim3((EE+255)/256), dim3(256), 0, stream, edge, hist);
  hipLaunchKernelGGL(scan_kernel, dim3(1), dim3(256), 0, stream, hist, cursor);
  hipLaunchKernelGGL(scatter_kernel, dim3((EE+255)/256), dim3(256), 0, stream, edge, cursor, pr, pc);

  const int nblk = (NN + 31) / 32;  // 313
  for (int t = 0; t < TT; ++t){
    hipMemsetAsync(agg, 0, 5120000, stream);
    hipLaunchKernelGGL(edge_kernel, dim3(EE/32), dim3(256), 0, stream,
                       pr, pc, UV, fc1b, fc2b, packs, agg);
    hipLaunchKernelGGL(node_kernel, dim3(nblk), dim3(256), 0, stream,
                       inputs + (size_t)t*NN*CC, out + (size_t)(t > 0 ? t-1 : 0)*NN*CC, burn, t,
                       agg, hid, irw, irb, iiw, iib, inw, inb,
                       o1b, o2b, o3w, o3b, packs, UV, out);
  }
}

// Round 17
// 1485.021 us; speedup vs baseline: 3.6308x; 1.0557x over previous
//
#include <hip/hip_runtime.h>

#define TT 10
#define NN 10000
#define CC 4
#define HH 128
#define EE 160000

typedef unsigned char u8;
typedef unsigned short u16;
typedef unsigned int u32;
typedef __attribute__((ext_vector_type(8))) short bf16x8;
typedef __attribute__((ext_vector_type(4))) float f32x4;

// packed fragment regions (each frag = 64 lanes * 16B = 1KB)
#define FW2 0      // W2: 96 hi + 96 lo
#define FW1 192    // W1: 6 matrices * 3 comps * 32
#define FO  768    // O1 hi/lo (32+32), O2 hi/lo (32+32)
#define FG  896    // GRU whr/whi/whh: 3 matrices * 3 comps * 32
#define NFRAG 1184

__device__ __forceinline__ u16 f2b(float x){ // f32 -> bf16 RNE
  union { float f; u32 u; } v; v.f = x;
  return (u16)((v.u + 0x7fffu + ((v.u >> 16) & 1u)) >> 16);
}
__device__ __forceinline__ float b2f(u16 b){
  union { u32 u; float f; } v; v.u = ((u32)b) << 16;
  return v.f;
}
// HW-exp tanh: 1 - 2/(exp2(2x*log2e)+1); <=3e-7 rel err, correct saturation.
__device__ __forceinline__ float fast_tanh(float x){
  float e = __builtin_amdgcn_exp2f(x * 2.885390081777927f);
  return 1.f - 2.f * __builtin_amdgcn_rcpf(e + 1.f);
}
__device__ __forceinline__ float fast_sigmoid(float x){
  return __builtin_amdgcn_rcpf(1.f + __builtin_amdgcn_exp2f(-1.4426950408889634f * x));
}
__device__ __forceinline__ f32x4 zero4(){ f32x4 z = {0.f,0.f,0.f,0.f}; return z; }
__device__ __forceinline__ f32x4 mfmab(bf16x8 a, bf16x8 b, f32x4 c){
  return __builtin_amdgcn_mfma_f32_16x16x32_bf16(a, b, c, 0, 0, 0);
}
// A-fragment read from XOR-swizzled LDS tile (rows of 128 u16 = 16 slots of 16B)
__device__ __forceinline__ bf16x8 ldA(const u16* L, int row, int sl){
  return *(const bf16x8*)(L + (row << 7) + ((sl ^ (row & 7)) << 3));
}
__device__ __forceinline__ bf16x8 ldB(const u16* packs, int frag, int lane){
  return *(const bf16x8*)(packs + frag*512 + lane*8);
}

struct PSrc { const float* w2; const float* w1; const float* o1; const float* o2;
              const float* gr; const float* gi; const float* gh; };

// ---------------- All weights -> bf16-component MFMA B-fragments.
__global__ void pack_weights(PSrc ps, u16* __restrict__ dst){
  int f = blockIdx.x, l = threadIdx.x;
  const float* src; int comp, kt, ct;
  if (f < 192){
    comp = f / 96; int g = f % 96;
    int br = g >> 5, rem = g & 31; kt = rem >> 3; ct = rem & 7;
    src = ps.w2 + (size_t)br*HH*HH;
  } else if (f < 768){
    int g = f - 192; int m = g / 96; int rem = g % 96;
    comp = rem >> 5; int idx = rem & 31; kt = idx >> 3; ct = idx & 7;
    src = ps.w1 + (size_t)m*HH*HH;
  } else if (f < 896){
    int g = f - 768; int mat = g >> 6; int rem = g & 63;
    comp = rem >> 5; int idx = rem & 31; kt = idx >> 3; ct = idx & 7;
    src = mat ? ps.o2 : ps.o1;
  } else {
    int g = f - 896; int mat = g / 96; int rem = g % 96;
    comp = rem >> 5; int idx = rem & 31; kt = idx >> 3; ct = idx & 7;
    src = mat == 0 ? ps.gr : (mat == 1 ? ps.gi : ps.gh);
  }
  int col = (ct << 4) + (l & 15);
  u16* d = dst + f*512 + l*8;
  #pragma unroll
  for (int j = 0; j < 8; ++j){
    int kk = (kt << 5) + ((l >> 4) << 3) + j;
    float v = src[kk*HH + col];
    u16 c0 = f2b(v); float r = v - b2f(c0);
    u16 c1 = f2b(r); r -= b2f(c1);
    u16 c2 = f2b(r);
    d[j] = comp == 0 ? c0 : (comp == 1 ? c1 : c2);
  }
}

// ---------------- Edge sort by receiver (counting sort), once per call.
__global__ void hist_kernel(const int* __restrict__ edge, int* __restrict__ hist){
  int i = blockIdx.x*256 + threadIdx.x;
  if (i < EE) atomicAdd(&hist[edge[EE + i]], 1);
}
__global__ void scan_kernel(const int* __restrict__ hist, int* __restrict__ cursor){
  __shared__ int part[256];
  __shared__ int partx[256];
  int tid = threadIdx.x;
  int base = tid*40;
  int s = 0;
  for (int j = 0; j < 40; ++j){ int b = base+j; if (b < NN) s += hist[b]; }
  part[tid] = s;
  __syncthreads();
  if (tid == 0){ int acc = 0; for (int i = 0; i < 256; ++i){ partx[i] = acc; acc += part[i]; } }
  __syncthreads();
  int acc = partx[tid];
  for (int j = 0; j < 40; ++j){ int b = base+j; if (b < NN){ cursor[b] = acc; acc += hist[b]; } }
}
__global__ void scatter_kernel(const int* __restrict__ edge, int* __restrict__ cursor,
                               int* __restrict__ pr, int* __restrict__ pc){
  int i = blockIdx.x*256 + threadIdx.x;
  if (i < EE){
    int r = edge[i], c = edge[EE + i];
    int pos = atomicAdd(&cursor[c], 1);
    pr[pos] = r; pc[pos] = c;
  }
}

// ---------------- Edge kernel: 32 sorted edges/block, double-buffered m1 LDS.
// stage(k+1) and MFMA(k) share a barrier interval -> gather latency hides under MFMA.
__global__ __launch_bounds__(256)
void edge_kernel(const int* __restrict__ pr, const int* __restrict__ pc,
                 const float* __restrict__ UV,
                 const float* __restrict__ b1, const float* __restrict__ b2,
                 const u16* __restrict__ packs, float* __restrict__ agg){
  __shared__ __align__(16) u16 m1hi[2][32*128];
  __shared__ __align__(16) u16 m1lo[2][32*128];
  __shared__ int er[32], ec[32];
  const int tid = threadIdx.x;
  const int lane = tid & 63, wid = tid >> 6;
  const int e0 = blockIdx.x << 5;

  if (tid < 32) er[tid] = pr[e0 + tid];
  else if (tid < 64) ec[tid - 32] = pc[e0 + tid - 32];
  __syncthreads();

  const int c4 = tid & 31;
  const int cOff = c4 << 2;
  const int ct0 = wid << 1;
  const int r0 = lane & 15, r1 = r0 + 16, kg = lane >> 4;

  auto stage = [&](int k, int b){
    float4 bb = *(const float4*)(b1 + k*HH + cOff);
    const float* __restrict__ Ub = UV + (size_t)(2*k)*NN*HH;
    const float* __restrict__ Vb = UV + (size_t)(2*k + 1)*NN*HH;
    u16* hiB = &m1hi[b][0];
    u16* loB = &m1lo[b][0];
    #pragma unroll
    for (int it = 0; it < 4; ++it){
      int e = (tid >> 5) + (it << 3);
      float4 u = *(const float4*)(Ub + (size_t)er[e]*HH + cOff);
      float4 v = *(const float4*)(Vb + (size_t)ec[e]*HH + cOff);
      float m0 = fast_tanh(u.x + v.x + bb.x);
      float m1 = fast_tanh(u.y + v.y + bb.y);
      float m2 = fast_tanh(u.z + v.z + bb.z);
      float m3 = fast_tanh(u.w + v.w + bb.w);
      ushort4 hi, lo;
      hi.x = f2b(m0); lo.x = f2b(m0 - b2f(hi.x));
      hi.y = f2b(m1); lo.y = f2b(m1 - b2f(hi.y));
      hi.z = f2b(m2); lo.z = f2b(m2 - b2f(hi.z));
      hi.w = f2b(m3); lo.w = f2b(m3 - b2f(hi.w));
      int idx = (e << 7) + (((c4 >> 1) ^ (e & 7)) << 3) + ((c4 & 1) << 2);
      *(ushort4*)(hiB + idx) = hi;
      *(ushort4*)(loB + idx) = lo;
    }
  };

  f32x4 acc[2][2];
  acc[0][0]=zero4(); acc[0][1]=zero4(); acc[1][0]=zero4(); acc[1][1]=zero4();

  stage(0, 0);
  __syncthreads();

  for (int k = 0; k < 3; ++k){
    int cur = k & 1;
    if (k < 2) stage(k + 1, cur ^ 1);   // gathers overlap this branch's MFMA (cross-wave)

    const u16* hiB = &m1hi[cur][0];
    const u16* loB = &m1lo[cur][0];
    f32x4 lacc[2][2];
    lacc[0][0]=zero4(); lacc[0][1]=zero4(); lacc[1][0]=zero4(); lacc[1][1]=zero4();
    #pragma unroll
    for (int kt = 0; kt < 4; ++kt){
      int sl = (kt << 2) + kg;
      bf16x8 a0h = ldA(hiB, r0, sl);
      bf16x8 a1h = ldA(hiB, r1, sl);
      bf16x8 a0l = ldA(loB, r0, sl);
      bf16x8 a1l = ldA(loB, r1, sl);
      #pragma unroll
      for (int ctl = 0; ctl < 2; ++ctl){
        int fh = FW2 + k*32 + (kt << 3) + ct0 + ctl;
        bf16x8 bh = ldB(packs, fh, lane);
        bf16x8 bl = ldB(packs, fh + 96, lane);
        lacc[0][ctl] = mfmab(a0h, bh, lacc[0][ctl]);
        lacc[0][ctl] = mfmab(a0l, bh, lacc[0][ctl]);
        lacc[0][ctl] = mfmab(a0h, bl, lacc[0][ctl]);
        lacc[1][ctl] = mfmab(a1h, bh, lacc[1][ctl]);
        lacc[1][ctl] = mfmab(a1l, bh, lacc[1][ctl]);
        lacc[1][ctl] = mfmab(a1h, bl, lacc[1][ctl]);
      }
    }
    #pragma unroll
    for (int ctl = 0; ctl < 2; ++ctl){
      int col = ((ct0 + ctl) << 4) + r0;
      float bb = b2[k*HH + col];
      #pragma unroll
      for (int rt = 0; rt < 2; ++rt)
        #pragma unroll
        for (int j = 0; j < 4; ++j)
          acc[rt][ctl][j] += fast_tanh(lacc[rt][ctl][j] + bb);
    }
    __syncthreads();   // next-branch buffer writes visible; current buffer free for k+2
  }

  // merged scatter: sorted ec -> run-length accumulate, flush once per receiver run
  {
    int col0 = (ct0 << 4) + r0;
    int col1 = ((ct0 + 1) << 4) + r0;
    int prevNode = -1;
    float s0 = 0.f, s1 = 0.f;
    #pragma unroll
    for (int rt = 0; rt < 2; ++rt)
      #pragma unroll
      for (int j = 0; j < 4; ++j){
        int row = (rt << 4) + (kg << 2) + j;
        int node = ec[row];
        float v0 = acc[rt][0][j], v1 = acc[rt][1][j];
        if (node != prevNode){
          if (prevNode >= 0){
            atomicAdd(agg + (size_t)prevNode*HH + col0, s0);
            atomicAdd(agg + (size_t)prevNode*HH + col1, s1);
          }
          prevNode = node; s0 = v0; s1 = v1;
        } else { s0 += v0; s1 += v1; }
      }
    atomicAdd(agg + (size_t)prevNode*HH + col0, s0);
    atomicAdd(agg + (size_t)prevNode*HH + col1, s1);
  }
}

// ---------------- Node kernel: GRU (split-MFMA) + fast gates + out-MLP + fused UV + agg-clear.
__global__ __launch_bounds__(256)
void node_kernel(const float* __restrict__ xin, const float* __restrict__ prevpred,
                 const int* __restrict__ burn, int t,
                 float* __restrict__ agg, float* __restrict__ hid,
                 const float* __restrict__ irw, const float* __restrict__ irb,
                 const float* __restrict__ iiw, const float* __restrict__ iib,
                 const float* __restrict__ inw, const float* __restrict__ inb,
                 const float* __restrict__ o1b, const float* __restrict__ o2b,
                 const float* __restrict__ o3w, const float* __restrict__ o3b,
                 const u16* __restrict__ packs, float* __restrict__ UV,
                 float* __restrict__ out){
  __shared__ __align__(16) u16 ag0[32*128], ag1[32*128], ag2[32*128]; // agg splits, then h splits
  __shared__ __align__(16) u16 p1Hi[32*128], p1Lo[32*128];
  __shared__ float p2L[32][136];
  __shared__ float xLs[32][4];
  const int tid = threadIdx.x;
  const int n0 = blockIdx.x << 5;
  const float* __restrict__ xs = (t == 0 || t < burn[0]) ? xin : prevpred;

  #pragma unroll
  for (int it = 0; it < 4; ++it){
    int s = tid + (it << 8);
    int r = s >> 5, c4 = s & 31;
    int node = n0 + r;
    int nodec = node > NN-1 ? NN-1 : node;
    float4 v = *(const float4*)(agg + (size_t)nodec*HH + (c4 << 2));
    if (node < NN){  // zero own element for next step's scatter (read-then-clear, same thread)
      float4 z = {0.f,0.f,0.f,0.f};
      *(float4*)(agg + (size_t)node*HH + (c4 << 2)) = z;
    }
    ushort4 q0, q1, q2;
    const float* pv = (const float*)&v;
    u16* q0p = (u16*)&q0; u16* q1p = (u16*)&q1; u16* q2p = (u16*)&q2;
    #pragma unroll
    for (int e = 0; e < 4; ++e){
      float x = pv[e];
      u16 a0 = f2b(x); float rr = x - b2f(a0);
      u16 a1 = f2b(rr); rr -= b2f(a1);
      q0p[e] = a0; q1p[e] = a1; q2p[e] = f2b(rr);
    }
    int idx = (r << 7) + (((c4 >> 1) ^ (r & 7)) << 3) + ((c4 & 1) << 2);
    *(ushort4*)(ag0 + idx) = q0;
    *(ushort4*)(ag1 + idx) = q1;
    *(ushort4*)(ag2 + idx) = q2;
  }
  if (tid < 128){
    int r = tid >> 2, c = tid & 3;
    int node = n0 + r; if (node > NN-1) node = NN-1;
    xLs[r][c] = xs[(size_t)node*CC + c];
  }
  __syncthreads();

  const int lane = tid & 63, wid = tid >> 6;
  const int ct0 = wid << 1;
  const int r0 = lane & 15, r1 = r0 + 16, kg = lane >> 4;

  // GRU matmuls via 3-comp split MFMA: aR/aI/aH = agg @ {whr, whi, whh}
  f32x4 aR[2][2], aI[2][2], aH[2][2];
  #pragma unroll
  for (int a = 0; a < 2; ++a){
    aR[a][0]=zero4(); aR[a][1]=zero4(); aI[a][0]=zero4(); aI[a][1]=zero4();
    aH[a][0]=zero4(); aH[a][1]=zero4();
  }
  #pragma unroll
  for (int kt = 0; kt < 4; ++kt){
    int sl = (kt << 2) + kg;
    bf16x8 a00 = ldA(ag0, r0, sl), a01 = ldA(ag1, r0, sl), a02 = ldA(ag2, r0, sl);
    bf16x8 a10 = ldA(ag0, r1, sl), a11 = ldA(ag1, r1, sl), a12 = ldA(ag2, r1, sl);
    #pragma unroll
    for (int ctl = 0; ctl < 2; ++ctl){
      #pragma unroll
      for (int m = 0; m < 3; ++m){
        int fb = FG + m*96 + (kt << 3) + ct0 + ctl;
        bf16x8 b0 = ldB(packs, fb,      lane);
        bf16x8 b1 = ldB(packs, fb + 32, lane);
        bf16x8 b2 = ldB(packs, fb + 64, lane);
        f32x4* A0 = m == 0 ? &aR[0][ctl] : (m == 1 ? &aI[0][ctl] : &aH[0][ctl]);
        f32x4* A1 = m == 0 ? &aR[1][ctl] : (m == 1 ? &aI[1][ctl] : &aH[1][ctl]);
        *A0 = mfmab(a00, b0, *A0);
        *A0 = mfmab(a01, b0, *A0);
        *A0 = mfmab(a00, b1, *A0);
        *A0 = mfmab(a02, b0, *A0);
        *A0 = mfmab(a01, b1, *A0);
        *A0 = mfmab(a00, b2, *A0);
        *A1 = mfmab(a10, b0, *A1);
        *A1 = mfmab(a11, b0, *A1);
        *A1 = mfmab(a10, b1, *A1);
        *A1 = mfmab(a12, b0, *A1);
        *A1 = mfmab(a11, b1, *A1);
        *A1 = mfmab(a10, b2, *A1);
      }
    }
  }
  __syncthreads();   // all waves done reading agg splits before h splits overwrite ag*

  // gates + hidden update; write 3-comp split of hnew into ag0/ag1/ag2
  #pragma unroll
  for (int ctl = 0; ctl < 2; ++ctl){
    int col = ((ct0 + ctl) << 4) + r0;
    float wr[CC], wi[CC], wn[CC];
    #pragma unroll
    for (int c = 0; c < CC; ++c){ wr[c]=irw[c*HH+col]; wi[c]=iiw[c*HH+col]; wn[c]=inw[c*HH+col]; }
    float rb = irb[col], ib = iib[col], nb = inb[col];
    #pragma unroll
    for (int rt = 0; rt < 2; ++rt)
      #pragma unroll
      for (int j = 0; j < 4; ++j){
        int row = (rt << 4) + (kg << 2) + j;
        int node = n0 + row;
        int nodec = node > NN-1 ? NN-1 : node;
        float xr = rb, xi = ib, xn = nb;
        #pragma unroll
        for (int c = 0; c < CC; ++c){
          float xv = xLs[row][c];
          xr = fmaf(xv, wr[c], xr); xi = fmaf(xv, wi[c], xi); xn = fmaf(xv, wn[c], xn);
        }
        float r = fast_sigmoid(xr + aR[rt][ctl][j]);
        float i = fast_sigmoid(xi + aI[rt][ctl][j]);
        float n = fast_tanh(xn + r * aH[rt][ctl][j]);
        float hold = hid[(size_t)nodec*HH + col];
        float hnew = (1.f - i)*n + i*hold;
        if (node < NN) hid[(size_t)node*HH + col] = hnew;
        u16 a = f2b(hnew); float rr = hnew - b2f(a);
        u16 b = f2b(rr);   rr -= b2f(b);
        int idx = (row << 7) + (((col >> 3) ^ (row & 7)) << 3) + (col & 7);
        ag0[idx] = a;
        ag1[idx] = b;
        ag2[idx] = f2b(rr);
      }
  }
  __syncthreads();

  // out1: relu(h @ O1 + b1) via 3-term split MFMA (h hi/lo = ag0/ag1) -> p1 hi/lo
  {
    f32x4 q[2][2];
    q[0][0]=zero4(); q[0][1]=zero4(); q[1][0]=zero4(); q[1][1]=zero4();
    #pragma unroll
    for (int kt = 0; kt < 4; ++kt){
      int sl = (kt << 2) + kg;
      bf16x8 ah0 = ldA(ag0, r0, sl), al0 = ldA(ag1, r0, sl);
      bf16x8 ah1 = ldA(ag0, r1, sl), al1 = ldA(ag1, r1, sl);
      #pragma unroll
      for (int ctl = 0; ctl < 2; ++ctl){
        int fo = FO + (kt << 3) + ct0 + ctl;
        bf16x8 bh = ldB(packs, fo, lane);
        bf16x8 bl = ldB(packs, fo + 32, lane);
        q[0][ctl] = mfmab(ah0, bh, q[0][ctl]);
        q[0][ctl] = mfmab(al0, bh, q[0][ctl]);
        q[0][ctl] = mfmab(ah0, bl, q[0][ctl]);
        q[1][ctl] = mfmab(ah1, bh, q[1][ctl]);
        q[1][ctl] = mfmab(al1, bh, q[1][ctl]);
        q[1][ctl] = mfmab(ah1, bl, q[1][ctl]);
      }
    }
    #pragma unroll
    for (int ctl = 0; ctl < 2; ++ctl){
      int col = ((ct0 + ctl) << 4) + r0;
      float bb = o1b[col];
      #pragma unroll
      for (int rt = 0; rt < 2; ++rt)
        #pragma unroll
        for (int j = 0; j < 4; ++j){
          int row = (rt << 4) + (kg << 2) + j;
          float v = q[rt][ctl][j] + bb; v = v > 0.f ? v : 0.f;
          u16 a = f2b(v);
          int idx = (row << 7) + (((col >> 3) ^ (row & 7)) << 3) + (col & 7);
          p1Hi[idx] = a;
          p1Lo[idx] = f2b(v - b2f(a));
        }
    }
  }
  __syncthreads();

  // out2: relu(p1 @ O2 + b2) via 3-term split MFMA -> p2 f32
  {
    f32x4 q[2][2];
    q[0][0]=zero4(); q[0][1]=zero4(); q[1][0]=zero4(); q[1][1]=zero4();
    #pragma unroll
    for (int kt = 0; kt < 4; ++kt){
      int sl = (kt << 2) + kg;
      bf16x8 ah0 = ldA(p1Hi, r0, sl), al0 = ldA(p1Lo, r0, sl);
      bf16x8 ah1 = ldA(p1Hi, r1, sl), al1 = ldA(p1Lo, r1, sl);
      #pragma unroll
      for (int ctl = 0; ctl < 2; ++ctl){
        int fo = FO + 64 + (kt << 3) + ct0 + ctl;
        bf16x8 bh = ldB(packs, fo, lane);
        bf16x8 bl = ldB(packs, fo + 32, lane);
        q[0][ctl] = mfmab(ah0, bh, q[0][ctl]);
        q[0][ctl] = mfmab(al0, bh, q[0][ctl]);
        q[0][ctl] = mfmab(ah0, bl, q[0][ctl]);
        q[1][ctl] = mfmab(ah1, bh, q[1][ctl]);
        q[1][ctl] = mfmab(al1, bh, q[1][ctl]);
        q[1][ctl] = mfmab(ah1, bl, q[1][ctl]);
      }
    }
    #pragma unroll
    for (int ctl = 0; ctl < 2; ++ctl){
      int col = ((ct0 + ctl) << 4) + r0;
      float bb = o2b[col];
      #pragma unroll
      for (int rt = 0; rt < 2; ++rt)
        #pragma unroll
        for (int j = 0; j < 4; ++j){
          int row = (rt << 4) + (kg << 2) + j;
          float v = q[rt][ctl][j] + bb; v = v > 0.f ? v : 0.f;
          p2L[row][col] = v;
        }
    }
  }
  __syncthreads();

  // fused UV for step t+1: UV[m] = h @ W1[m], 3-comp split (identical math to uv_kernel)
  if (t < TT-1){
    for (int m = 0; m < 6; ++m){
      f32x4 acc[2][2];
      acc[0][0]=zero4(); acc[0][1]=zero4(); acc[1][0]=zero4(); acc[1][1]=zero4();
      #pragma unroll
      for (int kt = 0; kt < 4; ++kt){
        int sl = (kt << 2) + kg;
        bf16x8 a00 = ldA(ag0, r0, sl), a01 = ldA(ag1, r0, sl), a02 = ldA(ag2, r0, sl);
        bf16x8 a10 = ldA(ag0, r1, sl), a11 = ldA(ag1, r1, sl), a12 = ldA(ag2, r1, sl);
        #pragma unroll
        for (int ctl = 0; ctl < 2; ++ctl){
          int fb = FW1 + m*96 + (kt << 3) + ct0 + ctl;
          bf16x8 b0 = ldB(packs, fb,      lane);
          bf16x8 b1 = ldB(packs, fb + 32, lane);
          bf16x8 b2 = ldB(packs, fb + 64, lane);
          acc[0][ctl] = mfmab(a00, b0, acc[0][ctl]);
          acc[0][ctl] = mfmab(a01, b0, acc[0][ctl]);
          acc[0][ctl] = mfmab(a00, b1, acc[0][ctl]);
          acc[0][ctl] = mfmab(a02, b0, acc[0][ctl]);
          acc[0][ctl] = mfmab(a01, b1, acc[0][ctl]);
          acc[0][ctl] = mfmab(a00, b2, acc[0][ctl]);
          acc[1][ctl] = mfmab(a10, b0, acc[1][ctl]);
          acc[1][ctl] = mfmab(a11, b0, acc[1][ctl]);
          acc[1][ctl] = mfmab(a10, b1, acc[1][ctl]);
          acc[1][ctl] = mfmab(a12, b0, acc[1][ctl]);
          acc[1][ctl] = mfmab(a11, b1, acc[1][ctl]);
          acc[1][ctl] = mfmab(a10, b2, acc[1][ctl]);
        }
      }
      #pragma unroll
      for (int ctl = 0; ctl < 2; ++ctl)
        #pragma unroll
        for (int rt = 0; rt < 2; ++rt)
          #pragma unroll
          for (int j = 0; j < 4; ++j){
            int row = (rt << 4) + (kg << 2) + j;
            int col = ((ct0 + ctl) << 4) + r0;
            int node = n0 + row;
            if (node < NN) UV[((size_t)m*NN + node)*HH + col] = acc[rt][ctl][j];
          }
    }
  }

  // out3: H -> 4, then pred = x + relu(...)
  if (tid < 128){
    int r = tid >> 2, c = tid & 3;
    int node = n0 + r;
    if (node < NN){
      float s = o3b[c];
      for (int kk = 0; kk < HH; ++kk) s = fmaf(p2L[r][kk], o3w[kk*CC + c], s);
      float v = fmaxf(s, 0.f);
      out[((size_t)t*NN + node)*CC + c] = xLs[r][c] + v;
    }
  }
}

extern "C" void kernel_launch(void* const* d_in, const int* in_sizes, int n_in,
                              void* d_out, int out_size, void* d_ws, size_t ws_size,
                              hipStream_t stream){
  const float* inputs = (const float*)d_in[0];
  const float* fc1w = (const float*)d_in[1];
  const float* fc1b = (const float*)d_in[2];
  const float* fc2w = (const float*)d_in[3];
  const float* fc2b = (const float*)d_in[4];
  const float* whr  = (const float*)d_in[5];
  const float* whi  = (const float*)d_in[6];
  const float* whh  = (const float*)d_in[7];
  const float* irw  = (const float*)d_in[8];
  const float* irb  = (const float*)d_in[9];
  const float* iiw  = (const float*)d_in[10];
  const float* iib  = (const float*)d_in[11];
  const float* inw  = (const float*)d_in[12];
  const float* inb  = (const float*)d_in[13];
  const float* o1w  = (const float*)d_in[14];
  const float* o1b  = (const float*)d_in[15];
  const float* o2w  = (const float*)d_in[16];
  const float* o2b  = (const float*)d_in[17];
  const float* o3w  = (const float*)d_in[18];
  const float* o3b  = (const float*)d_in[19];
  const int* edge   = (const int*)d_in[20];
  const int* burn   = (const int*)d_in[21];
  float* out = (float*)d_out;

  u8* ws = (u8*)d_ws;
  float* hid   = (float*)(ws);               // N*H fp32 = 5,120,000 B
  float* agg   = (float*)(ws + 5120000);     // N*H fp32 = 5,120,000 B
  float* UV    = (float*)(ws + 10240000);    // 6*N*H fp32 = 30,720,000 B
  u16*   packs = (u16*)(ws + 40960000);      // 1184 frags = 1,212,416 B
  int*   pr    = (int*)(ws + 42172416);      // 640,000 B
  int*   pc    = (int*)(ws + 42812416);      // 640,000 B
  int*   hist  = (int*)(ws + 43452416);      // 40,000 B
  int*   cursor= (int*)(ws + 43492416);      // 40,000 B

  hipMemsetAsync(hid, 0, 5120000, stream);
  hipMemsetAsync(agg, 0, 5120000, stream);   // t=0 only; node_kernel clears for t>0
  hipMemsetAsync(UV, 0, 30720000, stream);   // h(0)=0 -> UV(0)=0
  hipMemsetAsync(hist, 0, 40000, stream);

  PSrc ps; ps.w2 = fc2w; ps.w1 = fc1w; ps.o1 = o1w; ps.o2 = o2w;
  ps.gr = whr; ps.gi = whi; ps.gh = whh;
  hipLaunchKernelGGL(pack_weights, dim3(NFRAG), dim3(64), 0, stream, ps, packs);
  hipLaunchKernelGGL(hist_kernel, dim3((EE+255)/256), dim3(256), 0, stream, edge, hist);
  hipLaunchKernelGGL(scan_kernel, dim3(1), dim3(256), 0, stream, hist, cursor);
  hipLaunchKernelGGL(scatter_kernel, dim3((EE+255)/256), dim3(256), 0, stream, edge, cursor, pr, pc);

  const int nblk = (NN + 31) / 32;  // 313
  for (int t = 0; t < TT; ++t){
    hipLaunchKernelGGL(edge_kernel, dim3(EE/32), dim3(256), 0, stream,
                       pr, pc, UV, fc1b, fc2b, packs, agg);
    hipLaunchKernelGGL(node_kernel, dim3(nblk), dim3(256), 0, stream,
                       inputs + (size_t)t*NN*CC, out + (size_t)(t > 0 ? t-1 : 0)*NN*CC, burn, t,
                       agg, hid, irw, irb, iiw, iib, inw, inb,
                       o1b, o2b, o3w, o3b, packs, UV, out);
  }
}